// Round 16
// baseline (245.745 us; speedup 1.0000x reference)
//
#include <hip/hip_runtime.h>
#include <hip/hip_bf16.h>

typedef unsigned short u16;
typedef unsigned int u32;

#define Tn 128
#define Fn 512
#define HWc (Tn*Fn)
#define EPS 1e-5f

using bf16x8 = __attribute__((ext_vector_type(8))) short;
using f32x4  = __attribute__((ext_vector_type(4))) float;

__device__ __forceinline__ float b2f(u16 x){ return __uint_as_float(((u32)x)<<16); }
__device__ __forceinline__ u16 f2b(float f){
  __hip_bfloat16 h = __float2bfloat16(f);
  return *reinterpret_cast<u16*>(&h);
}

// async global->LDS, 16B per lane
__device__ __forceinline__ void gload16(const u16* g, u16* l){
  __builtin_amdgcn_global_load_lds((const __attribute__((address_space(1))) void*)g,
                                   (__attribute__((address_space(3))) void*)l, 16, 0, 0);
}

// ---------------- zero stats ----------------
__global__ void zero_stats2(float* a, float* b){
  int i = threadIdx.x;
  if (i < 128) a[i] = 0.f;
  else if (i < 160) b[i-128] = 0.f;
}

// ---------------- zero only the padded borders of an NHWC-padded buffer ----------------
__global__ __launch_bounds__(256) void border_zero(u16* __restrict__ p, int CS){
  int b = blockIdx.y;
  u16* base = p + (long)b*130*514*CS;
  int rowN = 514*CS;
  for (int i = blockIdx.x*256 + threadIdx.x; i < rowN; i += gridDim.x*256){
    base[i] = 0;
    base[(long)129*rowN + i] = 0;
  }
  int colN = 128*CS;
  for (int i = blockIdx.x*256 + threadIdx.x; i < colN; i += gridDim.x*256){
    int row = 1 + i/CS, ch = i - (i/CS)*CS;
    base[((long)row*514 + 0)*CS + ch] = 0;
    base[((long)row*514 + 513)*CS + ch] = 0;
  }
}

// ---------------- fp32 -> bf16 weight conversion (flat) ----------------
__global__ __launch_bounds__(256) void cvt_f2b(const float* __restrict__ src, u16* __restrict__ dst){
  int i = (blockIdx.x*256 + threadIdx.x)*4;
  float4 v = *(const float4*)(src + i);
  ushort4 o;
  o.x=f2b(v.x); o.y=f2b(v.y); o.z=f2b(v.z); o.w=f2b(v.w);
  *(ushort4*)(dst + i) = o;
}

// ---------------- conv weight reorg, FRAGMENT ORDER: wr[dt][KP/32][q:4][h:2][r:16][8] ----------------
__global__ __launch_bounds__(256)
void prep_wr(const float* __restrict__ w, u16* __restrict__ wr,
             int CIN, int cs, int cof, int KP){
  int i = blockIdx.x*256 + threadIdx.x;
  int tot = 96*KP;
  if (i >= tot) return;
  int e  = i & 7;
  int r  = (i >> 3) & 15;
  int h  = (i >> 7) & 1;
  int q  = (i >> 8) & 3;
  int rest = i >> 10;
  int NK = KP >> 5;
  int ks = rest % NK, dt = rest / NK;
  int o = h*16 + r;
  int k = ks*32 + q*8 + e;
  float v = 0.f;
  int g = cof + k, df = g/cs, ch = g - df*cs;
  if (o < 24 && df < 3 && ch >= cof && ch < cof+CIN)
    v = w[((o*CIN + (ch-cof))*3 + dt)*3 + df];
  wr[i] = f2b(v);
}

// ---------------- copy x (CHW fp32) -> b72p NHWC ch48..72 AND xc24 NHWC compact ----------------
__global__ __launch_bounds__(256)
void copy_x2(const float* __restrict__ x, u16* __restrict__ b72p, u16* __restrict__ xc24){
  __shared__ u16 sh[24][520];
  int t = blockIdx.x & 127, b = blockIdx.x >> 7;
  const float* src = x + ((long)(b*24)*128 + t)*512;
  for (int c=0; c<24; c++){
    float2 v = *(const float2*)(src + (long)c*65536 + threadIdx.x*2);
    sh[c][threadIdx.x*2]   = f2b(v.x);
    sh[c][threadIdx.x*2+1] = f2b(v.y);
  }
  __syncthreads();
  long r72 = ((long)(b*130 + t+1))*514*72;
  long r24 = ((long)(b*130 + t+1))*514*24;
  for (int i = threadIdx.x; i < 1536; i += 256){
    int f = i/3, c0 = (i%3)*8;
    union {int4 q; u16 u[8];} o;
    #pragma unroll
    for (int j=0;j<8;j++) o.u[j] = sh[c0+j][f];
    *(int4*)(b72p + r72 + (long)(f+1)*72 + 48 + c0) = o.q;
    *(int4*)(xc24 + r24 + (long)(f+1)*24 + c0) = o.q;
  }
}

// ---------------- MFMA implicit-GEMM 3x3 conv v6 (r13 known-good) ----------------
template<int KP, int CS>
__global__ __launch_bounds__(256)
void conv_mfma(const u16* __restrict__ X, int coff, const u16* __restrict__ WR,
               const float* __restrict__ bias, u16* __restrict__ Y,
               float* __restrict__ raw){
  constexpr int NK = KP/32;
  __shared__ u16 WS[3*32*KP];
  __shared__ float ssum[4][32], ssq[4][32];
  __shared__ float g24s[24], g24q[24];
  __shared__ __align__(16) u16 Ysh[128*24];
  int bid = (blockIdx.x & 7)*64 + (blockIdx.x >> 3);   // grid 512, chunk 64
  int b = bid >> 7, t = bid & 127;
  int tid = threadIdx.x, wid = tid >> 6, l = tid & 63;
  int r = l & 15, q = l >> 4;

  for (int i = tid*8; i < 3*32*KP; i += 2048)
    *(int4*)(WS + i) = *(const int4*)(WR + i);

  float bv0 = bias[r];
  float bv1 = (r < 8) ? bias[16+r] : 0.f;
  float s0=0,q0=0,s1=0,q1=0;
  __syncthreads();

  #pragma unroll
  for (int fi=0; fi<4; fi++){
    int f0w = fi*128 + wid*32;
    f32x4 acc[2][2] = {};
    #pragma unroll
    for (int dt=0; dt<3; dt++){
      const u16* Ab = X + ((long)((b*130 + t+dt)*514 + f0w + r))*CS + coff + q*8;
      bf16x8 a[2][NK];
      #pragma unroll
      for (int ks=0; ks<NK; ks++){
        a[0][ks] = *(const bf16x8*)(Ab + ks*32);
        a[1][ks] = *(const bf16x8*)(Ab + (long)16*CS + ks*32);
      }
      #pragma unroll
      for (int ks=0; ks<NK; ks++){
        const u16* Bb = WS + ((dt*NK + ks)*4 + q)*256 + r*8;
        bf16x8 b0 = *(const bf16x8*)(Bb);
        bf16x8 b1 = *(const bf16x8*)(Bb + 128);
        acc[0][0] = __builtin_amdgcn_mfma_f32_16x16x32_bf16(a[0][ks],b0,acc[0][0],0,0,0);
        acc[0][1] = __builtin_amdgcn_mfma_f32_16x16x32_bf16(a[0][ks],b1,acc[0][1],0,0,0);
        acc[1][0] = __builtin_amdgcn_mfma_f32_16x16x32_bf16(a[1][ks],b0,acc[1][0],0,0,0);
        acc[1][1] = __builtin_amdgcn_mfma_f32_16x16x32_bf16(a[1][ks],b1,acc[1][1],0,0,0);
      }
    }
    #pragma unroll
    for (int m=0;m<2;m++){
      #pragma unroll
      for (int j=0;j<4;j++){
        acc[m][0][j] += bv0; acc[m][1][j] += bv1;
        s0 += acc[m][0][j]; q0 += acc[m][0][j]*acc[m][0][j];
        s1 += acc[m][1][j]; q1 += acc[m][1][j]*acc[m][1][j];
      }
    }
    __syncthreads();
    #pragma unroll
    for (int m=0;m<2;m++){
      int fr = wid*32 + m*16 + q*4;
      #pragma unroll
      for (int j=0;j<4;j++){
        Ysh[(fr+j)*24 + r] = f2b(acc[m][0][j]);
        if (r < 8) Ysh[(fr+j)*24 + 16 + r] = f2b(acc[m][1][j]);
      }
    }
    __syncthreads();
    long Yb = ((long)((b*128 + t)*512) + fi*128)*24;
    const int4* sp = (const int4*)Ysh;
    for (int i = tid; i < 384; i += 256)
      *(int4*)(Y + Yb + (long)i*8) = sp[i];
  }

  #pragma unroll
  for (int off=16; off<=32; off<<=1){
    s0 += __shfl_xor(s0, off, 64); q0 += __shfl_xor(q0, off, 64);
    s1 += __shfl_xor(s1, off, 64); q1 += __shfl_xor(q1, off, 64);
  }
  if (q == 0){
    ssum[wid][r] = s0;     ssq[wid][r] = q0;
    ssum[wid][16+r] = s1;  ssq[wid][16+r] = q1;
  }
  __syncthreads();
  if (tid < 24){
    g24s[tid] = ssum[0][tid]+ssum[1][tid]+ssum[2][tid]+ssum[3][tid];
    g24q[tid] = ssq[0][tid]+ssq[1][tid]+ssq[2][tid]+ssq[3][tid];
  }
  __syncthreads();
  if (tid < 4){
    float as=0, aq=0;
    #pragma unroll
    for (int j=0;j<6;j++){ as += g24s[tid*6+j]; aq += g24q[tid*6+j]; }
    atomicAdd(&raw[b*4+tid], as);
    atomicAdd(&raw[16+b*4+tid], aq);
  }
}

// ---------------- normalize+relu: Y NHWC -> b72p channel slice (inline GN params) ----------------
__global__ __launch_bounds__(256)
void norm_relu_nhwc(const u16* __restrict__ Y, u16* __restrict__ dst, int coff,
                    const float* __restrict__ raw, const float* __restrict__ gw,
                    const float* __restrict__ gb, float invN){
  __shared__ float sA[24], sB[24];
  int bb = blockIdx.x / 768;                 // block spans a single batch b
  if (threadIdx.x < 24){
    int g = bb*4 + threadIdx.x/6;
    float m = raw[g]*invN;
    float var = raw[16+g]*invN - m*m;
    float is = rsqrtf(var + EPS);
    float sc = is*gw[threadIdx.x];
    sA[threadIdx.x] = sc;
    sB[threadIdx.x] = gb[threadIdx.x] - m*sc;
  }
  __syncthreads();
  long e = ((long)blockIdx.x*256 + threadIdx.x)*8;
  int c0 = (int)(e % 24);
  long fi = e / 24;
  int f = (int)(fi & 511);
  int bt = (int)(fi >> 9); int t = bt & 127, b = bt >> 7;
  union {int4 q; u16 u[8];} pk; pk.q = *(const int4*)(Y + e);
  union {int4 q; u16 u[8];} o;
  #pragma unroll
  for (int j=0;j<8;j++){
    float v = b2f(pk.u[j])*sA[c0+j] + sB[c0+j];
    o.u[j] = f2b(v>0.f?v:0.f);
  }
  *(int4*)(dst + ((long)(b*130 + t+1)*514 + (f+1))*72 + coff + c0) = o.q;
}

// ---------------- normalize+relu + NHWC->CHW transpose (inline GN params) ----------------
__global__ __launch_bounds__(256)
void norm_relu_chw(const u16* __restrict__ Y, u16* __restrict__ xr,
                   const float* __restrict__ raw, const float* __restrict__ gw,
                   const float* __restrict__ gb, float invN){
  __shared__ u16 sh[24][520];
  __shared__ float sA[24], sB[24];
  int t = blockIdx.x & 127, b = blockIdx.x >> 7;
  if (threadIdx.x < 24){
    int g = b*4 + threadIdx.x/6;
    float m = raw[g]*invN;
    float var = raw[16+g]*invN - m*m;
    float is = rsqrtf(var + EPS);
    float sc = is*gw[threadIdx.x];
    sA[threadIdx.x] = sc;
    sB[threadIdx.x] = gb[threadIdx.x] - m*sc;
  }
  __syncthreads();
  const u16* src = Y + ((long)(b*128+t))*12288;
  for (int i = threadIdx.x; i < 1536; i += 256){
    int e = i*8; int c0 = e % 24; int f = e / 24;
    union {int4 q; u16 u[8];} pk; pk.q = *(const int4*)(src + e);
    #pragma unroll
    for (int j=0;j<8;j++){
      float v = b2f(pk.u[j])*sA[c0+j] + sB[c0+j];
      sh[c0+j][f] = f2b(v>0.f?v:0.f);
    }
  }
  __syncthreads();
  for (int i = threadIdx.x; i < 1536; i += 256){
    int c = i >> 6, fq = (i & 63)*8;
    union {int4 q; u16 u[8];} o;
    #pragma unroll
    for (int j=0;j<8;j++) o.u[j] = sh[c][fq+j];
    *(int4*)(xr + ((long)((b*24+c)*128 + t))*512 + fq) = o.q;
  }
}

// ---------------- elementwise normalize+relu on CHW rows (h1), inline GN params ----------------
__global__ __launch_bounds__(256)
void norm_chw(u16* __restrict__ h, const float* __restrict__ raw,
              const float* __restrict__ gw, const float* __restrict__ gb, float invN){
  __shared__ float s_sc, s_off;
  int bc = blockIdx.x / 12;                 // block spans a single (b,c)
  if (threadIdx.x == 0){
    int b = bc/24, c = bc%24;
    int g = b*4 + c/6;
    float m = raw[g]*invN;
    float var = raw[16+g]*invN - m*m;
    float is = rsqrtf(var + EPS);
    float sc = is*gw[c];
    s_sc = sc;
    s_off = gb[c] - m*sc;
  }
  __syncthreads();
  float sc = s_sc, off = s_off;
  long e = ((long)blockIdx.x*256 + threadIdx.x)*8;
  union {int4 q; u16 u[8];} pk; pk.q = *(const int4*)(h + e);
  #pragma unroll
  for (int j=0;j<8;j++){ float v = b2f(pk.u[j])*sc + off; pk.u[j] = f2b(v>0.f?v:0.f); }
  *(int4*)(h + e) = pk.q;
}

// ---------------- gemm1: LDS-staged MFMA GEMM, depth-2 counted-vmcnt pipeline ----------------
template<int NF, bool STORE>
__global__ __launch_bounds__(256)
void gemm_lds(const u16* __restrict__ A, const u16* __restrict__ Bt, u16* __restrict__ C,
              int N, int K, int NBX, float* __restrict__ raw){
  constexpr int BN = NF*32;
  constexpr int BNP = BN + 4;
  constexpr int ABUF = 128*32;
  constexpr int BBUF = BN*32;
  __shared__ __align__(16) u16 SH[3*(ABUF+BBUF)];
  u16* Asb = SH;
  u16* Bsb = SH + 3*ABUF;
  int tid = threadIdx.x, wid = tid >> 6, l = tid & 63;
  int r = l & 15, q = l >> 4;
  int wr = wid >> 1, wc = wid & 1;
  int chunk = gridDim.x >> 3;
  int lin = (blockIdx.x & 7)*chunk + (blockIdx.x >> 3);
  int bx = lin % NBX, by = lin / NBX;
  long m0 = (long)by*128;
  int n0 = bx*BN;

  int arow[2], ach[2], aslot[2];
  #pragma unroll
  for (int j=0;j<2;j++){
    int idx = (wid*2+j)*64 + l;
    aslot[j] = idx*8;
    arow[j]  = ((idx>>6)<<4) | (idx & 15);
    ach[j]   = ((idx>>4) & 3)*8;
  }
  int brow[NF/2], bch[NF/2], bslot[NF/2];
  #pragma unroll
  for (int j=0;j<NF/2;j++){
    int idx = (wid*(NF/2)+j)*64 + l;
    bslot[j] = idx*8;
    brow[j]  = ((idx>>6)<<4) | (idx & 15);
    bch[j]   = ((idx>>4) & 3)*8;
  }

  f32x4 acc[4][NF];
  #pragma unroll
  for (int mf=0;mf<4;mf++)
    #pragma unroll
    for (int nf=0;nf<NF;nf++) acc[mf][nf] = (f32x4){0.f,0.f,0.f,0.f};

  int nt = K >> 5;
  #pragma unroll
  for (int j=0;j<2;j++)    gload16(A  + (m0+arow[j])*K + ach[j], Asb + aslot[j]);
  #pragma unroll
  for (int j=0;j<NF/2;j++) gload16(Bt + (long)(n0+brow[j])*K + bch[j], Bsb + bslot[j]);
  #pragma unroll
  for (int j=0;j<2;j++)    gload16(A  + (m0+arow[j])*K + 32 + ach[j], Asb + ABUF + aslot[j]);
  #pragma unroll
  for (int j=0;j<NF/2;j++) gload16(Bt + (long)(n0+brow[j])*K + 32 + bch[j], Bsb + BBUF + bslot[j]);

  int c0 = 0;
  for (int kt=0; kt<nt; kt++){
    if constexpr (NF==4) asm volatile("s_waitcnt vmcnt(4)" ::: "memory");
    else                 asm volatile("s_waitcnt vmcnt(3)" ::: "memory");
    __builtin_amdgcn_s_barrier();
    __builtin_amdgcn_sched_barrier(0);
    if (kt+2 < nt){
      int c2 = c0+2; if (c2>=3) c2-=3;
      int ko = (kt+2)*32;
      #pragma unroll
      for (int j=0;j<2;j++)    gload16(A  + (m0+arow[j])*K + ko + ach[j], Asb + c2*ABUF + aslot[j]);
      #pragma unroll
      for (int j=0;j<NF/2;j++) gload16(Bt + (long)(n0+brow[j])*K + ko + bch[j], Bsb + c2*BBUF + bslot[j]);
    }
    const u16* Ac = Asb + c0*ABUF;
    const u16* Bc = Bsb + c0*BBUF;
    bf16x8 af[4], bfv[NF];
    #pragma unroll
    for (int mf=0;mf<4;mf++) af[mf]  = *(const bf16x8*)(Ac + (((wr*4+mf)*4 + q)*16 + r)*8);
    #pragma unroll
    for (int nf=0;nf<NF;nf++) bfv[nf] = *(const bf16x8*)(Bc + (((wc*NF+nf)*4 + q)*16 + r)*8);
    #pragma unroll
    for (int mf=0;mf<4;mf++)
      #pragma unroll
      for (int nf=0;nf<NF;nf++)
        acc[mf][nf] = __builtin_amdgcn_mfma_f32_16x16x32_bf16(af[mf], bfv[nf], acc[mf][nf], 0,0,0);
    c0 = (c0+1==3) ? 0 : c0+1;
  }

  float s=0.f, ss=0.f;
  #pragma unroll
  for (int mf=0;mf<4;mf++)
    #pragma unroll
    for (int nf=0;nf<NF;nf++)
      #pragma unroll
      for (int j=0;j<4;j++){ float v = acc[mf][nf][j]; s += v; ss += v*v; }
  #pragma unroll
  for (int off=32; off>0; off>>=1){ s += __shfl_down(s,off,64); ss += __shfl_down(ss,off,64); }
  __shared__ float rs[4], rss[4];
  if (l==0){ rs[wid]=s; rss[wid]=ss; }
  __syncthreads();
  if (tid==0){
    int bc = (int)(m0 >> 7);
    int g = (bc/24)*4 + (bc%24)/6;
    atomicAdd(&raw[g],    rs[0]+rs[1]+rs[2]+rs[3]);
    atomicAdd(&raw[16+g], rss[0]+rss[1]+rss[2]+rss[3]);
  }

  if constexpr (STORE){
    #pragma unroll
    for (int mf=0;mf<4;mf++){
      int row = wr*64 + mf*16 + q*4;
      #pragma unroll
      for (int nf=0;nf<NF;nf++){
        int col = wc*(NF*16) + nf*16 + r;
        #pragma unroll
        for (int j=0;j<4;j++)
          SH[(row+j)*BNP + col] = f2b(acc[mf][nf][j]);
      }
    }
    __syncthreads();
    constexpr int RPT = BN/16;
    #pragma unroll
    for (int k=0;k<RPT;k++){
      int j = tid + k*256;
      int row = j / (BN/8), col8 = (j % (BN/8))*8;
      *(int4*)(C + (m0+row)*N + n0 + col8) = *(const int4*)(SH + row*BNP + col8);
    }
  }
}

// ---------------- gemm2 N-sweep: A-panel resident in LDS, 36-step B pipeline ----------------
// Block: 64 M-rows x 384 N-cols (6 n-tiles of 64), K=192. Grid 1536 = 192(M) x 8(N), XCD-chunked.
__global__ __launch_bounds__(256)
void gemm2_ns(const u16* __restrict__ A, const u16* __restrict__ Bt, u16* __restrict__ C,
              float* __restrict__ raw){
  __shared__ __align__(16) u16 As[24*512];      // 64 rows x 192 k (24 frag-slots x 512)
  __shared__ __align__(16) u16 Bring[4*2048];   // 4-slot ring, each 64 rows x 32 k
  __shared__ float rs[4], rss[4];
  const int K = 192, N = 3072;
  int tid = threadIdx.x, wid = tid >> 6, l = tid & 63;
  int r = l & 15, q = l >> 4;
  int wr = wid >> 1, wc = wid & 1;
  int lin = (blockIdx.x & 7)*192 + (blockIdx.x >> 3);
  int by = lin >> 3, bx2 = lin & 7;
  long m0 = (long)by*64;
  int nbase = bx2*384;

  // stage A (64x192) once: 6 gload16/thread, fragment-ordered slots
  #pragma unroll
  for (int j=0;j<6;j++){
    int e = j*4 + wid;
    int hi = e/6, ks = e%6;
    gload16(A + (m0 + hi*16 + r)*K + ks*32 + q*8, As + e*512 + l*8);
  }
  // prologue: stage B steps 0,1,2 (n-tile 0)
  #pragma unroll
  for (int p=0;p<3;p++)
    gload16(Bt + (long)(nbase + wid*16 + r)*K + p*32 + q*8, Bring + p*2048 + tid*8);

  float s=0.f, ss=0.f;
  f32x4 acc[2][2];
  #pragma unroll
  for (int mf=0;mf<2;mf++)
    #pragma unroll
    for (int nf=0;nf<2;nf++) acc[mf][nf] = (f32x4){0.f,0.f,0.f,0.f};

  for (int t=0; t<36; t++){
    int ks = t % 6;
    // store queue accounting: 16 C-stores enter the vmcnt queue at each tile end.
    // steps t>=6 with ks<3 have those stores newer than B(t) -> vmcnt(18); else vmcnt(2).
    if (t >= 6 && ks < 3) asm volatile("s_waitcnt vmcnt(18)" ::: "memory");
    else                  asm volatile("s_waitcnt vmcnt(2)"  ::: "memory");
    __builtin_amdgcn_s_barrier();
    __builtin_amdgcn_sched_barrier(0);
    if (t+3 < 36){
      int t3 = t+3;
      int jn3 = t3/6, ks3 = t3%6;
      gload16(Bt + (long)(nbase + jn3*64 + wid*16 + r)*K + ks3*32 + q*8,
              Bring + (t3&3)*2048 + tid*8);
    }
    const u16* Bs = Bring + (t&3)*2048;
    bf16x8 af[2], bfv[2];
    #pragma unroll
    for (int mf=0;mf<2;mf++) af[mf]  = *(const bf16x8*)(As + ((wr*2+mf)*6 + ks)*512 + (q*16+r)*8);
    #pragma unroll
    for (int nf=0;nf<2;nf++) bfv[nf] = *(const bf16x8*)(Bs + ((wc*2+nf)*64 + q*16 + r)*8);
    #pragma unroll
    for (int mf=0;mf<2;mf++)
      #pragma unroll
      for (int nf=0;nf<2;nf++)
        acc[mf][nf] = __builtin_amdgcn_mfma_f32_16x16x32_bf16(af[mf], bfv[nf], acc[mf][nf], 0,0,0);
    if (ks == 5){
      int jn = t/6;
      long ncol = nbase + jn*64;
      #pragma unroll
      for (int mf=0;mf<2;mf++){
        long rowb = m0 + wr*32 + mf*16 + q*4;
        #pragma unroll
        for (int nf=0;nf<2;nf++){
          long col = ncol + wc*32 + nf*16 + r;
          #pragma unroll
          for (int j=0;j<4;j++){
            float v = acc[mf][nf][j];
            s += v; ss += v*v;
            C[(rowb+j)*N + col] = f2b(v);
          }
          acc[mf][nf] = (f32x4){0.f,0.f,0.f,0.f};
        }
      }
    }
  }

  #pragma unroll
  for (int off=32; off>0; off>>=1){ s += __shfl_down(s,off,64); ss += __shfl_down(ss,off,64); }
  if (l==0){ rs[wid]=s; rss[wid]=ss; }
  __syncthreads();
  if (tid==0){
    int bc = (int)(m0 >> 7);
    int g = (bc/24)*4 + (bc%24)/6;
    atomicAdd(&raw[g],    rs[0]+rs[1]+rs[2]+rs[3]);
    atomicAdd(&raw[16+g], rss[0]+rss[1]+rss[2]+rss[3]);
  }
}

// ---------------- attention: att[4][6] (fp32) ----------------
__global__ void attention_kernel(const float* __restrict__ c, const float* __restrict__ wq,
                                 const float* __restrict__ bq, const float* __restrict__ keys,
                                 float* __restrict__ att){
  __shared__ float q[4][32];
  __shared__ float s[4][6];
  int t = threadIdx.x;
  if (t < 128){
    int b = t >> 5, k = t & 31;
    float a = bq[k];
    for (int j=0;j<32;j++) a += c[b*32+j] * wq[k*32+j];
    q[b][k] = a;
  }
  __syncthreads();
  if (t < 24){
    int b = t/6, n = t%6;
    float a = 0.f;
    for (int k=0;k<32;k++) a += q[b][k]*keys[k*6+n];
    s[b][n] = a * 0.17677669529663689f;
  }
  __syncthreads();
  if (t < 4){
    float mx = -1e30f;
    for (int n=0;n<6;n++) mx = fmaxf(mx, s[t][n]);
    float e[6], sm=0.f;
    for (int n=0;n<6;n++){ e[n]=expf(s[t][n]-mx); sm+=e[n]; }
    for (int n=0;n<6;n++) att[t*6+n] = e[n]/sm;
  }
}

// ---------------- final: out(fp32) = x_ + sum_n relu(gn2(h2))[...,n]*att[b,n] (inline GN) ----------------
__global__ __launch_bounds__(256)
void final_mix(const u16* __restrict__ h2, const u16* __restrict__ xr,
               const float* __restrict__ raw, const float* __restrict__ gw,
               const float* __restrict__ gb, float invN,
               const float* __restrict__ att, float* __restrict__ out){
  __shared__ float s_sc, s_off, s_att[6];
  int bc0 = blockIdx.x / 64;                // block spans single (b,c)
  int c  = bc0 % 24, b = bc0 / 24;
  if (threadIdx.x == 0){
    int g = b*4 + c/6;
    float m = raw[g]*invN;
    float var = raw[16+g]*invN - m*m;
    float is = rsqrtf(var + EPS);
    float sc = is*gw[c];
    s_sc = sc;
    s_off = gb[c] - m*sc;
  }
  if (threadIdx.x < 6) s_att[threadIdx.x] = att[b*6+threadIdx.x];
  __syncthreads();
  float sc = s_sc, off = s_off;
  float a[6];
  #pragma unroll
  for (int n=0;n<6;n++) a[n] = s_att[n];

  int gid = blockIdx.x*256 + threadIdx.x;
  int fq = gid & 127;
  int t  = (gid >> 7) & 127;
  int bc = gid >> 14;

  long hbase = (((long)bc*Tn + t))*3072 + (long)fq*24;
  union { int4 v[3]; u16 u[24]; } hv;
  const int4* hp = (const int4*)(h2 + hbase);
  hv.v[0]=hp[0]; hv.v[1]=hp[1]; hv.v[2]=hp[2];

  long xbase = (((long)bc*Tn + t))*Fn + (long)fq*4;
  union { unsigned long long q; u16 u[4]; } xv;
  xv.q = *(const unsigned long long*)(xr + xbase);

  float4 ov;
  float* op = &ov.x;
  #pragma unroll
  for (int j=0;j<4;j++){
    float accv = b2f(xv.u[j]);
    #pragma unroll
    for (int n=0;n<6;n++){
      float hvf = b2f(hv.u[j*6+n])*sc + off;
      hvf = hvf > 0.f ? hvf : 0.f;
      accv += hvf * a[n];
    }
    op[j] = accv;
  }
  *(float4*)(out + xbase) = ov;
}

extern "C" void kernel_launch(void* const* d_in, const int* in_sizes, int n_in,
                              void* d_out, int out_size, void* d_ws, size_t ws_size,
                              hipStream_t stream){
  const float* x   = (const float*)d_in[0];
  const float* c   = (const float*)d_in[1];
  const float* cw0 = (const float*)d_in[2];  const float* cb0 = (const float*)d_in[3];
  const float* gw0 = (const float*)d_in[4];  const float* gb0 = (const float*)d_in[5];
  const float* cw1 = (const float*)d_in[6];  const float* cb1 = (const float*)d_in[7];
  const float* gw1 = (const float*)d_in[8];  const float* gb1 = (const float*)d_in[9];
  const float* cw2 = (const float*)d_in[10]; const float* cb2 = (const float*)d_in[11];
  const float* gw2 = (const float*)d_in[12]; const float* gb2 = (const float*)d_in[13];
  const float* tw1 = (const float*)d_in[14]; const float* tg1w= (const float*)d_in[15]; const float* tg1b=(const float*)d_in[16];
  const float* tw2 = (const float*)d_in[17]; const float* tg2w= (const float*)d_in[18]; const float* tg2b=(const float*)d_in[19];
  const float* wqp = (const float*)d_in[20]; const float* bqp = (const float*)d_in[21]; const float* keys=(const float*)d_in[22];

  char* ws = (char*)d_ws;
  u16*   xr     = (u16*)(ws + 0);               // 12,582,912 B  [12288,512] bf16 CHW
  u16*   h1     = (u16*)(ws + 12582912);        //  4,718,592 B  [12288,192]
  u16*   tw1b   = (u16*)(ws + 17301504);        //    196,608 B
  u16*   tw2b   = (u16*)(ws + 17498112);        //  1,179,648 B
  float* stats5 = (float*)(ws + 18677760);      //        128 B
  float* att    = (float*)(ws + 18678656);      //        128 B
  // ---- h2 span (reused during conv phase) ----
  u16*   h2     = (u16*)(ws + 18680832);        // 75,497,472 B  [12288,3072]
  u16*   Y      = (u16*)(ws + 18680832);        // 12,582,912 B  NHWC conv out [4,128,512,24]
  u16*   b72p   = (u16*)(ws + 31263744);        // 38,488,320 B  NHWC padded [4,130,514,72]
  u16*   xc24   = (u16*)(ws + 69752064);        // 12,829,440 B (+256 slack) NHWC padded [4,130,514,24]
  float* stats14= (float*)(ws + 82581760);      //        512 B
  u16*   wr0    = (u16*)(ws + 82585344);        //     18,432 B
  u16*   wr1    = (u16*)(ws + 82603776);        //     36,864 B
  u16*   wr2    = (u16*)(ws + 82640640);        //     43,008 B

  border_zero<<<dim3(32,4),256,0,stream>>>(b72p, 72);
  border_zero<<<dim3(16,4),256,0,stream>>>(xc24, 24);
  zero_stats2<<<1,256,0,stream>>>(stats14, stats5);

  prep_wr<<<36,256,0,stream>>>(cw0, wr0, 24, 24, 0, 96);
  prep_wr<<<72,256,0,stream>>>(cw1, wr1, 48, 72, 24, 192);
  prep_wr<<<84,256,0,stream>>>(cw2, wr2, 72, 72, 0, 224);
  cvt_f2b<<<96,256,0,stream>>>(tw1, tw1b);
  cvt_f2b<<<576,256,0,stream>>>(tw2, tw2b);
  copy_x2<<<512,256,0,stream>>>(x, b72p, xc24);
  attention_kernel<<<1,128,0,stream>>>(c, wqp, bqp, keys, att);

  // ---- conv block 0 ----
  conv_mfma<96,24><<<512,256,0,stream>>>(xc24, 0, wr0, cb0, Y, stats14+0);
  norm_relu_nhwc<<<3072,256,0,stream>>>(Y, b72p, 24, stats14+0, gw0, gb0, 1.f/393216.f);

  // ---- conv block 1 ----
  conv_mfma<192,72><<<512,256,0,stream>>>(b72p, 24, wr1, cb1, Y, stats14+32);
  norm_relu_nhwc<<<3072,256,0,stream>>>(Y, b72p, 0, stats14+32, gw1, gb1, 1.f/393216.f);

  // ---- conv block 2 -> xr (CHW) ----
  conv_mfma<224,72><<<512,256,0,stream>>>(b72p, 0, wr2, cb2, Y, stats14+64);
  norm_relu_chw<<<512,256,0,stream>>>(Y, xr, stats14+64, gw2, gb2, 1.f/393216.f);

  // ---- TDF: gemm1 (12288x192x512) + GN + relu ----
  gemm_lds<2,true><<<288,256,0,stream>>>(xr, tw1b, h1, 192, 512, 3, stats14+96);
  norm_chw<<<1152,256,0,stream>>>(h1, stats14+96, tg1w, tg1b, 1.f/147456.f);

  // ---- TDF: gemm2 (12288x3072x192), A-resident N-sweep ----
  gemm2_ns<<<1536,256,0,stream>>>(h1, tw2b, h2, stats5);

  // ---- final mix (inline GN2 params) ----
  final_mix<<<6144,256,0,stream>>>(h2, xr, stats5, tg2w, tg2b, 1.f/2359296.f, att, (float*)d_out);
}

// Round 17
// 230.218 us; speedup vs baseline: 1.0674x; 1.0674x over previous
//
#include <hip/hip_runtime.h>
#include <hip/hip_bf16.h>

typedef unsigned short u16;
typedef unsigned int u32;

#define Tn 128
#define Fn 512
#define HWc (Tn*Fn)
#define EPS 1e-5f

using bf16x8 = __attribute__((ext_vector_type(8))) short;
using f32x4  = __attribute__((ext_vector_type(4))) float;

__device__ __forceinline__ float b2f(u16 x){ return __uint_as_float(((u32)x)<<16); }
__device__ __forceinline__ u16 f2b(float f){
  __hip_bfloat16 h = __float2bfloat16(f);
  return *reinterpret_cast<u16*>(&h);
}

// async global->LDS, 16B per lane
__device__ __forceinline__ void gload16(const u16* g, u16* l){
  __builtin_amdgcn_global_load_lds((const __attribute__((address_space(1))) void*)g,
                                   (__attribute__((address_space(3))) void*)l, 16, 0, 0);
}

// ---------------- zero stats ----------------
__global__ void zero_stats2(float* a, float* b){
  int i = threadIdx.x;
  if (i < 128) a[i] = 0.f;
  else if (i < 160) b[i-128] = 0.f;
}

// ---------------- zero only the padded borders of an NHWC-padded buffer ----------------
__global__ __launch_bounds__(256) void border_zero(u16* __restrict__ p, int CS){
  int b = blockIdx.y;
  u16* base = p + (long)b*130*514*CS;
  int rowN = 514*CS;
  for (int i = blockIdx.x*256 + threadIdx.x; i < rowN; i += gridDim.x*256){
    base[i] = 0;
    base[(long)129*rowN + i] = 0;
  }
  int colN = 128*CS;
  for (int i = blockIdx.x*256 + threadIdx.x; i < colN; i += gridDim.x*256){
    int row = 1 + i/CS, ch = i - (i/CS)*CS;
    base[((long)row*514 + 0)*CS + ch] = 0;
    base[((long)row*514 + 513)*CS + ch] = 0;
  }
}

// ---------------- fp32 -> bf16 weight conversion (flat) ----------------
__global__ __launch_bounds__(256) void cvt_f2b(const float* __restrict__ src, u16* __restrict__ dst){
  int i = (blockIdx.x*256 + threadIdx.x)*4;
  float4 v = *(const float4*)(src + i);
  ushort4 o;
  o.x=f2b(v.x); o.y=f2b(v.y); o.z=f2b(v.z); o.w=f2b(v.w);
  *(ushort4*)(dst + i) = o;
}

// ---------------- conv weight reorg, FRAGMENT ORDER: wr[dt][KP/32][q:4][h:2][r:16][8] ----------------
__global__ __launch_bounds__(256)
void prep_wr(const float* __restrict__ w, u16* __restrict__ wr,
             int CIN, int cs, int cof, int KP){
  int i = blockIdx.x*256 + threadIdx.x;
  int tot = 96*KP;
  if (i >= tot) return;
  int e  = i & 7;
  int r  = (i >> 3) & 15;
  int h  = (i >> 7) & 1;
  int q  = (i >> 8) & 3;
  int rest = i >> 10;
  int NK = KP >> 5;
  int ks = rest % NK, dt = rest / NK;
  int o = h*16 + r;
  int k = ks*32 + q*8 + e;
  float v = 0.f;
  int g = cof + k, df = g/cs, ch = g - df*cs;
  if (o < 24 && df < 3 && ch >= cof && ch < cof+CIN)
    v = w[((o*CIN + (ch-cof))*3 + dt)*3 + df];
  wr[i] = f2b(v);
}

// ---------------- copy x (CHW fp32) -> b72p NHWC ch48..72 AND xc24 NHWC compact ----------------
__global__ __launch_bounds__(256)
void copy_x2(const float* __restrict__ x, u16* __restrict__ b72p, u16* __restrict__ xc24){
  __shared__ u16 sh[24][520];
  int t = blockIdx.x & 127, b = blockIdx.x >> 7;
  const float* src = x + ((long)(b*24)*128 + t)*512;
  for (int c=0; c<24; c++){
    float2 v = *(const float2*)(src + (long)c*65536 + threadIdx.x*2);
    sh[c][threadIdx.x*2]   = f2b(v.x);
    sh[c][threadIdx.x*2+1] = f2b(v.y);
  }
  __syncthreads();
  long r72 = ((long)(b*130 + t+1))*514*72;
  long r24 = ((long)(b*130 + t+1))*514*24;
  for (int i = threadIdx.x; i < 1536; i += 256){
    int f = i/3, c0 = (i%3)*8;
    union {int4 q; u16 u[8];} o;
    #pragma unroll
    for (int j=0;j<8;j++) o.u[j] = sh[c0+j][f];
    *(int4*)(b72p + r72 + (long)(f+1)*72 + 48 + c0) = o.q;
    *(int4*)(xc24 + r24 + (long)(f+1)*24 + c0) = o.q;
  }
}

// ---------------- MFMA implicit-GEMM 3x3 conv v6 (r13 known-good) ----------------
template<int KP, int CS>
__global__ __launch_bounds__(256)
void conv_mfma(const u16* __restrict__ X, int coff, const u16* __restrict__ WR,
               const float* __restrict__ bias, u16* __restrict__ Y,
               float* __restrict__ raw){
  constexpr int NK = KP/32;
  __shared__ u16 WS[3*32*KP];
  __shared__ float ssum[4][32], ssq[4][32];
  __shared__ float g24s[24], g24q[24];
  __shared__ __align__(16) u16 Ysh[128*24];
  int bid = (blockIdx.x & 7)*64 + (blockIdx.x >> 3);   // grid 512, chunk 64
  int b = bid >> 7, t = bid & 127;
  int tid = threadIdx.x, wid = tid >> 6, l = tid & 63;
  int r = l & 15, q = l >> 4;

  for (int i = tid*8; i < 3*32*KP; i += 2048)
    *(int4*)(WS + i) = *(const int4*)(WR + i);

  float bv0 = bias[r];
  float bv1 = (r < 8) ? bias[16+r] : 0.f;
  float s0=0,q0=0,s1=0,q1=0;
  __syncthreads();

  #pragma unroll
  for (int fi=0; fi<4; fi++){
    int f0w = fi*128 + wid*32;
    f32x4 acc[2][2] = {};
    #pragma unroll
    for (int dt=0; dt<3; dt++){
      const u16* Ab = X + ((long)((b*130 + t+dt)*514 + f0w + r))*CS + coff + q*8;
      bf16x8 a[2][NK];
      #pragma unroll
      for (int ks=0; ks<NK; ks++){
        a[0][ks] = *(const bf16x8*)(Ab + ks*32);
        a[1][ks] = *(const bf16x8*)(Ab + (long)16*CS + ks*32);
      }
      #pragma unroll
      for (int ks=0; ks<NK; ks++){
        const u16* Bb = WS + ((dt*NK + ks)*4 + q)*256 + r*8;
        bf16x8 b0 = *(const bf16x8*)(Bb);
        bf16x8 b1 = *(const bf16x8*)(Bb + 128);
        acc[0][0] = __builtin_amdgcn_mfma_f32_16x16x32_bf16(a[0][ks],b0,acc[0][0],0,0,0);
        acc[0][1] = __builtin_amdgcn_mfma_f32_16x16x32_bf16(a[0][ks],b1,acc[0][1],0,0,0);
        acc[1][0] = __builtin_amdgcn_mfma_f32_16x16x32_bf16(a[1][ks],b0,acc[1][0],0,0,0);
        acc[1][1] = __builtin_amdgcn_mfma_f32_16x16x32_bf16(a[1][ks],b1,acc[1][1],0,0,0);
      }
    }
    #pragma unroll
    for (int m=0;m<2;m++){
      #pragma unroll
      for (int j=0;j<4;j++){
        acc[m][0][j] += bv0; acc[m][1][j] += bv1;
        s0 += acc[m][0][j]; q0 += acc[m][0][j]*acc[m][0][j];
        s1 += acc[m][1][j]; q1 += acc[m][1][j]*acc[m][1][j];
      }
    }
    __syncthreads();
    #pragma unroll
    for (int m=0;m<2;m++){
      int fr = wid*32 + m*16 + q*4;
      #pragma unroll
      for (int j=0;j<4;j++){
        Ysh[(fr+j)*24 + r] = f2b(acc[m][0][j]);
        if (r < 8) Ysh[(fr+j)*24 + 16 + r] = f2b(acc[m][1][j]);
      }
    }
    __syncthreads();
    long Yb = ((long)((b*128 + t)*512) + fi*128)*24;
    const int4* sp = (const int4*)Ysh;
    for (int i = tid; i < 384; i += 256)
      *(int4*)(Y + Yb + (long)i*8) = sp[i];
  }

  #pragma unroll
  for (int off=16; off<=32; off<<=1){
    s0 += __shfl_xor(s0, off, 64); q0 += __shfl_xor(q0, off, 64);
    s1 += __shfl_xor(s1, off, 64); q1 += __shfl_xor(q1, off, 64);
  }
  if (q == 0){
    ssum[wid][r] = s0;     ssq[wid][r] = q0;
    ssum[wid][16+r] = s1;  ssq[wid][16+r] = q1;
  }
  __syncthreads();
  if (tid < 24){
    g24s[tid] = ssum[0][tid]+ssum[1][tid]+ssum[2][tid]+ssum[3][tid];
    g24q[tid] = ssq[0][tid]+ssq[1][tid]+ssq[2][tid]+ssq[3][tid];
  }
  __syncthreads();
  if (tid < 4){
    float as=0, aq=0;
    #pragma unroll
    for (int j=0;j<6;j++){ as += g24s[tid*6+j]; aq += g24q[tid*6+j]; }
    atomicAdd(&raw[b*4+tid], as);
    atomicAdd(&raw[16+b*4+tid], aq);
  }
}

// ---------------- normalize+relu: Y NHWC -> b72p channel slice (inline GN params) ----------------
__global__ __launch_bounds__(256)
void norm_relu_nhwc(const u16* __restrict__ Y, u16* __restrict__ dst, int coff,
                    const float* __restrict__ raw, const float* __restrict__ gw,
                    const float* __restrict__ gb, float invN){
  __shared__ float sA[24], sB[24];
  int bb = blockIdx.x / 768;                 // block spans a single batch b
  if (threadIdx.x < 24){
    int g = bb*4 + threadIdx.x/6;
    float m = raw[g]*invN;
    float var = raw[16+g]*invN - m*m;
    float is = rsqrtf(var + EPS);
    float sc = is*gw[threadIdx.x];
    sA[threadIdx.x] = sc;
    sB[threadIdx.x] = gb[threadIdx.x] - m*sc;
  }
  __syncthreads();
  long e = ((long)blockIdx.x*256 + threadIdx.x)*8;
  int c0 = (int)(e % 24);
  long fi = e / 24;
  int f = (int)(fi & 511);
  int bt = (int)(fi >> 9); int t = bt & 127, b = bt >> 7;
  union {int4 q; u16 u[8];} pk; pk.q = *(const int4*)(Y + e);
  union {int4 q; u16 u[8];} o;
  #pragma unroll
  for (int j=0;j<8;j++){
    float v = b2f(pk.u[j])*sA[c0+j] + sB[c0+j];
    o.u[j] = f2b(v>0.f?v:0.f);
  }
  *(int4*)(dst + ((long)(b*130 + t+1)*514 + (f+1))*72 + coff + c0) = o.q;
}

// ---------------- normalize+relu + NHWC->CHW transpose (inline GN params) ----------------
__global__ __launch_bounds__(256)
void norm_relu_chw(const u16* __restrict__ Y, u16* __restrict__ xr,
                   const float* __restrict__ raw, const float* __restrict__ gw,
                   const float* __restrict__ gb, float invN){
  __shared__ u16 sh[24][520];
  __shared__ float sA[24], sB[24];
  int t = blockIdx.x & 127, b = blockIdx.x >> 7;
  if (threadIdx.x < 24){
    int g = b*4 + threadIdx.x/6;
    float m = raw[g]*invN;
    float var = raw[16+g]*invN - m*m;
    float is = rsqrtf(var + EPS);
    float sc = is*gw[threadIdx.x];
    sA[threadIdx.x] = sc;
    sB[threadIdx.x] = gb[threadIdx.x] - m*sc;
  }
  __syncthreads();
  const u16* src = Y + ((long)(b*128+t))*12288;
  for (int i = threadIdx.x; i < 1536; i += 256){
    int e = i*8; int c0 = e % 24; int f = e / 24;
    union {int4 q; u16 u[8];} pk; pk.q = *(const int4*)(src + e);
    #pragma unroll
    for (int j=0;j<8;j++){
      float v = b2f(pk.u[j])*sA[c0+j] + sB[c0+j];
      sh[c0+j][f] = f2b(v>0.f?v:0.f);
    }
  }
  __syncthreads();
  for (int i = threadIdx.x; i < 1536; i += 256){
    int c = i >> 6, fq = (i & 63)*8;
    union {int4 q; u16 u[8];} o;
    #pragma unroll
    for (int j=0;j<8;j++) o.u[j] = sh[c][fq+j];
    *(int4*)(xr + ((long)((b*24+c)*128 + t))*512 + fq) = o.q;
  }
}

// ---------------- elementwise normalize+relu on CHW rows (h1), inline GN params ----------------
__global__ __launch_bounds__(256)
void norm_chw(u16* __restrict__ h, const float* __restrict__ raw,
              const float* __restrict__ gw, const float* __restrict__ gb, float invN){
  __shared__ float s_sc, s_off;
  int bc = blockIdx.x / 12;                 // block spans a single (b,c)
  if (threadIdx.x == 0){
    int b = bc/24, c = bc%24;
    int g = b*4 + c/6;
    float m = raw[g]*invN;
    float var = raw[16+g]*invN - m*m;
    float is = rsqrtf(var + EPS);
    float sc = is*gw[c];
    s_sc = sc;
    s_off = gb[c] - m*sc;
  }
  __syncthreads();
  float sc = s_sc, off = s_off;
  long e = ((long)blockIdx.x*256 + threadIdx.x)*8;
  union {int4 q; u16 u[8];} pk; pk.q = *(const int4*)(h + e);
  #pragma unroll
  for (int j=0;j<8;j++){ float v = b2f(pk.u[j])*sc + off; pk.u[j] = f2b(v>0.f?v:0.f); }
  *(int4*)(h + e) = pk.q;
}

// ---------------- gemm1: LDS-staged MFMA GEMM, depth-2 counted-vmcnt pipeline ----------------
template<int NF, bool STORE>
__global__ __launch_bounds__(256)
void gemm_lds(const u16* __restrict__ A, const u16* __restrict__ Bt, u16* __restrict__ C,
              int N, int K, int NBX, float* __restrict__ raw){
  constexpr int BN = NF*32;
  constexpr int BNP = BN + 4;
  constexpr int ABUF = 128*32;
  constexpr int BBUF = BN*32;
  __shared__ __align__(16) u16 SH[3*(ABUF+BBUF)];
  u16* Asb = SH;
  u16* Bsb = SH + 3*ABUF;
  int tid = threadIdx.x, wid = tid >> 6, l = tid & 63;
  int r = l & 15, q = l >> 4;
  int wr = wid >> 1, wc = wid & 1;
  int chunk = gridDim.x >> 3;
  int lin = (blockIdx.x & 7)*chunk + (blockIdx.x >> 3);
  int bx = lin % NBX, by = lin / NBX;
  long m0 = (long)by*128;
  int n0 = bx*BN;

  int arow[2], ach[2], aslot[2];
  #pragma unroll
  for (int j=0;j<2;j++){
    int idx = (wid*2+j)*64 + l;
    aslot[j] = idx*8;
    arow[j]  = ((idx>>6)<<4) | (idx & 15);
    ach[j]   = ((idx>>4) & 3)*8;
  }
  int brow[NF/2], bch[NF/2], bslot[NF/2];
  #pragma unroll
  for (int j=0;j<NF/2;j++){
    int idx = (wid*(NF/2)+j)*64 + l;
    bslot[j] = idx*8;
    brow[j]  = ((idx>>6)<<4) | (idx & 15);
    bch[j]   = ((idx>>4) & 3)*8;
  }

  f32x4 acc[4][NF];
  #pragma unroll
  for (int mf=0;mf<4;mf++)
    #pragma unroll
    for (int nf=0;nf<NF;nf++) acc[mf][nf] = (f32x4){0.f,0.f,0.f,0.f};

  int nt = K >> 5;
  #pragma unroll
  for (int j=0;j<2;j++)    gload16(A  + (m0+arow[j])*K + ach[j], Asb + aslot[j]);
  #pragma unroll
  for (int j=0;j<NF/2;j++) gload16(Bt + (long)(n0+brow[j])*K + bch[j], Bsb + bslot[j]);
  #pragma unroll
  for (int j=0;j<2;j++)    gload16(A  + (m0+arow[j])*K + 32 + ach[j], Asb + ABUF + aslot[j]);
  #pragma unroll
  for (int j=0;j<NF/2;j++) gload16(Bt + (long)(n0+brow[j])*K + 32 + bch[j], Bsb + BBUF + bslot[j]);

  int c0 = 0;
  for (int kt=0; kt<nt; kt++){
    if constexpr (NF==4) asm volatile("s_waitcnt vmcnt(4)" ::: "memory");
    else                 asm volatile("s_waitcnt vmcnt(3)" ::: "memory");
    __builtin_amdgcn_s_barrier();
    __builtin_amdgcn_sched_barrier(0);
    if (kt+2 < nt){
      int c2 = c0+2; if (c2>=3) c2-=3;
      int ko = (kt+2)*32;
      #pragma unroll
      for (int j=0;j<2;j++)    gload16(A  + (m0+arow[j])*K + ko + ach[j], Asb + c2*ABUF + aslot[j]);
      #pragma unroll
      for (int j=0;j<NF/2;j++) gload16(Bt + (long)(n0+brow[j])*K + ko + bch[j], Bsb + c2*BBUF + bslot[j]);
    }
    const u16* Ac = Asb + c0*ABUF;
    const u16* Bc = Bsb + c0*BBUF;
    bf16x8 af[4], bfv[NF];
    #pragma unroll
    for (int mf=0;mf<4;mf++) af[mf]  = *(const bf16x8*)(Ac + (((wr*4+mf)*4 + q)*16 + r)*8);
    #pragma unroll
    for (int nf=0;nf<NF;nf++) bfv[nf] = *(const bf16x8*)(Bc + (((wc*NF+nf)*4 + q)*16 + r)*8);
    #pragma unroll
    for (int mf=0;mf<4;mf++)
      #pragma unroll
      for (int nf=0;nf<NF;nf++)
        acc[mf][nf] = __builtin_amdgcn_mfma_f32_16x16x32_bf16(af[mf], bfv[nf], acc[mf][nf], 0,0,0);
    c0 = (c0+1==3) ? 0 : c0+1;
  }

  float s=0.f, ss=0.f;
  #pragma unroll
  for (int mf=0;mf<4;mf++)
    #pragma unroll
    for (int nf=0;nf<NF;nf++)
      #pragma unroll
      for (int j=0;j<4;j++){ float v = acc[mf][nf][j]; s += v; ss += v*v; }
  #pragma unroll
  for (int off=32; off>0; off>>=1){ s += __shfl_down(s,off,64); ss += __shfl_down(ss,off,64); }
  __shared__ float rs[4], rss[4];
  if (l==0){ rs[wid]=s; rss[wid]=ss; }
  __syncthreads();
  if (tid==0){
    int bc = (int)(m0 >> 7);
    int g = (bc/24)*4 + (bc%24)/6;
    atomicAdd(&raw[g],    rs[0]+rs[1]+rs[2]+rs[3]);
    atomicAdd(&raw[16+g], rss[0]+rss[1]+rss[2]+rss[3]);
  }

  if constexpr (STORE){
    #pragma unroll
    for (int mf=0;mf<4;mf++){
      int row = wr*64 + mf*16 + q*4;
      #pragma unroll
      for (int nf=0;nf<NF;nf++){
        int col = wc*(NF*16) + nf*16 + r;
        #pragma unroll
        for (int j=0;j<4;j++)
          SH[(row+j)*BNP + col] = f2b(acc[mf][nf][j]);
      }
    }
    __syncthreads();
    constexpr int RPT = BN/16;
    #pragma unroll
    for (int k=0;k<RPT;k++){
      int j = tid + k*256;
      int row = j / (BN/8), col8 = (j % (BN/8))*8;
      *(int4*)(C + (m0+row)*N + n0 + col8) = *(const int4*)(SH + row*BNP + col8);
    }
  }
}

// ---------------- gemm2 w8: 512 threads, 8 waves (2x4), tile 128x128, depth-2 vmcnt ring ----------------
// LDS 48KB -> 3 blocks/CU = 24 waves/CU. 1 A-load + 1 B-load per thread per K-step.
__global__ __launch_bounds__(512)
void gemm2_w8(const u16* __restrict__ A, const u16* __restrict__ Bt, u16* __restrict__ C,
              float* __restrict__ raw){
  const int K = 192, N = 3072;
  constexpr int SB = 128*32;                 // 4096 u16 per operand-buffer
  __shared__ __align__(16) u16 SH[6*SB];     // A ring [0..3SB), B ring [3SB..6SB); reused for repack
  __shared__ float rs[8], rss[8];
  u16* Asb = SH;
  u16* Bsb = SH + 3*SB;
  int tid = threadIdx.x, wid = tid >> 6, l = tid & 63;
  int r = l & 15, q = l >> 4;
  int wr = wid >> 2, wc = wid & 3;
  int chunk = gridDim.x >> 3;
  int lin = (blockIdx.x & 7)*chunk + (blockIdx.x >> 3);
  int bx = lin % 24, by = lin / 24;
  long m0 = (long)by*128;
  int n0 = bx*128;

  // staging coords: slot tid*8 <-> fragment [hi:8][q:4][r:16][e:8]
  int srow = ((tid>>6)<<4) | (tid & 15);
  int sch  = ((tid>>4) & 3)*8;
  int sslot = tid*8;

  f32x4 acc[4][2];
  #pragma unroll
  for (int mf=0;mf<4;mf++){ acc[mf][0] = (f32x4){0.f,0.f,0.f,0.f}; acc[mf][1] = (f32x4){0.f,0.f,0.f,0.f}; }

  // prologue: stage K-steps 0 and 1
  gload16(A  + (m0+srow)*K + sch,          Asb + sslot);
  gload16(Bt + (long)(n0+srow)*K + sch,    Bsb + sslot);
  gload16(A  + (m0+srow)*K + 32 + sch,     Asb + SB + sslot);
  gload16(Bt + (long)(n0+srow)*K + 32 + sch, Bsb + SB + sslot);

  int c0 = 0;
  for (int kt=0; kt<6; kt++){
    asm volatile("s_waitcnt vmcnt(2)" ::: "memory");   // stage(kt) done; stage(kt+1) in flight
    __builtin_amdgcn_s_barrier();
    __builtin_amdgcn_sched_barrier(0);
    if (kt+2 < 6){
      int c2 = c0+2; if (c2>=3) c2-=3;
      int ko = (kt+2)*32;
      gload16(A  + (m0+srow)*K + ko + sch,       Asb + c2*SB + sslot);
      gload16(Bt + (long)(n0+srow)*K + ko + sch, Bsb + c2*SB + sslot);
    }
    const u16* Ac = Asb + c0*SB;
    const u16* Bc = Bsb + c0*SB;
    bf16x8 af[4], bfv[2];
    #pragma unroll
    for (int mf=0;mf<4;mf++) af[mf]  = *(const bf16x8*)(Ac + (((wr*4+mf)*4 + q)*16 + r)*8);
    #pragma unroll
    for (int nf=0;nf<2;nf++) bfv[nf] = *(const bf16x8*)(Bc + (((wc*2+nf)*4 + q)*16 + r)*8);
    #pragma unroll
    for (int mf=0;mf<4;mf++){
      acc[mf][0] = __builtin_amdgcn_mfma_f32_16x16x32_bf16(af[mf], bfv[0], acc[mf][0], 0,0,0);
      acc[mf][1] = __builtin_amdgcn_mfma_f32_16x16x32_bf16(af[mf], bfv[1], acc[mf][1], 0,0,0);
    }
    c0 = (c0+1==3) ? 0 : c0+1;
  }

  // fused GN stats (block spans 128 rows = one (b,c) plane)
  float s=0.f, ss=0.f;
  #pragma unroll
  for (int mf=0;mf<4;mf++)
    #pragma unroll
    for (int nf=0;nf<2;nf++)
      #pragma unroll
      for (int j=0;j<4;j++){ float v = acc[mf][nf][j]; s += v; ss += v*v; }
  #pragma unroll
  for (int off=32; off>0; off>>=1){ s += __shfl_down(s,off,64); ss += __shfl_down(ss,off,64); }
  if (l==0){ rs[wid]=s; rss[wid]=ss; }
  __syncthreads();                 // also: all reads of SH done -> reusable for repack
  if (tid==0){
    float as=0, aq=0;
    #pragma unroll
    for (int j=0;j<8;j++){ as += rs[j]; aq += rss[j]; }
    int bc = (int)(m0 >> 7);
    int g = (bc/24)*4 + (bc%24)/6;
    atomicAdd(&raw[g], as);
    atomicAdd(&raw[16+g], aq);
  }

  // padded repack (stride 132) + coalesced int4 stores, 4 per thread
  #pragma unroll
  for (int mf=0;mf<4;mf++){
    int row = wr*64 + mf*16 + q*4;
    #pragma unroll
    for (int nf=0;nf<2;nf++){
      int col = wc*32 + nf*16 + r;
      #pragma unroll
      for (int j=0;j<4;j++)
        SH[(row+j)*132 + col] = f2b(acc[mf][nf][j]);
    }
  }
  __syncthreads();
  #pragma unroll
  for (int k=0;k<4;k++){
    int j = tid + k*512;
    int row = j >> 4, col8 = (j & 15)*8;
    *(int4*)(C + (m0+row)*N + n0 + col8) = *(const int4*)(SH + row*132 + col8);
  }
}

// ---------------- attention: att[4][6] (fp32) ----------------
__global__ void attention_kernel(const float* __restrict__ c, const float* __restrict__ wq,
                                 const float* __restrict__ bq, const float* __restrict__ keys,
                                 float* __restrict__ att){
  __shared__ float q[4][32];
  __shared__ float s[4][6];
  int t = threadIdx.x;
  if (t < 128){
    int b = t >> 5, k = t & 31;
    float a = bq[k];
    for (int j=0;j<32;j++) a += c[b*32+j] * wq[k*32+j];
    q[b][k] = a;
  }
  __syncthreads();
  if (t < 24){
    int b = t/6, n = t%6;
    float a = 0.f;
    for (int k=0;k<32;k++) a += q[b][k]*keys[k*6+n];
    s[b][n] = a * 0.17677669529663689f;
  }
  __syncthreads();
  if (t < 4){
    float mx = -1e30f;
    for (int n=0;n<6;n++) mx = fmaxf(mx, s[t][n]);
    float e[6], sm=0.f;
    for (int n=0;n<6;n++){ e[n]=expf(s[t][n]-mx); sm+=e[n]; }
    for (int n=0;n<6;n++) att[t*6+n] = e[n]/sm;
  }
}

// ---------------- final: out(fp32) = x_ + sum_n relu(gn2(h2))[...,n]*att[b,n] (inline GN) ----------------
__global__ __launch_bounds__(256)
void final_mix(const u16* __restrict__ h2, const u16* __restrict__ xr,
               const float* __restrict__ raw, const float* __restrict__ gw,
               const float* __restrict__ gb, float invN,
               const float* __restrict__ att, float* __restrict__ out){
  __shared__ float s_sc, s_off, s_att[6];
  int bc0 = blockIdx.x / 64;                // block spans single (b,c)
  int c  = bc0 % 24, b = bc0 / 24;
  if (threadIdx.x == 0){
    int g = b*4 + c/6;
    float m = raw[g]*invN;
    float var = raw[16+g]*invN - m*m;
    float is = rsqrtf(var + EPS);
    float sc = is*gw[c];
    s_sc = sc;
    s_off = gb[c] - m*sc;
  }
  if (threadIdx.x < 6) s_att[threadIdx.x] = att[b*6+threadIdx.x];
  __syncthreads();
  float sc = s_sc, off = s_off;
  float a[6];
  #pragma unroll
  for (int n=0;n<6;n++) a[n] = s_att[n];

  int gid = blockIdx.x*256 + threadIdx.x;
  int fq = gid & 127;
  int t  = (gid >> 7) & 127;
  int bc = gid >> 14;

  long hbase = (((long)bc*Tn + t))*3072 + (long)fq*24;
  union { int4 v[3]; u16 u[24]; } hv;
  const int4* hp = (const int4*)(h2 + hbase);
  hv.v[0]=hp[0]; hv.v[1]=hp[1]; hv.v[2]=hp[2];

  long xbase = (((long)bc*Tn + t))*Fn + (long)fq*4;
  union { unsigned long long q; u16 u[4]; } xv;
  xv.q = *(const unsigned long long*)(xr + xbase);

  float4 ov;
  float* op = &ov.x;
  #pragma unroll
  for (int j=0;j<4;j++){
    float accv = b2f(xv.u[j]);
    #pragma unroll
    for (int n=0;n<6;n++){
      float hvf = b2f(hv.u[j*6+n])*sc + off;
      hvf = hvf > 0.f ? hvf : 0.f;
      accv += hvf * a[n];
    }
    op[j] = accv;
  }
  *(float4*)(out + xbase) = ov;
}

extern "C" void kernel_launch(void* const* d_in, const int* in_sizes, int n_in,
                              void* d_out, int out_size, void* d_ws, size_t ws_size,
                              hipStream_t stream){
  const float* x   = (const float*)d_in[0];
  const float* c   = (const float*)d_in[1];
  const float* cw0 = (const float*)d_in[2];  const float* cb0 = (const float*)d_in[3];
  const float* gw0 = (const float*)d_in[4];  const float* gb0 = (const float*)d_in[5];
  const float* cw1 = (const float*)d_in[6];  const float* cb1 = (const float*)d_in[7];
  const float* gw1 = (const float*)d_in[8];  const float* gb1 = (const float*)d_in[9];
  const float* cw2 = (const float*)d_in[10]; const float* cb2 = (const float*)d_in[11];
  const float* gw2 = (const float*)d_in[12]; const float* gb2 = (const float*)d_in[13];
  const float* tw1 = (const float*)d_in[14]; const float* tg1w= (const float*)d_in[15]; const float* tg1b=(const float*)d_in[16];
  const float* tw2 = (const float*)d_in[17]; const float* tg2w= (const float*)d_in[18]; const float* tg2b=(const float*)d_in[19];
  const float* wqp = (const float*)d_in[20]; const float* bqp = (const float*)d_in[21]; const float* keys=(const float*)d_in[22];

  char* ws = (char*)d_ws;
  u16*   xr     = (u16*)(ws + 0);               // 12,582,912 B  [12288,512] bf16 CHW
  u16*   h1     = (u16*)(ws + 12582912);        //  4,718,592 B  [12288,192]
  u16*   tw1b   = (u16*)(ws + 17301504);        //    196,608 B
  u16*   tw2b   = (u16*)(ws + 17498112);        //  1,179,648 B
  float* stats5 = (float*)(ws + 18677760);      //        128 B
  float* att    = (float*)(ws + 18678656);      //        128 B
  // ---- h2 span (reused during conv phase) ----
  u16*   h2     = (u16*)(ws + 18680832);        // 75,497,472 B  [12288,3072]
  u16*   Y      = (u16*)(ws + 18680832);        // 12,582,912 B  NHWC conv out [4,128,512,24]
  u16*   b72p   = (u16*)(ws + 31263744);        // 38,488,320 B  NHWC padded [4,130,514,72]
  u16*   xc24   = (u16*)(ws + 69752064);        // 12,829,440 B (+256 slack) NHWC padded [4,130,514,24]
  float* stats14= (float*)(ws + 82581760);      //        512 B
  u16*   wr0    = (u16*)(ws + 82585344);        //     18,432 B
  u16*   wr1    = (u16*)(ws + 82603776);        //     36,864 B
  u16*   wr2    = (u16*)(ws + 82640640);        //     43,008 B

  border_zero<<<dim3(32,4),256,0,stream>>>(b72p, 72);
  border_zero<<<dim3(16,4),256,0,stream>>>(xc24, 24);
  zero_stats2<<<1,256,0,stream>>>(stats14, stats5);

  prep_wr<<<36,256,0,stream>>>(cw0, wr0, 24, 24, 0, 96);
  prep_wr<<<72,256,0,stream>>>(cw1, wr1, 48, 72, 24, 192);
  prep_wr<<<84,256,0,stream>>>(cw2, wr2, 72, 72, 0, 224);
  cvt_f2b<<<96,256,0,stream>>>(tw1, tw1b);
  cvt_f2b<<<576,256,0,stream>>>(tw2, tw2b);
  copy_x2<<<512,256,0,stream>>>(x, b72p, xc24);
  attention_kernel<<<1,128,0,stream>>>(c, wqp, bqp, keys, att);

  // ---- conv block 0 ----
  conv_mfma<96,24><<<512,256,0,stream>>>(xc24, 0, wr0, cb0, Y, stats14+0);
  norm_relu_nhwc<<<3072,256,0,stream>>>(Y, b72p, 24, stats14+0, gw0, gb0, 1.f/393216.f);

  // ---- conv block 1 ----
  conv_mfma<192,72><<<512,256,0,stream>>>(b72p, 24, wr1, cb1, Y, stats14+32);
  norm_relu_nhwc<<<3072,256,0,stream>>>(Y, b72p, 0, stats14+32, gw1, gb1, 1.f/393216.f);

  // ---- conv block 2 -> xr (CHW) ----
  conv_mfma<224,72><<<512,256,0,stream>>>(b72p, 0, wr2, cb2, Y, stats14+64);
  norm_relu_chw<<<512,256,0,stream>>>(Y, xr, stats14+64, gw2, gb2, 1.f/393216.f);

  // ---- TDF: gemm1 (12288x192x512) + GN + relu ----
  gemm_lds<2,true><<<288,256,0,stream>>>(xr, tw1b, h1, 192, 512, 3, stats14+96);
  norm_chw<<<1152,256,0,stream>>>(h1, stats14+96, tg1w, tg1b, 1.f/147456.f);

  // ---- TDF: gemm2 (12288x3072x192), 8-wave 128x128 ----
  gemm2_w8<<<2304,512,0,stream>>>(h1, tw2b, h2, stats5);

  // ---- final mix (inline GN2 params) ----
  final_mix<<<6144,256,0,stream>>>(h2, xr, stats5, tg2w, tg2b, 1.f/2359296.f, att, (float*)d_out);
}

// Round 18
// 208.432 us; speedup vs baseline: 1.1790x; 1.1045x over previous
//
#include <hip/hip_runtime.h>
#include <hip/hip_bf16.h>

typedef unsigned short u16;
typedef unsigned int u32;

#define Tn 128
#define Fn 512
#define HWc (Tn*Fn)
#define EPS 1e-5f

using bf16x8 = __attribute__((ext_vector_type(8))) short;
using f32x4  = __attribute__((ext_vector_type(4))) float;

__device__ __forceinline__ float b2f(u16 x){ return __uint_as_float(((u32)x)<<16); }
__device__ __forceinline__ u16 f2b(float f){
  __hip_bfloat16 h = __float2bfloat16(f);
  return *reinterpret_cast<u16*>(&h);
}

// async global->LDS, 16B per lane
__device__ __forceinline__ void gload16(const u16* g, u16* l){
  __builtin_amdgcn_global_load_lds((const __attribute__((address_space(1))) void*)g,
                                   (__attribute__((address_space(3))) void*)l, 16, 0, 0);
}

// ---------------- prep_all: fused prologue (10 kernels -> 1 launch) ----------------
// grid 1570:
// [0,512)     copy_x2
// [512,1088)  cvt tw2 (576)
// [1088,1184) cvt tw1 (96)
// [1184,1312) border b72p (128)
// [1312,1376) border xc24 (64)
// [1376,1412) prep_wr0 (36)
// [1412,1484) prep_wr1 (72)
// [1484,1568) prep_wr2 (84)
// 1568        zero stats
// 1569        attention
__global__ __launch_bounds__(256)
void prep_all(const float* __restrict__ x, u16* __restrict__ b72p, u16* __restrict__ xc24,
              const float* __restrict__ tw1, u16* __restrict__ tw1b,
              const float* __restrict__ tw2, u16* __restrict__ tw2b,
              const float* __restrict__ cw0, u16* __restrict__ wr0,
              const float* __restrict__ cw1, u16* __restrict__ wr1,
              const float* __restrict__ cw2, u16* __restrict__ wr2,
              float* __restrict__ stats14, float* __restrict__ stats5,
              const float* __restrict__ cc, const float* __restrict__ wq,
              const float* __restrict__ bq, const float* __restrict__ keys,
              float* __restrict__ att){
  __shared__ __align__(16) char smem[24*520*2];
  int bid = blockIdx.x, tid = threadIdx.x;

  if (bid < 512){
    // ---- copy_x2 ----
    u16 (*sh)[520] = (u16(*)[520])smem;
    int t = bid & 127, b = bid >> 7;
    const float* src = x + ((long)(b*24)*128 + t)*512;
    for (int c=0; c<24; c++){
      float2 v = *(const float2*)(src + (long)c*65536 + tid*2);
      sh[c][tid*2]   = f2b(v.x);
      sh[c][tid*2+1] = f2b(v.y);
    }
    __syncthreads();
    long r72 = ((long)(b*130 + t+1))*514*72;
    long r24 = ((long)(b*130 + t+1))*514*24;
    for (int i = tid; i < 1536; i += 256){
      int f = i/3, c0 = (i%3)*8;
      union {int4 q; u16 u[8];} o;
      #pragma unroll
      for (int j=0;j<8;j++) o.u[j] = sh[c0+j][f];
      *(int4*)(b72p + r72 + (long)(f+1)*72 + 48 + c0) = o.q;
      *(int4*)(xc24 + r24 + (long)(f+1)*24 + c0) = o.q;
    }
  } else if (bid < 1088){
    // ---- cvt tw2 ----
    int i = ((bid-512)*256 + tid)*4;
    float4 v = *(const float4*)(tw2 + i);
    ushort4 o;
    o.x=f2b(v.x); o.y=f2b(v.y); o.z=f2b(v.z); o.w=f2b(v.w);
    *(ushort4*)(tw2b + i) = o;
  } else if (bid < 1184){
    // ---- cvt tw1 ----
    int i = ((bid-1088)*256 + tid)*4;
    float4 v = *(const float4*)(tw1 + i);
    ushort4 o;
    o.x=f2b(v.x); o.y=f2b(v.y); o.z=f2b(v.z); o.w=f2b(v.w);
    *(ushort4*)(tw1b + i) = o;
  } else if (bid < 1312){
    // ---- border zero b72p (CS=72) ----
    int sub = bid - 1184;
    int b = sub >> 5, j = sub & 31;
    u16* base = b72p + (long)b*130*514*72;
    int rowN = 514*72;
    for (int i = j*256 + tid; i < rowN; i += 32*256){
      base[i] = 0;
      base[(long)129*rowN + i] = 0;
    }
    int colN = 128*72;
    for (int i = j*256 + tid; i < colN; i += 32*256){
      int row = 1 + i/72, ch = i - (i/72)*72;
      base[((long)row*514 + 0)*72 + ch] = 0;
      base[((long)row*514 + 513)*72 + ch] = 0;
    }
  } else if (bid < 1376){
    // ---- border zero xc24 (CS=24) ----
    int sub = bid - 1312;
    int b = sub >> 4, j = sub & 15;
    u16* base = xc24 + (long)b*130*514*24;
    int rowN = 514*24;
    for (int i = j*256 + tid; i < rowN; i += 16*256){
      base[i] = 0;
      base[(long)129*rowN + i] = 0;
    }
    int colN = 128*24;
    for (int i = j*256 + tid; i < colN; i += 16*256){
      int row = 1 + i/24, ch = i - (i/24)*24;
      base[((long)row*514 + 0)*24 + ch] = 0;
      base[((long)row*514 + 513)*24 + ch] = 0;
    }
  } else if (bid < 1568){
    // ---- prep_wr 0/1/2 (fragment order wr[dt][NK][q:4][h:2][r:16][8]) ----
    const float* w; u16* wr; int CIN, cs, cof, KP, sub;
    if (bid < 1412){ sub = bid-1376; w = cw0; wr = wr0; CIN=24; cs=24; cof=0;  KP=96;  }
    else if (bid < 1484){ sub = bid-1412; w = cw1; wr = wr1; CIN=48; cs=72; cof=24; KP=192; }
    else { sub = bid-1484; w = cw2; wr = wr2; CIN=72; cs=72; cof=0;  KP=224; }
    int i = sub*256 + tid;
    int tot = 96*KP;
    if (i < tot){
      int e  = i & 7;
      int r  = (i >> 3) & 15;
      int h  = (i >> 7) & 1;
      int q  = (i >> 8) & 3;
      int rest = i >> 10;
      int NK = KP >> 5;
      int ks = rest % NK, dt = rest / NK;
      int o = h*16 + r;
      int k = ks*32 + q*8 + e;
      float v = 0.f;
      int g = cof + k, df = g/cs, ch = g - df*cs;
      if (o < 24 && df < 3 && ch >= cof && ch < cof+CIN)
        v = w[((o*CIN + (ch-cof))*3 + dt)*3 + df];
      wr[i] = f2b(v);
    }
  } else if (bid == 1568){
    if (tid < 128) stats14[tid] = 0.f;
    else if (tid < 160) stats5[tid-128] = 0.f;
  } else {
    // ---- attention ----
    float (*qs)[32] = (float(*)[32])smem;
    float (*ss)[6]  = (float(*)[6])(smem + 4*32*4);
    int t = tid;
    if (t < 128){
      int b = t >> 5, k = t & 31;
      float a = bq[k];
      for (int j=0;j<32;j++) a += cc[b*32+j] * wq[k*32+j];
      qs[b][k] = a;
    }
    __syncthreads();
    if (t < 24){
      int b = t/6, n = t%6;
      float a = 0.f;
      for (int k=0;k<32;k++) a += qs[b][k]*keys[k*6+n];
      ss[b][n] = a * 0.17677669529663689f;
    }
    __syncthreads();
    if (t < 4){
      float mx = -1e30f;
      for (int n=0;n<6;n++) mx = fmaxf(mx, ss[t][n]);
      float e[6], sm=0.f;
      for (int n=0;n<6;n++){ e[n]=expf(ss[t][n]-mx); sm+=e[n]; }
      for (int n=0;n<6;n++) att[t*6+n] = e[n]/sm;
    }
  }
}

// ---------------- MFMA implicit-GEMM 3x3 conv v6 (r13 known-good) ----------------
template<int KP, int CS>
__global__ __launch_bounds__(256)
void conv_mfma(const u16* __restrict__ X, int coff, const u16* __restrict__ WR,
               const float* __restrict__ bias, u16* __restrict__ Y,
               float* __restrict__ raw){
  constexpr int NK = KP/32;
  __shared__ u16 WS[3*32*KP];
  __shared__ float ssum[4][32], ssq[4][32];
  __shared__ float g24s[24], g24q[24];
  __shared__ __align__(16) u16 Ysh[128*24];
  int bid = (blockIdx.x & 7)*64 + (blockIdx.x >> 3);   // grid 512, chunk 64
  int b = bid >> 7, t = bid & 127;
  int tid = threadIdx.x, wid = tid >> 6, l = tid & 63;
  int r = l & 15, q = l >> 4;

  for (int i = tid*8; i < 3*32*KP; i += 2048)
    *(int4*)(WS + i) = *(const int4*)(WR + i);

  float bv0 = bias[r];
  float bv1 = (r < 8) ? bias[16+r] : 0.f;
  float s0=0,q0=0,s1=0,q1=0;
  __syncthreads();

  #pragma unroll
  for (int fi=0; fi<4; fi++){
    int f0w = fi*128 + wid*32;
    f32x4 acc[2][2] = {};
    #pragma unroll
    for (int dt=0; dt<3; dt++){
      const u16* Ab = X + ((long)((b*130 + t+dt)*514 + f0w + r))*CS + coff + q*8;
      bf16x8 a[2][NK];
      #pragma unroll
      for (int ks=0; ks<NK; ks++){
        a[0][ks] = *(const bf16x8*)(Ab + ks*32);
        a[1][ks] = *(const bf16x8*)(Ab + (long)16*CS + ks*32);
      }
      #pragma unroll
      for (int ks=0; ks<NK; ks++){
        const u16* Bb = WS + ((dt*NK + ks)*4 + q)*256 + r*8;
        bf16x8 b0 = *(const bf16x8*)(Bb);
        bf16x8 b1 = *(const bf16x8*)(Bb + 128);
        acc[0][0] = __builtin_amdgcn_mfma_f32_16x16x32_bf16(a[0][ks],b0,acc[0][0],0,0,0);
        acc[0][1] = __builtin_amdgcn_mfma_f32_16x16x32_bf16(a[0][ks],b1,acc[0][1],0,0,0);
        acc[1][0] = __builtin_amdgcn_mfma_f32_16x16x32_bf16(a[1][ks],b0,acc[1][0],0,0,0);
        acc[1][1] = __builtin_amdgcn_mfma_f32_16x16x32_bf16(a[1][ks],b1,acc[1][1],0,0,0);
      }
    }
    #pragma unroll
    for (int m=0;m<2;m++){
      #pragma unroll
      for (int j=0;j<4;j++){
        acc[m][0][j] += bv0; acc[m][1][j] += bv1;
        s0 += acc[m][0][j]; q0 += acc[m][0][j]*acc[m][0][j];
        s1 += acc[m][1][j]; q1 += acc[m][1][j]*acc[m][1][j];
      }
    }
    __syncthreads();
    #pragma unroll
    for (int m=0;m<2;m++){
      int fr = wid*32 + m*16 + q*4;
      #pragma unroll
      for (int j=0;j<4;j++){
        Ysh[(fr+j)*24 + r] = f2b(acc[m][0][j]);
        if (r < 8) Ysh[(fr+j)*24 + 16 + r] = f2b(acc[m][1][j]);
      }
    }
    __syncthreads();
    long Yb = ((long)((b*128 + t)*512) + fi*128)*24;
    const int4* sp = (const int4*)Ysh;
    for (int i = tid; i < 384; i += 256)
      *(int4*)(Y + Yb + (long)i*8) = sp[i];
  }

  #pragma unroll
  for (int off=16; off<=32; off<<=1){
    s0 += __shfl_xor(s0, off, 64); q0 += __shfl_xor(q0, off, 64);
    s1 += __shfl_xor(s1, off, 64); q1 += __shfl_xor(q1, off, 64);
  }
  if (q == 0){
    ssum[wid][r] = s0;     ssq[wid][r] = q0;
    ssum[wid][16+r] = s1;  ssq[wid][16+r] = q1;
  }
  __syncthreads();
  if (tid < 24){
    g24s[tid] = ssum[0][tid]+ssum[1][tid]+ssum[2][tid]+ssum[3][tid];
    g24q[tid] = ssq[0][tid]+ssq[1][tid]+ssq[2][tid]+ssq[3][tid];
  }
  __syncthreads();
  if (tid < 4){
    float as=0, aq=0;
    #pragma unroll
    for (int j=0;j<6;j++){ as += g24s[tid*6+j]; aq += g24q[tid*6+j]; }
    atomicAdd(&raw[b*4+tid], as);
    atomicAdd(&raw[16+b*4+tid], aq);
  }
}

// ---------------- normalize+relu: Y NHWC -> b72p channel slice (inline GN params) ----------------
__global__ __launch_bounds__(256)
void norm_relu_nhwc(const u16* __restrict__ Y, u16* __restrict__ dst, int coff,
                    const float* __restrict__ raw, const float* __restrict__ gw,
                    const float* __restrict__ gb, float invN){
  __shared__ float sA[24], sB[24];
  int bb = blockIdx.x / 768;                 // block spans a single batch b
  if (threadIdx.x < 24){
    int g = bb*4 + threadIdx.x/6;
    float m = raw[g]*invN;
    float var = raw[16+g]*invN - m*m;
    float is = rsqrtf(var + EPS);
    float sc = is*gw[threadIdx.x];
    sA[threadIdx.x] = sc;
    sB[threadIdx.x] = gb[threadIdx.x] - m*sc;
  }
  __syncthreads();
  long e = ((long)blockIdx.x*256 + threadIdx.x)*8;
  int c0 = (int)(e % 24);
  long fi = e / 24;
  int f = (int)(fi & 511);
  int bt = (int)(fi >> 9); int t = bt & 127, b = bt >> 7;
  union {int4 q; u16 u[8];} pk; pk.q = *(const int4*)(Y + e);
  union {int4 q; u16 u[8];} o;
  #pragma unroll
  for (int j=0;j<8;j++){
    float v = b2f(pk.u[j])*sA[c0+j] + sB[c0+j];
    o.u[j] = f2b(v>0.f?v:0.f);
  }
  *(int4*)(dst + ((long)(b*130 + t+1)*514 + (f+1))*72 + coff + c0) = o.q;
}

// ---------------- normalize+relu + NHWC->CHW transpose (inline GN params) ----------------
__global__ __launch_bounds__(256)
void norm_relu_chw(const u16* __restrict__ Y, u16* __restrict__ xr,
                   const float* __restrict__ raw, const float* __restrict__ gw,
                   const float* __restrict__ gb, float invN){
  __shared__ u16 sh[24][520];
  __shared__ float sA[24], sB[24];
  int t = blockIdx.x & 127, b = blockIdx.x >> 7;
  if (threadIdx.x < 24){
    int g = b*4 + threadIdx.x/6;
    float m = raw[g]*invN;
    float var = raw[16+g]*invN - m*m;
    float is = rsqrtf(var + EPS);
    float sc = is*gw[threadIdx.x];
    sA[threadIdx.x] = sc;
    sB[threadIdx.x] = gb[threadIdx.x] - m*sc;
  }
  __syncthreads();
  const u16* src = Y + ((long)(b*128+t))*12288;
  for (int i = threadIdx.x; i < 1536; i += 256){
    int e = i*8; int c0 = e % 24; int f = e / 24;
    union {int4 q; u16 u[8];} pk; pk.q = *(const int4*)(src + e);
    #pragma unroll
    for (int j=0;j<8;j++){
      float v = b2f(pk.u[j])*sA[c0+j] + sB[c0+j];
      sh[c0+j][f] = f2b(v>0.f?v:0.f);
    }
  }
  __syncthreads();
  for (int i = threadIdx.x; i < 1536; i += 256){
    int c = i >> 6, fq = (i & 63)*8;
    union {int4 q; u16 u[8];} o;
    #pragma unroll
    for (int j=0;j<8;j++) o.u[j] = sh[c][fq+j];
    *(int4*)(xr + ((long)((b*24+c)*128 + t))*512 + fq) = o.q;
  }
}

// ---------------- elementwise normalize+relu on CHW rows (h1), inline GN params ----------------
__global__ __launch_bounds__(256)
void norm_chw(u16* __restrict__ h, const float* __restrict__ raw,
              const float* __restrict__ gw, const float* __restrict__ gb, float invN){
  __shared__ float s_sc, s_off;
  int bc = blockIdx.x / 12;                 // block spans a single (b,c)
  if (threadIdx.x == 0){
    int b = bc/24, c = bc%24;
    int g = b*4 + c/6;
    float m = raw[g]*invN;
    float var = raw[16+g]*invN - m*m;
    float is = rsqrtf(var + EPS);
    float sc = is*gw[c];
    s_sc = sc;
    s_off = gb[c] - m*sc;
  }
  __syncthreads();
  float sc = s_sc, off = s_off;
  long e = ((long)blockIdx.x*256 + threadIdx.x)*8;
  union {int4 q; u16 u[8];} pk; pk.q = *(const int4*)(h + e);
  #pragma unroll
  for (int j=0;j<8;j++){ float v = b2f(pk.u[j])*sc + off; pk.u[j] = f2b(v>0.f?v:0.f); }
  *(int4*)(h + e) = pk.q;
}

// ---------------- gemm1: LDS-staged MFMA GEMM, depth-2 counted-vmcnt pipeline ----------------
template<int NF, bool STORE>
__global__ __launch_bounds__(256)
void gemm_lds(const u16* __restrict__ A, const u16* __restrict__ Bt, u16* __restrict__ C,
              int N, int K, int NBX, float* __restrict__ raw){
  constexpr int BN = NF*32;
  constexpr int BNP = BN + 4;
  constexpr int ABUF = 128*32;
  constexpr int BBUF = BN*32;
  __shared__ __align__(16) u16 SH[3*(ABUF+BBUF)];
  u16* Asb = SH;
  u16* Bsb = SH + 3*ABUF;
  int tid = threadIdx.x, wid = tid >> 6, l = tid & 63;
  int r = l & 15, q = l >> 4;
  int wr = wid >> 1, wc = wid & 1;
  int chunk = gridDim.x >> 3;
  int lin = (blockIdx.x & 7)*chunk + (blockIdx.x >> 3);
  int bx = lin % NBX, by = lin / NBX;
  long m0 = (long)by*128;
  int n0 = bx*BN;

  int arow[2], ach[2], aslot[2];
  #pragma unroll
  for (int j=0;j<2;j++){
    int idx = (wid*2+j)*64 + l;
    aslot[j] = idx*8;
    arow[j]  = ((idx>>6)<<4) | (idx & 15);
    ach[j]   = ((idx>>4) & 3)*8;
  }
  int brow[NF/2], bch[NF/2], bslot[NF/2];
  #pragma unroll
  for (int j=0;j<NF/2;j++){
    int idx = (wid*(NF/2)+j)*64 + l;
    bslot[j] = idx*8;
    brow[j]  = ((idx>>6)<<4) | (idx & 15);
    bch[j]   = ((idx>>4) & 3)*8;
  }

  f32x4 acc[4][NF];
  #pragma unroll
  for (int mf=0;mf<4;mf++)
    #pragma unroll
    for (int nf=0;nf<NF;nf++) acc[mf][nf] = (f32x4){0.f,0.f,0.f,0.f};

  int nt = K >> 5;
  #pragma unroll
  for (int j=0;j<2;j++)    gload16(A  + (m0+arow[j])*K + ach[j], Asb + aslot[j]);
  #pragma unroll
  for (int j=0;j<NF/2;j++) gload16(Bt + (long)(n0+brow[j])*K + bch[j], Bsb + bslot[j]);
  #pragma unroll
  for (int j=0;j<2;j++)    gload16(A  + (m0+arow[j])*K + 32 + ach[j], Asb + ABUF + aslot[j]);
  #pragma unroll
  for (int j=0;j<NF/2;j++) gload16(Bt + (long)(n0+brow[j])*K + 32 + bch[j], Bsb + BBUF + bslot[j]);

  int c0 = 0;
  for (int kt=0; kt<nt; kt++){
    if constexpr (NF==4) asm volatile("s_waitcnt vmcnt(4)" ::: "memory");
    else                 asm volatile("s_waitcnt vmcnt(3)" ::: "memory");
    __builtin_amdgcn_s_barrier();
    __builtin_amdgcn_sched_barrier(0);
    if (kt+2 < nt){
      int c2 = c0+2; if (c2>=3) c2-=3;
      int ko = (kt+2)*32;
      #pragma unroll
      for (int j=0;j<2;j++)    gload16(A  + (m0+arow[j])*K + ko + ach[j], Asb + c2*ABUF + aslot[j]);
      #pragma unroll
      for (int j=0;j<NF/2;j++) gload16(Bt + (long)(n0+brow[j])*K + ko + bch[j], Bsb + c2*BBUF + bslot[j]);
    }
    const u16* Ac = Asb + c0*ABUF;
    const u16* Bc = Bsb + c0*BBUF;
    bf16x8 af[4], bfv[NF];
    #pragma unroll
    for (int mf=0;mf<4;mf++) af[mf]  = *(const bf16x8*)(Ac + (((wr*4+mf)*4 + q)*16 + r)*8);
    #pragma unroll
    for (int nf=0;nf<NF;nf++) bfv[nf] = *(const bf16x8*)(Bc + (((wc*NF+nf)*4 + q)*16 + r)*8);
    #pragma unroll
    for (int mf=0;mf<4;mf++)
      #pragma unroll
      for (int nf=0;nf<NF;nf++)
        acc[mf][nf] = __builtin_amdgcn_mfma_f32_16x16x32_bf16(af[mf], bfv[nf], acc[mf][nf], 0,0,0);
    c0 = (c0+1==3) ? 0 : c0+1;
  }

  float s=0.f, ss=0.f;
  #pragma unroll
  for (int mf=0;mf<4;mf++)
    #pragma unroll
    for (int nf=0;nf<NF;nf++)
      #pragma unroll
      for (int j=0;j<4;j++){ float v = acc[mf][nf][j]; s += v; ss += v*v; }
  #pragma unroll
  for (int off=32; off>0; off>>=1){ s += __shfl_down(s,off,64); ss += __shfl_down(ss,off,64); }
  __shared__ float rs[4], rss[4];
  if (l==0){ rs[wid]=s; rss[wid]=ss; }
  __syncthreads();
  if (tid==0){
    int bc = (int)(m0 >> 7);
    int g = (bc/24)*4 + (bc%24)/6;
    atomicAdd(&raw[g],    rs[0]+rs[1]+rs[2]+rs[3]);
    atomicAdd(&raw[16+g], rss[0]+rss[1]+rss[2]+rss[3]);
  }

  if constexpr (STORE){
    #pragma unroll
    for (int mf=0;mf<4;mf++){
      int row = wr*64 + mf*16 + q*4;
      #pragma unroll
      for (int nf=0;nf<NF;nf++){
        int col = wc*(NF*16) + nf*16 + r;
        #pragma unroll
        for (int j=0;j<4;j++)
          SH[(row+j)*BNP + col] = f2b(acc[mf][nf][j]);
      }
    }
    __syncthreads();
    constexpr int RPT = BN/16;
    #pragma unroll
    for (int k=0;k<RPT;k++){
      int j = tid + k*256;
      int row = j / (BN/8), col8 = (j % (BN/8))*8;
      *(int4*)(C + (m0+row)*N + n0 + col8) = *(const int4*)(SH + row*BNP + col8);
    }
  }
}

// ---------------- gemm2 w8: 512 threads, 8 waves (2x4), tile 128x128, depth-2 vmcnt ring ----------------
__global__ __launch_bounds__(512)
void gemm2_w8(const u16* __restrict__ A, const u16* __restrict__ Bt, u16* __restrict__ C,
              float* __restrict__ raw){
  const int K = 192, N = 3072;
  constexpr int SB = 128*32;
  __shared__ __align__(16) u16 SH[6*SB];
  __shared__ float rs[8], rss[8];
  u16* Asb = SH;
  u16* Bsb = SH + 3*SB;
  int tid = threadIdx.x, wid = tid >> 6, l = tid & 63;
  int r = l & 15, q = l >> 4;
  int wr = wid >> 2, wc = wid & 3;
  int chunk = gridDim.x >> 3;
  int lin = (blockIdx.x & 7)*chunk + (blockIdx.x >> 3);
  int bx = lin % 24, by = lin / 24;
  long m0 = (long)by*128;
  int n0 = bx*128;

  int srow = ((tid>>6)<<4) | (tid & 15);
  int sch  = ((tid>>4) & 3)*8;
  int sslot = tid*8;

  f32x4 acc[4][2];
  #pragma unroll
  for (int mf=0;mf<4;mf++){ acc[mf][0] = (f32x4){0.f,0.f,0.f,0.f}; acc[mf][1] = (f32x4){0.f,0.f,0.f,0.f}; }

  gload16(A  + (m0+srow)*K + sch,          Asb + sslot);
  gload16(Bt + (long)(n0+srow)*K + sch,    Bsb + sslot);
  gload16(A  + (m0+srow)*K + 32 + sch,     Asb + SB + sslot);
  gload16(Bt + (long)(n0+srow)*K + 32 + sch, Bsb + SB + sslot);

  int c0 = 0;
  for (int kt=0; kt<6; kt++){
    asm volatile("s_waitcnt vmcnt(2)" ::: "memory");
    __builtin_amdgcn_s_barrier();
    __builtin_amdgcn_sched_barrier(0);
    if (kt+2 < 6){
      int c2 = c0+2; if (c2>=3) c2-=3;
      int ko = (kt+2)*32;
      gload16(A  + (m0+srow)*K + ko + sch,       Asb + c2*SB + sslot);
      gload16(Bt + (long)(n0+srow)*K + ko + sch, Bsb + c2*SB + sslot);
    }
    const u16* Ac = Asb + c0*SB;
    const u16* Bc = Bsb + c0*SB;
    bf16x8 af[4], bfv[2];
    #pragma unroll
    for (int mf=0;mf<4;mf++) af[mf]  = *(const bf16x8*)(Ac + (((wr*4+mf)*4 + q)*16 + r)*8);
    #pragma unroll
    for (int nf=0;nf<2;nf++) bfv[nf] = *(const bf16x8*)(Bc + (((wc*2+nf)*4 + q)*16 + r)*8);
    #pragma unroll
    for (int mf=0;mf<4;mf++){
      acc[mf][0] = __builtin_amdgcn_mfma_f32_16x16x32_bf16(af[mf], bfv[0], acc[mf][0], 0,0,0);
      acc[mf][1] = __builtin_amdgcn_mfma_f32_16x16x32_bf16(af[mf], bfv[1], acc[mf][1], 0,0,0);
    }
    c0 = (c0+1==3) ? 0 : c0+1;
  }

  float s=0.f, ss=0.f;
  #pragma unroll
  for (int mf=0;mf<4;mf++)
    #pragma unroll
    for (int nf=0;nf<2;nf++)
      #pragma unroll
      for (int j=0;j<4;j++){ float v = acc[mf][nf][j]; s += v; ss += v*v; }
  #pragma unroll
  for (int off=32; off>0; off>>=1){ s += __shfl_down(s,off,64); ss += __shfl_down(ss,off,64); }
  if (l==0){ rs[wid]=s; rss[wid]=ss; }
  __syncthreads();
  if (tid==0){
    float as=0, aq=0;
    #pragma unroll
    for (int j=0;j<8;j++){ as += rs[j]; aq += rss[j]; }
    int bc = (int)(m0 >> 7);
    int g = (bc/24)*4 + (bc%24)/6;
    atomicAdd(&raw[g], as);
    atomicAdd(&raw[16+g], aq);
  }

  #pragma unroll
  for (int mf=0;mf<4;mf++){
    int row = wr*64 + mf*16 + q*4;
    #pragma unroll
    for (int nf=0;nf<2;nf++){
      int col = wc*32 + nf*16 + r;
      #pragma unroll
      for (int j=0;j<4;j++)
        SH[(row+j)*132 + col] = f2b(acc[mf][nf][j]);
    }
  }
  __syncthreads();
  #pragma unroll
  for (int k=0;k<4;k++){
    int j = tid + k*512;
    int row = j >> 4, col8 = (j & 15)*8;
    *(int4*)(C + (m0+row)*N + n0 + col8) = *(const int4*)(SH + row*132 + col8);
  }
}

// ---------------- final: out(fp32) = x_ + sum_n relu(gn2(h2))[...,n]*att[b,n] (inline GN) ----------------
__global__ __launch_bounds__(256)
void final_mix(const u16* __restrict__ h2, const u16* __restrict__ xr,
               const float* __restrict__ raw, const float* __restrict__ gw,
               const float* __restrict__ gb, float invN,
               const float* __restrict__ att, float* __restrict__ out){
  __shared__ float s_sc, s_off, s_att[6];
  int bc0 = blockIdx.x / 64;                // block spans single (b,c)
  int c  = bc0 % 24, b = bc0 / 24;
  if (threadIdx.x == 0){
    int g = b*4 + c/6;
    float m = raw[g]*invN;
    float var = raw[16+g]*invN - m*m;
    float is = rsqrtf(var + EPS);
    float sc = is*gw[c];
    s_sc = sc;
    s_off = gb[c] - m*sc;
  }
  if (threadIdx.x < 6) s_att[threadIdx.x] = att[b*6+threadIdx.x];
  __syncthreads();
  float sc = s_sc, off = s_off;
  float a[6];
  #pragma unroll
  for (int n=0;n<6;n++) a[n] = s_att[n];

  int gid = blockIdx.x*256 + threadIdx.x;
  int fq = gid & 127;
  int t  = (gid >> 7) & 127;
  int bc = gid >> 14;

  long hbase = (((long)bc*Tn + t))*3072 + (long)fq*24;
  union { int4 v[3]; u16 u[24]; } hv;
  const int4* hp = (const int4*)(h2 + hbase);
  hv.v[0]=hp[0]; hv.v[1]=hp[1]; hv.v[2]=hp[2];

  long xbase = (((long)bc*Tn + t))*Fn + (long)fq*4;
  union { unsigned long long q; u16 u[4]; } xv;
  xv.q = *(const unsigned long long*)(xr + xbase);

  float4 ov;
  float* op = &ov.x;
  #pragma unroll
  for (int j=0;j<4;j++){
    float accv = b2f(xv.u[j]);
    #pragma unroll
    for (int n=0;n<6;n++){
      float hvf = b2f(hv.u[j*6+n])*sc + off;
      hvf = hvf > 0.f ? hvf : 0.f;
      accv += hvf * a[n];
    }
    op[j] = accv;
  }
  *(float4*)(out + xbase) = ov;
}

extern "C" void kernel_launch(void* const* d_in, const int* in_sizes, int n_in,
                              void* d_out, int out_size, void* d_ws, size_t ws_size,
                              hipStream_t stream){
  const float* x   = (const float*)d_in[0];
  const float* c   = (const float*)d_in[1];
  const float* cw0 = (const float*)d_in[2];  const float* cb0 = (const float*)d_in[3];
  const float* gw0 = (const float*)d_in[4];  const float* gb0 = (const float*)d_in[5];
  const float* cw1 = (const float*)d_in[6];  const float* cb1 = (const float*)d_in[7];
  const float* gw1 = (const float*)d_in[8];  const float* gb1 = (const float*)d_in[9];
  const float* cw2 = (const float*)d_in[10]; const float* cb2 = (const float*)d_in[11];
  const float* gw2 = (const float*)d_in[12]; const float* gb2 = (const float*)d_in[13];
  const float* tw1 = (const float*)d_in[14]; const float* tg1w= (const float*)d_in[15]; const float* tg1b=(const float*)d_in[16];
  const float* tw2 = (const float*)d_in[17]; const float* tg2w= (const float*)d_in[18]; const float* tg2b=(const float*)d_in[19];
  const float* wqp = (const float*)d_in[20]; const float* bqp = (const float*)d_in[21]; const float* keys=(const float*)d_in[22];

  char* ws = (char*)d_ws;
  u16*   xr     = (u16*)(ws + 0);               // 12,582,912 B  [12288,512] bf16 CHW
  u16*   h1     = (u16*)(ws + 12582912);        //  4,718,592 B  [12288,192]
  u16*   tw1b   = (u16*)(ws + 17301504);        //    196,608 B
  u16*   tw2b   = (u16*)(ws + 17498112);        //  1,179,648 B
  float* stats5 = (float*)(ws + 18677760);      //        128 B
  float* att    = (float*)(ws + 18678656);      //        128 B
  // ---- h2 span (reused during conv phase) ----
  u16*   h2     = (u16*)(ws + 18680832);        // 75,497,472 B  [12288,3072]
  u16*   Y      = (u16*)(ws + 18680832);        // 12,582,912 B  NHWC conv out [4,128,512,24]
  u16*   b72p   = (u16*)(ws + 31263744);        // 38,488,320 B  NHWC padded [4,130,514,72]
  u16*   xc24   = (u16*)(ws + 69752064);        // 12,829,440 B (+256 slack) NHWC padded [4,130,514,24]
  float* stats14= (float*)(ws + 82581760);      //        512 B
  u16*   wr0    = (u16*)(ws + 82585344);        //     18,432 B
  u16*   wr1    = (u16*)(ws + 82603776);        //     36,864 B
  u16*   wr2    = (u16*)(ws + 82640640);        //     43,008 B

  // ---- fused prologue (1 launch) ----
  prep_all<<<1570,256,0,stream>>>(x, b72p, xc24, tw1, tw1b, tw2, tw2b,
                                  cw0, wr0, cw1, wr1, cw2, wr2,
                                  stats14, stats5, c, wqp, bqp, keys, att);

  // ---- conv block 0 ----
  conv_mfma<96,24><<<512,256,0,stream>>>(xc24, 0, wr0, cb0, Y, stats14+0);
  norm_relu_nhwc<<<3072,256,0,stream>>>(Y, b72p, 24, stats14+0, gw0, gb0, 1.f/393216.f);

  // ---- conv block 1 ----
  conv_mfma<192,72><<<512,256,0,stream>>>(b72p, 24, wr1, cb1, Y, stats14+32);
  norm_relu_nhwc<<<3072,256,0,stream>>>(Y, b72p, 0, stats14+32, gw1, gb1, 1.f/393216.f);

  // ---- conv block 2 -> xr (CHW) ----
  conv_mfma<224,72><<<512,256,0,stream>>>(b72p, 0, wr2, cb2, Y, stats14+64);
  norm_relu_chw<<<512,256,0,stream>>>(Y, xr, stats14+64, gw2, gb2, 1.f/393216.f);

  // ---- TDF: gemm1 (12288x192x512) + GN + relu ----
  gemm_lds<2,true><<<288,256,0,stream>>>(xr, tw1b, h1, 192, 512, 3, stats14+96);
  norm_chw<<<1152,256,0,stream>>>(h1, stats14+96, tg1w, tg1b, 1.f/147456.f);

  // ---- TDF: gemm2 (12288x3072x192), 8-wave 128x128 ----
  gemm2_w8<<<2304,512,0,stream>>>(h1, tw2b, h2, stats5);

  // ---- final mix (inline GN2 params) ----
  final_mix<<<6144,256,0,stream>>>(h2, xr, stats5, tg2w, tg2b, 1.f/2359296.f, att, (float*)d_out);
}

// Round 19
// 198.960 us; speedup vs baseline: 1.2351x; 1.0476x over previous
//
#include <hip/hip_runtime.h>
#include <hip/hip_bf16.h>

typedef unsigned short u16;
typedef unsigned int u32;

#define Tn 128
#define Fn 512
#define HWc (Tn*Fn)
#define EPS 1e-5f

using bf16x8 = __attribute__((ext_vector_type(8))) short;
using f32x4  = __attribute__((ext_vector_type(4))) float;

__device__ __forceinline__ float b2f(u16 x){ return __uint_as_float(((u32)x)<<16); }
__device__ __forceinline__ u16 f2b(float f){
  __hip_bfloat16 h = __float2bfloat16(f);
  return *reinterpret_cast<u16*>(&h);
}

// async global->LDS, 16B per lane
__device__ __forceinline__ void gload16(const u16* g, u16* l){
  __builtin_amdgcn_global_load_lds((const __attribute__((address_space(1))) void*)g,
                                   (__attribute__((address_space(3))) void*)l, 16, 0, 0);
}

// ---------------- prep_all: fused prologue (10 kernels -> 1 launch) ----------------
__global__ __launch_bounds__(256)
void prep_all(const float* __restrict__ x, u16* __restrict__ b72p, u16* __restrict__ xc24,
              const float* __restrict__ tw1, u16* __restrict__ tw1b,
              const float* __restrict__ tw2, u16* __restrict__ tw2b,
              const float* __restrict__ cw0, u16* __restrict__ wr0,
              const float* __restrict__ cw1, u16* __restrict__ wr1,
              const float* __restrict__ cw2, u16* __restrict__ wr2,
              float* __restrict__ stats14, float* __restrict__ stats5,
              const float* __restrict__ cc, const float* __restrict__ wq,
              const float* __restrict__ bq, const float* __restrict__ keys,
              float* __restrict__ att){
  __shared__ __align__(16) char smem[24*520*2];
  int bid = blockIdx.x, tid = threadIdx.x;

  if (bid < 512){
    u16 (*sh)[520] = (u16(*)[520])smem;
    int t = bid & 127, b = bid >> 7;
    const float* src = x + ((long)(b*24)*128 + t)*512;
    for (int c=0; c<24; c++){
      float2 v = *(const float2*)(src + (long)c*65536 + tid*2);
      sh[c][tid*2]   = f2b(v.x);
      sh[c][tid*2+1] = f2b(v.y);
    }
    __syncthreads();
    long r72 = ((long)(b*130 + t+1))*514*72;
    long r24 = ((long)(b*130 + t+1))*514*24;
    for (int i = tid; i < 1536; i += 256){
      int f = i/3, c0 = (i%3)*8;
      union {int4 q; u16 u[8];} o;
      #pragma unroll
      for (int j=0;j<8;j++) o.u[j] = sh[c0+j][f];
      *(int4*)(b72p + r72 + (long)(f+1)*72 + 48 + c0) = o.q;
      *(int4*)(xc24 + r24 + (long)(f+1)*24 + c0) = o.q;
    }
  } else if (bid < 1088){
    int i = ((bid-512)*256 + tid)*4;
    float4 v = *(const float4*)(tw2 + i);
    ushort4 o;
    o.x=f2b(v.x); o.y=f2b(v.y); o.z=f2b(v.z); o.w=f2b(v.w);
    *(ushort4*)(tw2b + i) = o;
  } else if (bid < 1184){
    int i = ((bid-1088)*256 + tid)*4;
    float4 v = *(const float4*)(tw1 + i);
    ushort4 o;
    o.x=f2b(v.x); o.y=f2b(v.y); o.z=f2b(v.z); o.w=f2b(v.w);
    *(ushort4*)(tw1b + i) = o;
  } else if (bid < 1312){
    int sub = bid - 1184;
    int b = sub >> 5, j = sub & 31;
    u16* base = b72p + (long)b*130*514*72;
    int rowN = 514*72;
    for (int i = j*256 + tid; i < rowN; i += 32*256){
      base[i] = 0;
      base[(long)129*rowN + i] = 0;
    }
    int colN = 128*72;
    for (int i = j*256 + tid; i < colN; i += 32*256){
      int row = 1 + i/72, ch = i - (i/72)*72;
      base[((long)row*514 + 0)*72 + ch] = 0;
      base[((long)row*514 + 513)*72 + ch] = 0;
    }
  } else if (bid < 1376){
    int sub = bid - 1312;
    int b = sub >> 4, j = sub & 15;
    u16* base = xc24 + (long)b*130*514*24;
    int rowN = 514*24;
    for (int i = j*256 + tid; i < rowN; i += 16*256){
      base[i] = 0;
      base[(long)129*rowN + i] = 0;
    }
    int colN = 128*24;
    for (int i = j*256 + tid; i < colN; i += 16*256){
      int row = 1 + i/24, ch = i - (i/24)*24;
      base[((long)row*514 + 0)*24 + ch] = 0;
      base[((long)row*514 + 513)*24 + ch] = 0;
    }
  } else if (bid < 1568){
    const float* w; u16* wr; int CIN, cs, cof, KP, sub;
    if (bid < 1412){ sub = bid-1376; w = cw0; wr = wr0; CIN=24; cs=24; cof=0;  KP=96;  }
    else if (bid < 1484){ sub = bid-1412; w = cw1; wr = wr1; CIN=48; cs=72; cof=24; KP=192; }
    else { sub = bid-1484; w = cw2; wr = wr2; CIN=72; cs=72; cof=0;  KP=224; }
    int i = sub*256 + tid;
    int tot = 96*KP;
    if (i < tot){
      int e  = i & 7;
      int r  = (i >> 3) & 15;
      int h  = (i >> 7) & 1;
      int q  = (i >> 8) & 3;
      int rest = i >> 10;
      int NK = KP >> 5;
      int ks = rest % NK, dt = rest / NK;
      int o = h*16 + r;
      int k = ks*32 + q*8 + e;
      float v = 0.f;
      int g = cof + k, df = g/cs, ch = g - df*cs;
      if (o < 24 && df < 3 && ch >= cof && ch < cof+CIN)
        v = w[((o*CIN + (ch-cof))*3 + dt)*3 + df];
      wr[i] = f2b(v);
    }
  } else if (bid == 1568){
    if (tid < 128) stats14[tid] = 0.f;
    else if (tid < 160) stats5[tid-128] = 0.f;
  } else {
    float (*qs)[32] = (float(*)[32])smem;
    float (*ss)[6]  = (float(*)[6])(smem + 4*32*4);
    int t = tid;
    if (t < 128){
      int b = t >> 5, k = t & 31;
      float a = bq[k];
      for (int j=0;j<32;j++) a += cc[b*32+j] * wq[k*32+j];
      qs[b][k] = a;
    }
    __syncthreads();
    if (t < 24){
      int b = t/6, n = t%6;
      float a = 0.f;
      for (int k=0;k<32;k++) a += qs[b][k]*keys[k*6+n];
      ss[b][n] = a * 0.17677669529663689f;
    }
    __syncthreads();
    if (t < 4){
      float mx = -1e30f;
      for (int n=0;n<6;n++) mx = fmaxf(mx, ss[t][n]);
      float e[6], sm=0.f;
      for (int n=0;n<6;n++){ e[n]=expf(ss[t][n]-mx); sm+=e[n]; }
      for (int n=0;n<6;n++) att[t*6+n] = e[n]/sm;
    }
  }
}

// ---------------- MFMA implicit-GEMM 3x3 conv v11: 512 threads, 2 t-rows/block, shared WS ----------------
// grid 256 (chunk 32 per XCD): bid in [0,256): b = bid>>6, t0 = (bid&63)*2. 16 waves/CU.
template<int KP, int CS>
__global__ __launch_bounds__(512)
void conv_mfma(const u16* __restrict__ X, int coff, const u16* __restrict__ WR,
               const float* __restrict__ bias, u16* __restrict__ Y,
               float* __restrict__ raw){
  constexpr int NK = KP/32;
  __shared__ u16 WS[3*32*KP];
  __shared__ float ssum[8][32], ssq[8][32];
  __shared__ float g24s[24], g24q[24];
  __shared__ __align__(16) u16 Ysh[2*128*24];
  int bid = (blockIdx.x & 7)*32 + (blockIdx.x >> 3);   // grid 256, chunk 32
  int b = bid >> 6, t0 = (bid & 63)*2;
  int tid = threadIdx.x, wid = tid >> 6, l = tid & 63;
  int r = l & 15, q = l >> 4;
  int h = wid >> 2;            // half: t = t0 + h
  int wid4 = wid & 3;
  int t = t0 + h;

  for (int i = tid*8; i < 3*32*KP; i += 4096)
    *(int4*)(WS + i) = *(const int4*)(WR + i);

  float bv0 = bias[r];
  float bv1 = (r < 8) ? bias[16+r] : 0.f;
  float s0=0,q0=0,s1=0,q1=0;
  __syncthreads();

  #pragma unroll
  for (int fi=0; fi<4; fi++){
    int f0w = fi*128 + wid4*32;
    f32x4 acc[2][2] = {};
    #pragma unroll
    for (int dt=0; dt<3; dt++){
      const u16* Ab = X + ((long)((b*130 + t+dt)*514 + f0w + r))*CS + coff + q*8;
      bf16x8 a[2][NK];
      #pragma unroll
      for (int ks=0; ks<NK; ks++){
        a[0][ks] = *(const bf16x8*)(Ab + ks*32);
        a[1][ks] = *(const bf16x8*)(Ab + (long)16*CS + ks*32);
      }
      #pragma unroll
      for (int ks=0; ks<NK; ks++){
        const u16* Bb = WS + ((dt*NK + ks)*4 + q)*256 + r*8;
        bf16x8 b0 = *(const bf16x8*)(Bb);
        bf16x8 b1 = *(const bf16x8*)(Bb + 128);
        acc[0][0] = __builtin_amdgcn_mfma_f32_16x16x32_bf16(a[0][ks],b0,acc[0][0],0,0,0);
        acc[0][1] = __builtin_amdgcn_mfma_f32_16x16x32_bf16(a[0][ks],b1,acc[0][1],0,0,0);
        acc[1][0] = __builtin_amdgcn_mfma_f32_16x16x32_bf16(a[1][ks],b0,acc[1][0],0,0,0);
        acc[1][1] = __builtin_amdgcn_mfma_f32_16x16x32_bf16(a[1][ks],b1,acc[1][1],0,0,0);
      }
    }
    #pragma unroll
    for (int m=0;m<2;m++){
      #pragma unroll
      for (int j=0;j<4;j++){
        acc[m][0][j] += bv0; acc[m][1][j] += bv1;
        s0 += acc[m][0][j]; q0 += acc[m][0][j]*acc[m][0][j];
        s1 += acc[m][1][j]; q1 += acc[m][1][j]*acc[m][1][j];
      }
    }
    __syncthreads();   // previous f-tile's Ysh->global copy done
    #pragma unroll
    for (int m=0;m<2;m++){
      int fr = wid4*32 + m*16 + q*4;
      #pragma unroll
      for (int j=0;j<4;j++){
        Ysh[h*3072 + (fr+j)*24 + r] = f2b(acc[m][0][j]);
        if (r < 8) Ysh[h*3072 + (fr+j)*24 + 16 + r] = f2b(acc[m][1][j]);
      }
    }
    __syncthreads();
    const int4* sp = (const int4*)Ysh;
    for (int i = tid; i < 768; i += 512){
      int hh = i >> 8 >= 1 ? (i >= 384 ? 1 : 0) : 0;   // i<384 -> half 0
      hh = (i >= 384) ? 1 : 0;
      int rem = i - hh*384;
      long Yb = ((long)((b*128 + t0 + hh)*512) + fi*128)*24;
      *(int4*)(Y + Yb + (long)rem*8) = sp[i];
    }
  }

  // block-wide stats reduction (once)
  #pragma unroll
  for (int off=16; off<=32; off<<=1){
    s0 += __shfl_xor(s0, off, 64); q0 += __shfl_xor(q0, off, 64);
    s1 += __shfl_xor(s1, off, 64); q1 += __shfl_xor(q1, off, 64);
  }
  if (q == 0){
    ssum[wid][r] = s0;     ssq[wid][r] = q0;
    ssum[wid][16+r] = s1;  ssq[wid][16+r] = q1;
  }
  __syncthreads();
  if (tid < 24){
    float as = 0, aq = 0;
    #pragma unroll
    for (int w2=0; w2<8; w2++){ as += ssum[w2][tid]; aq += ssq[w2][tid]; }
    g24s[tid] = as;
    g24q[tid] = aq;
  }
  __syncthreads();
  if (tid < 4){
    float as=0, aq=0;
    #pragma unroll
    for (int j=0;j<6;j++){ as += g24s[tid*6+j]; aq += g24q[tid*6+j]; }
    atomicAdd(&raw[b*4+tid], as);
    atomicAdd(&raw[16+b*4+tid], aq);
  }
}

// ---------------- normalize+relu: Y NHWC -> b72p channel slice (inline GN params) ----------------
__global__ __launch_bounds__(256)
void norm_relu_nhwc(const u16* __restrict__ Y, u16* __restrict__ dst, int coff,
                    const float* __restrict__ raw, const float* __restrict__ gw,
                    const float* __restrict__ gb, float invN){
  __shared__ float sA[24], sB[24];
  int bb = blockIdx.x / 768;
  if (threadIdx.x < 24){
    int g = bb*4 + threadIdx.x/6;
    float m = raw[g]*invN;
    float var = raw[16+g]*invN - m*m;
    float is = rsqrtf(var + EPS);
    float sc = is*gw[threadIdx.x];
    sA[threadIdx.x] = sc;
    sB[threadIdx.x] = gb[threadIdx.x] - m*sc;
  }
  __syncthreads();
  long e = ((long)blockIdx.x*256 + threadIdx.x)*8;
  int c0 = (int)(e % 24);
  long fi = e / 24;
  int f = (int)(fi & 511);
  int bt = (int)(fi >> 9); int t = bt & 127, b = bt >> 7;
  union {int4 q; u16 u[8];} pk; pk.q = *(const int4*)(Y + e);
  union {int4 q; u16 u[8];} o;
  #pragma unroll
  for (int j=0;j<8;j++){
    float v = b2f(pk.u[j])*sA[c0+j] + sB[c0+j];
    o.u[j] = f2b(v>0.f?v:0.f);
  }
  *(int4*)(dst + ((long)(b*130 + t+1)*514 + (f+1))*72 + coff + c0) = o.q;
}

// ---------------- normalize+relu + NHWC->CHW transpose (inline GN params) ----------------
__global__ __launch_bounds__(256)
void norm_relu_chw(const u16* __restrict__ Y, u16* __restrict__ xr,
                   const float* __restrict__ raw, const float* __restrict__ gw,
                   const float* __restrict__ gb, float invN){
  __shared__ u16 sh[24][520];
  __shared__ float sA[24], sB[24];
  int t = blockIdx.x & 127, b = blockIdx.x >> 7;
  if (threadIdx.x < 24){
    int g = b*4 + threadIdx.x/6;
    float m = raw[g]*invN;
    float var = raw[16+g]*invN - m*m;
    float is = rsqrtf(var + EPS);
    float sc = is*gw[threadIdx.x];
    sA[threadIdx.x] = sc;
    sB[threadIdx.x] = gb[threadIdx.x] - m*sc;
  }
  __syncthreads();
  const u16* src = Y + ((long)(b*128+t))*12288;
  for (int i = threadIdx.x; i < 1536; i += 256){
    int e = i*8; int c0 = e % 24; int f = e / 24;
    union {int4 q; u16 u[8];} pk; pk.q = *(const int4*)(src + e);
    #pragma unroll
    for (int j=0;j<8;j++){
      float v = b2f(pk.u[j])*sA[c0+j] + sB[c0+j];
      sh[c0+j][f] = f2b(v>0.f?v:0.f);
    }
  }
  __syncthreads();
  for (int i = threadIdx.x; i < 1536; i += 256){
    int c = i >> 6, fq = (i & 63)*8;
    union {int4 q; u16 u[8];} o;
    #pragma unroll
    for (int j=0;j<8;j++) o.u[j] = sh[c][fq+j];
    *(int4*)(xr + ((long)((b*24+c)*128 + t))*512 + fq) = o.q;
  }
}

// ---------------- elementwise normalize+relu on CHW rows (h1), inline GN params ----------------
__global__ __launch_bounds__(256)
void norm_chw(u16* __restrict__ h, const float* __restrict__ raw,
              const float* __restrict__ gw, const float* __restrict__ gb, float invN){
  __shared__ float s_sc, s_off;
  int bc = blockIdx.x / 12;
  if (threadIdx.x == 0){
    int b = bc/24, c = bc%24;
    int g = b*4 + c/6;
    float m = raw[g]*invN;
    float var = raw[16+g]*invN - m*m;
    float is = rsqrtf(var + EPS);
    float sc = is*gw[c];
    s_sc = sc;
    s_off = gb[c] - m*sc;
  }
  __syncthreads();
  float sc = s_sc, off = s_off;
  long e = ((long)blockIdx.x*256 + threadIdx.x)*8;
  union {int4 q; u16 u[8];} pk; pk.q = *(const int4*)(h + e);
  #pragma unroll
  for (int j=0;j<8;j++){ float v = b2f(pk.u[j])*sc + off; pk.u[j] = f2b(v>0.f?v:0.f); }
  *(int4*)(h + e) = pk.q;
}

// ---------------- gemm1: LDS-staged MFMA GEMM, depth-2 counted-vmcnt pipeline ----------------
template<int NF, bool STORE>
__global__ __launch_bounds__(256)
void gemm_lds(const u16* __restrict__ A, const u16* __restrict__ Bt, u16* __restrict__ C,
              int N, int K, int NBX, float* __restrict__ raw){
  constexpr int BN = NF*32;
  constexpr int BNP = BN + 4;
  constexpr int ABUF = 128*32;
  constexpr int BBUF = BN*32;
  __shared__ __align__(16) u16 SH[3*(ABUF+BBUF)];
  u16* Asb = SH;
  u16* Bsb = SH + 3*ABUF;
  int tid = threadIdx.x, wid = tid >> 6, l = tid & 63;
  int r = l & 15, q = l >> 4;
  int wr = wid >> 1, wc = wid & 1;
  int chunk = gridDim.x >> 3;
  int lin = (blockIdx.x & 7)*chunk + (blockIdx.x >> 3);
  int bx = lin % NBX, by = lin / NBX;
  long m0 = (long)by*128;
  int n0 = bx*BN;

  int arow[2], ach[2], aslot[2];
  #pragma unroll
  for (int j=0;j<2;j++){
    int idx = (wid*2+j)*64 + l;
    aslot[j] = idx*8;
    arow[j]  = ((idx>>6)<<4) | (idx & 15);
    ach[j]   = ((idx>>4) & 3)*8;
  }
  int brow[NF/2], bch[NF/2], bslot[NF/2];
  #pragma unroll
  for (int j=0;j<NF/2;j++){
    int idx = (wid*(NF/2)+j)*64 + l;
    bslot[j] = idx*8;
    brow[j]  = ((idx>>6)<<4) | (idx & 15);
    bch[j]   = ((idx>>4) & 3)*8;
  }

  f32x4 acc[4][NF];
  #pragma unroll
  for (int mf=0;mf<4;mf++)
    #pragma unroll
    for (int nf=0;nf<NF;nf++) acc[mf][nf] = (f32x4){0.f,0.f,0.f,0.f};

  int nt = K >> 5;
  #pragma unroll
  for (int j=0;j<2;j++)    gload16(A  + (m0+arow[j])*K + ach[j], Asb + aslot[j]);
  #pragma unroll
  for (int j=0;j<NF/2;j++) gload16(Bt + (long)(n0+brow[j])*K + bch[j], Bsb + bslot[j]);
  #pragma unroll
  for (int j=0;j<2;j++)    gload16(A  + (m0+arow[j])*K + 32 + ach[j], Asb + ABUF + aslot[j]);
  #pragma unroll
  for (int j=0;j<NF/2;j++) gload16(Bt + (long)(n0+brow[j])*K + 32 + bch[j], Bsb + BBUF + bslot[j]);

  int c0 = 0;
  for (int kt=0; kt<nt; kt++){
    if constexpr (NF==4) asm volatile("s_waitcnt vmcnt(4)" ::: "memory");
    else                 asm volatile("s_waitcnt vmcnt(3)" ::: "memory");
    __builtin_amdgcn_s_barrier();
    __builtin_amdgcn_sched_barrier(0);
    if (kt+2 < nt){
      int c2 = c0+2; if (c2>=3) c2-=3;
      int ko = (kt+2)*32;
      #pragma unroll
      for (int j=0;j<2;j++)    gload16(A  + (m0+arow[j])*K + ko + ach[j], Asb + c2*ABUF + aslot[j]);
      #pragma unroll
      for (int j=0;j<NF/2;j++) gload16(Bt + (long)(n0+brow[j])*K + ko + bch[j], Bsb + c2*BBUF + bslot[j]);
    }
    const u16* Ac = Asb + c0*ABUF;
    const u16* Bc = Bsb + c0*BBUF;
    bf16x8 af[4], bfv[NF];
    #pragma unroll
    for (int mf=0;mf<4;mf++) af[mf]  = *(const bf16x8*)(Ac + (((wr*4+mf)*4 + q)*16 + r)*8);
    #pragma unroll
    for (int nf=0;nf<NF;nf++) bfv[nf] = *(const bf16x8*)(Bc + (((wc*NF+nf)*4 + q)*16 + r)*8);
    #pragma unroll
    for (int mf=0;mf<4;mf++)
      #pragma unroll
      for (int nf=0;nf<NF;nf++)
        acc[mf][nf] = __builtin_amdgcn_mfma_f32_16x16x32_bf16(af[mf], bfv[nf], acc[mf][nf], 0,0,0);
    c0 = (c0+1==3) ? 0 : c0+1;
  }

  float s=0.f, ss=0.f;
  #pragma unroll
  for (int mf=0;mf<4;mf++)
    #pragma unroll
    for (int nf=0;nf<NF;nf++)
      #pragma unroll
      for (int j=0;j<4;j++){ float v = acc[mf][nf][j]; s += v; ss += v*v; }
  #pragma unroll
  for (int off=32; off>0; off>>=1){ s += __shfl_down(s,off,64); ss += __shfl_down(ss,off,64); }
  __shared__ float rs[4], rss[4];
  if (l==0){ rs[wid]=s; rss[wid]=ss; }
  __syncthreads();
  if (tid==0){
    int bc = (int)(m0 >> 7);
    int g = (bc/24)*4 + (bc%24)/6;
    atomicAdd(&raw[g],    rs[0]+rs[1]+rs[2]+rs[3]);
    atomicAdd(&raw[16+g], rss[0]+rss[1]+rss[2]+rss[3]);
  }

  if constexpr (STORE){
    #pragma unroll
    for (int mf=0;mf<4;mf++){
      int row = wr*64 + mf*16 + q*4;
      #pragma unroll
      for (int nf=0;nf<NF;nf++){
        int col = wc*(NF*16) + nf*16 + r;
        #pragma unroll
        for (int j=0;j<4;j++)
          SH[(row+j)*BNP + col] = f2b(acc[mf][nf][j]);
      }
    }
    __syncthreads();
    constexpr int RPT = BN/16;
    #pragma unroll
    for (int k=0;k<RPT;k++){
      int j = tid + k*256;
      int row = j / (BN/8), col8 = (j % (BN/8))*8;
      *(int4*)(C + (m0+row)*N + n0 + col8) = *(const int4*)(SH + row*BNP + col8);
    }
  }
}

// ---------------- gemm2 w8: 512 threads, 8 waves (2x4), tile 128x128, depth-2 vmcnt ring ----------------
__global__ __launch_bounds__(512)
void gemm2_w8(const u16* __restrict__ A, const u16* __restrict__ Bt, u16* __restrict__ C,
              float* __restrict__ raw){
  const int K = 192, N = 3072;
  constexpr int SB = 128*32;
  __shared__ __align__(16) u16 SH[6*SB];
  __shared__ float rs[8], rss[8];
  u16* Asb = SH;
  u16* Bsb = SH + 3*SB;
  int tid = threadIdx.x, wid = tid >> 6, l = tid & 63;
  int r = l & 15, q = l >> 4;
  int wr = wid >> 2, wc = wid & 3;
  int chunk = gridDim.x >> 3;
  int lin = (blockIdx.x & 7)*chunk + (blockIdx.x >> 3);
  int bx = lin % 24, by = lin / 24;
  long m0 = (long)by*128;
  int n0 = bx*128;

  int srow = ((tid>>6)<<4) | (tid & 15);
  int sch  = ((tid>>4) & 3)*8;
  int sslot = tid*8;

  f32x4 acc[4][2];
  #pragma unroll
  for (int mf=0;mf<4;mf++){ acc[mf][0] = (f32x4){0.f,0.f,0.f,0.f}; acc[mf][1] = (f32x4){0.f,0.f,0.f,0.f}; }

  gload16(A  + (m0+srow)*K + sch,          Asb + sslot);
  gload16(Bt + (long)(n0+srow)*K + sch,    Bsb + sslot);
  gload16(A  + (m0+srow)*K + 32 + sch,     Asb + SB + sslot);
  gload16(Bt + (long)(n0+srow)*K + 32 + sch, Bsb + SB + sslot);

  int c0 = 0;
  for (int kt=0; kt<6; kt++){
    asm volatile("s_waitcnt vmcnt(2)" ::: "memory");
    __builtin_amdgcn_s_barrier();
    __builtin_amdgcn_sched_barrier(0);
    if (kt+2 < 6){
      int c2 = c0+2; if (c2>=3) c2-=3;
      int ko = (kt+2)*32;
      gload16(A  + (m0+srow)*K + ko + sch,       Asb + c2*SB + sslot);
      gload16(Bt + (long)(n0+srow)*K + ko + sch, Bsb + c2*SB + sslot);
    }
    const u16* Ac = Asb + c0*SB;
    const u16* Bc = Bsb + c0*SB;
    bf16x8 af[4], bfv[2];
    #pragma unroll
    for (int mf=0;mf<4;mf++) af[mf]  = *(const bf16x8*)(Ac + (((wr*4+mf)*4 + q)*16 + r)*8);
    #pragma unroll
    for (int nf=0;nf<2;nf++) bfv[nf] = *(const bf16x8*)(Bc + (((wc*2+nf)*4 + q)*16 + r)*8);
    #pragma unroll
    for (int mf=0;mf<4;mf++){
      acc[mf][0] = __builtin_amdgcn_mfma_f32_16x16x32_bf16(af[mf], bfv[0], acc[mf][0], 0,0,0);
      acc[mf][1] = __builtin_amdgcn_mfma_f32_16x16x32_bf16(af[mf], bfv[1], acc[mf][1], 0,0,0);
    }
    c0 = (c0+1==3) ? 0 : c0+1;
  }

  float s=0.f, ss=0.f;
  #pragma unroll
  for (int mf=0;mf<4;mf++)
    #pragma unroll
    for (int nf=0;nf<2;nf++)
      #pragma unroll
      for (int j=0;j<4;j++){ float v = acc[mf][nf][j]; s += v; ss += v*v; }
  #pragma unroll
  for (int off=32; off>0; off>>=1){ s += __shfl_down(s,off,64); ss += __shfl_down(ss,off,64); }
  if (l==0){ rs[wid]=s; rss[wid]=ss; }
  __syncthreads();
  if (tid==0){
    float as=0, aq=0;
    #pragma unroll
    for (int j=0;j<8;j++){ as += rs[j]; aq += rss[j]; }
    int bc = (int)(m0 >> 7);
    int g = (bc/24)*4 + (bc%24)/6;
    atomicAdd(&raw[g], as);
    atomicAdd(&raw[16+g], aq);
  }

  #pragma unroll
  for (int mf=0;mf<4;mf++){
    int row = wr*64 + mf*16 + q*4;
    #pragma unroll
    for (int nf=0;nf<2;nf++){
      int col = wc*32 + nf*16 + r;
      #pragma unroll
      for (int j=0;j<4;j++)
        SH[(row+j)*132 + col] = f2b(acc[mf][nf][j]);
    }
  }
  __syncthreads();
  #pragma unroll
  for (int k=0;k<4;k++){
    int j = tid + k*512;
    int row = j >> 4, col8 = (j & 15)*8;
    *(int4*)(C + (m0+row)*N + n0 + col8) = *(const int4*)(SH + row*132 + col8);
  }
}

// ---------------- final: out(fp32) = x_ + sum_n relu(gn2(h2))[...,n]*att[b,n] (inline GN) ----------------
__global__ __launch_bounds__(256)
void final_mix(const u16* __restrict__ h2, const u16* __restrict__ xr,
               const float* __restrict__ raw, const float* __restrict__ gw,
               const float* __restrict__ gb, float invN,
               const float* __restrict__ att, float* __restrict__ out){
  __shared__ float s_sc, s_off, s_att[6];
  int bc0 = blockIdx.x / 64;
  int c  = bc0 % 24, b = bc0 / 24;
  if (threadIdx.x == 0){
    int g = b*4 + c/6;
    float m = raw[g]*invN;
    float var = raw[16+g]*invN - m*m;
    float is = rsqrtf(var + EPS);
    float sc = is*gw[c];
    s_sc = sc;
    s_off = gb[c] - m*sc;
  }
  if (threadIdx.x < 6) s_att[threadIdx.x] = att[b*6+threadIdx.x];
  __syncthreads();
  float sc = s_sc, off = s_off;
  float a[6];
  #pragma unroll
  for (int n=0;n<6;n++) a[n] = s_att[n];

  int gid = blockIdx.x*256 + threadIdx.x;
  int fq = gid & 127;
  int t  = (gid >> 7) & 127;
  int bc = gid >> 14;

  long hbase = (((long)bc*Tn + t))*3072 + (long)fq*24;
  union { int4 v[3]; u16 u[24]; } hv;
  const int4* hp = (const int4*)(h2 + hbase);
  hv.v[0]=hp[0]; hv.v[1]=hp[1]; hv.v[2]=hp[2];

  long xbase = (((long)bc*Tn + t))*Fn + (long)fq*4;
  union { unsigned long long q; u16 u[4]; } xv;
  xv.q = *(const unsigned long long*)(xr + xbase);

  float4 ov;
  float* op = &ov.x;
  #pragma unroll
  for (int j=0;j<4;j++){
    float accv = b2f(xv.u[j]);
    #pragma unroll
    for (int n=0;n<6;n++){
      float hvf = b2f(hv.u[j*6+n])*sc + off;
      hvf = hvf > 0.f ? hvf : 0.f;
      accv += hvf * a[n];
    }
    op[j] = accv;
  }
  *(float4*)(out + xbase) = ov;
}

extern "C" void kernel_launch(void* const* d_in, const int* in_sizes, int n_in,
                              void* d_out, int out_size, void* d_ws, size_t ws_size,
                              hipStream_t stream){
  const float* x   = (const float*)d_in[0];
  const float* c   = (const float*)d_in[1];
  const float* cw0 = (const float*)d_in[2];  const float* cb0 = (const float*)d_in[3];
  const float* gw0 = (const float*)d_in[4];  const float* gb0 = (const float*)d_in[5];
  const float* cw1 = (const float*)d_in[6];  const float* cb1 = (const float*)d_in[7];
  const float* gw1 = (const float*)d_in[8];  const float* gb1 = (const float*)d_in[9];
  const float* cw2 = (const float*)d_in[10]; const float* cb2 = (const float*)d_in[11];
  const float* gw2 = (const float*)d_in[12]; const float* gb2 = (const float*)d_in[13];
  const float* tw1 = (const float*)d_in[14]; const float* tg1w= (const float*)d_in[15]; const float* tg1b=(const float*)d_in[16];
  const float* tw2 = (const float*)d_in[17]; const float* tg2w= (const float*)d_in[18]; const float* tg2b=(const float*)d_in[19];
  const float* wqp = (const float*)d_in[20]; const float* bqp = (const float*)d_in[21]; const float* keys=(const float*)d_in[22];

  char* ws = (char*)d_ws;
  u16*   xr     = (u16*)(ws + 0);               // 12,582,912 B  [12288,512] bf16 CHW
  u16*   h1     = (u16*)(ws + 12582912);        //  4,718,592 B  [12288,192]
  u16*   tw1b   = (u16*)(ws + 17301504);        //    196,608 B
  u16*   tw2b   = (u16*)(ws + 17498112);        //  1,179,648 B
  float* stats5 = (float*)(ws + 18677760);      //        128 B
  float* att    = (float*)(ws + 18678656);      //        128 B
  // ---- h2 span (reused during conv phase) ----
  u16*   h2     = (u16*)(ws + 18680832);        // 75,497,472 B  [12288,3072]
  u16*   Y      = (u16*)(ws + 18680832);        // 12,582,912 B  NHWC conv out [4,128,512,24]
  u16*   b72p   = (u16*)(ws + 31263744);        // 38,488,320 B  NHWC padded [4,130,514,72]
  u16*   xc24   = (u16*)(ws + 69752064);        // 12,829,440 B (+256 slack) NHWC padded [4,130,514,24]
  float* stats14= (float*)(ws + 82581760);      //        512 B
  u16*   wr0    = (u16*)(ws + 82585344);        //     18,432 B
  u16*   wr1    = (u16*)(ws + 82603776);        //     36,864 B
  u16*   wr2    = (u16*)(ws + 82640640);        //     43,008 B

  // ---- fused prologue (1 launch) ----
  prep_all<<<1570,256,0,stream>>>(x, b72p, xc24, tw1, tw1b, tw2, tw2b,
                                  cw0, wr0, cw1, wr1, cw2, wr2,
                                  stats14, stats5, c, wqp, bqp, keys, att);

  // ---- conv block 0 ----
  conv_mfma<96,24><<<256,512,0,stream>>>(xc24, 0, wr0, cb0, Y, stats14+0);
  norm_relu_nhwc<<<3072,256,0,stream>>>(Y, b72p, 24, stats14+0, gw0, gb0, 1.f/393216.f);

  // ---- conv block 1 ----
  conv_mfma<192,72><<<256,512,0,stream>>>(b72p, 24, wr1, cb1, Y, stats14+32);
  norm_relu_nhwc<<<3072,256,0,stream>>>(Y, b72p, 0, stats14+32, gw1, gb1, 1.f/393216.f);

  // ---- conv block 2 -> xr (CHW) ----
  conv_mfma<224,72><<<256,512,0,stream>>>(b72p, 0, wr2, cb2, Y, stats14+64);
  norm_relu_chw<<<512,256,0,stream>>>(Y, xr, stats14+64, gw2, gb2, 1.f/393216.f);

  // ---- TDF: gemm1 (12288x192x512) + GN + relu ----
  gemm_lds<2,true><<<288,256,0,stream>>>(xr, tw1b, h1, 192, 512, 3, stats14+96);
  norm_chw<<<1152,256,0,stream>>>(h1, stats14+96, tg1w, tg1b, 1.f/147456.f);

  // ---- TDF: gemm2 (12288x3072x192), 8-wave 128x128 ----
  gemm2_w8<<<2304,512,0,stream>>>(h1, tw2b, h2, stats5);

  // ---- final mix (inline GN2 params) ----
  final_mix<<<6144,256,0,stream>>>(h2, xr, stats5, tg2w, tg2b, 1.f/2359296.f, att, (float*)d_out);
}

// Round 20
// 191.144 us; speedup vs baseline: 1.2857x; 1.0409x over previous
//
#include <hip/hip_runtime.h>
#include <hip/hip_bf16.h>

typedef unsigned short u16;
typedef unsigned int u32;

#define Tn 128
#define Fn 512
#define HWc (Tn*Fn)
#define EPS 1e-5f

using bf16x8 = __attribute__((ext_vector_type(8))) short;
using f32x4  = __attribute__((ext_vector_type(4))) float;

__device__ __forceinline__ float b2f(u16 x){ return __uint_as_float(((u32)x)<<16); }
__device__ __forceinline__ u16 f2b(float f){
  __hip_bfloat16 h = __float2bfloat16(f);
  return *reinterpret_cast<u16*>(&h);
}

// async global->LDS, 16B per lane
__device__ __forceinline__ void gload16(const u16* g, u16* l){
  __builtin_amdgcn_global_load_lds((const __attribute__((address_space(1))) void*)g,
                                   (__attribute__((address_space(3))) void*)l, 16, 0, 0);
}

// ---------------- prep_all: fused prologue (10 kernels -> 1 launch) ----------------
__global__ __launch_bounds__(256)
void prep_all(const float* __restrict__ x, u16* __restrict__ b72p, u16* __restrict__ xc24,
              const float* __restrict__ tw1, u16* __restrict__ tw1b,
              const float* __restrict__ tw2, u16* __restrict__ tw2b,
              const float* __restrict__ cw0, u16* __restrict__ wr0,
              const float* __restrict__ cw1, u16* __restrict__ wr1,
              const float* __restrict__ cw2, u16* __restrict__ wr2,
              float* __restrict__ stats14, float* __restrict__ stats5,
              const float* __restrict__ cc, const float* __restrict__ wq,
              const float* __restrict__ bq, const float* __restrict__ keys,
              float* __restrict__ att){
  __shared__ __align__(16) char smem[24*520*2];
  int bid = blockIdx.x, tid = threadIdx.x;

  if (bid < 512){
    u16 (*sh)[520] = (u16(*)[520])smem;
    int t = bid & 127, b = bid >> 7;
    const float* src = x + ((long)(b*24)*128 + t)*512;
    for (int c=0; c<24; c++){
      float2 v = *(const float2*)(src + (long)c*65536 + tid*2);
      sh[c][tid*2]   = f2b(v.x);
      sh[c][tid*2+1] = f2b(v.y);
    }
    __syncthreads();
    long r72 = ((long)(b*130 + t+1))*514*72;
    long r24 = ((long)(b*130 + t+1))*514*24;
    for (int i = tid; i < 1536; i += 256){
      int f = i/3, c0 = (i%3)*8;
      union {int4 q; u16 u[8];} o;
      #pragma unroll
      for (int j=0;j<8;j++) o.u[j] = sh[c0+j][f];
      *(int4*)(b72p + r72 + (long)(f+1)*72 + 48 + c0) = o.q;
      *(int4*)(xc24 + r24 + (long)(f+1)*24 + c0) = o.q;
    }
  } else if (bid < 1088){
    int i = ((bid-512)*256 + tid)*4;
    float4 v = *(const float4*)(tw2 + i);
    ushort4 o;
    o.x=f2b(v.x); o.y=f2b(v.y); o.z=f2b(v.z); o.w=f2b(v.w);
    *(ushort4*)(tw2b + i) = o;
  } else if (bid < 1184){
    int i = ((bid-1088)*256 + tid)*4;
    float4 v = *(const float4*)(tw1 + i);
    ushort4 o;
    o.x=f2b(v.x); o.y=f2b(v.y); o.z=f2b(v.z); o.w=f2b(v.w);
    *(ushort4*)(tw1b + i) = o;
  } else if (bid < 1312){
    int sub = bid - 1184;
    int b = sub >> 5, j = sub & 31;
    u16* base = b72p + (long)b*130*514*72;
    int rowN = 514*72;
    for (int i = j*256 + tid; i < rowN; i += 32*256){
      base[i] = 0;
      base[(long)129*rowN + i] = 0;
    }
    int colN = 128*72;
    for (int i = j*256 + tid; i < colN; i += 32*256){
      int row = 1 + i/72, ch = i - (i/72)*72;
      base[((long)row*514 + 0)*72 + ch] = 0;
      base[((long)row*514 + 513)*72 + ch] = 0;
    }
  } else if (bid < 1376){
    int sub = bid - 1312;
    int b = sub >> 4, j = sub & 15;
    u16* base = xc24 + (long)b*130*514*24;
    int rowN = 514*24;
    for (int i = j*256 + tid; i < rowN; i += 16*256){
      base[i] = 0;
      base[(long)129*rowN + i] = 0;
    }
    int colN = 128*24;
    for (int i = j*256 + tid; i < colN; i += 16*256){
      int row = 1 + i/24, ch = i - (i/24)*24;
      base[((long)row*514 + 0)*24 + ch] = 0;
      base[((long)row*514 + 513)*24 + ch] = 0;
    }
  } else if (bid < 1568){
    const float* w; u16* wr; int CIN, cs, cof, KP, sub;
    if (bid < 1412){ sub = bid-1376; w = cw0; wr = wr0; CIN=24; cs=24; cof=0;  KP=96;  }
    else if (bid < 1484){ sub = bid-1412; w = cw1; wr = wr1; CIN=48; cs=72; cof=24; KP=192; }
    else { sub = bid-1484; w = cw2; wr = wr2; CIN=72; cs=72; cof=0;  KP=224; }
    int i = sub*256 + tid;
    int tot = 96*KP;
    if (i < tot){
      int e  = i & 7;
      int r  = (i >> 3) & 15;
      int h  = (i >> 7) & 1;
      int q  = (i >> 8) & 3;
      int rest = i >> 10;
      int NK = KP >> 5;
      int ks = rest % NK, dt = rest / NK;
      int o = h*16 + r;
      int k = ks*32 + q*8 + e;
      float v = 0.f;
      int g = cof + k, df = g/cs, ch = g - df*cs;
      if (o < 24 && df < 3 && ch >= cof && ch < cof+CIN)
        v = w[((o*CIN + (ch-cof))*3 + dt)*3 + df];
      wr[i] = f2b(v);
    }
  } else if (bid == 1568){
    if (tid < 128) stats14[tid] = 0.f;
    else if (tid < 160) stats5[tid-128] = 0.f;
  } else {
    float (*qs)[32] = (float(*)[32])smem;
    float (*ss)[6]  = (float(*)[6])(smem + 4*32*4);
    int t = tid;
    if (t < 128){
      int b = t >> 5, k = t & 31;
      float a = bq[k];
      for (int j=0;j<32;j++) a += cc[b*32+j] * wq[k*32+j];
      qs[b][k] = a;
    }
    __syncthreads();
    if (t < 24){
      int b = t/6, n = t%6;
      float a = 0.f;
      for (int k=0;k<32;k++) a += qs[b][k]*keys[k*6+n];
      ss[b][n] = a * 0.17677669529663689f;
    }
    __syncthreads();
    if (t < 4){
      float mx = -1e30f;
      for (int n=0;n<6;n++) mx = fmaxf(mx, ss[t][n]);
      float e[6], sm=0.f;
      for (int n=0;n<6;n++){ e[n]=expf(ss[t][n]-mx); sm+=e[n]; }
      for (int n=0;n<6;n++) att[t*6+n] = e[n]/sm;
    }
  }
}

// ---------------- MFMA implicit-GEMM 3x3 conv v12: 512 threads, 2 t-rows x 2 f-tiles, grid 512 ----------------
// 2 blocks/CU x 8 waves = 16 waves/CU. bid = ftg*256 + b*64 + t0h, XCD-chunked.
template<int KP, int CS>
__global__ __launch_bounds__(512)
void conv_mfma(const u16* __restrict__ X, int coff, const u16* __restrict__ WR,
               const float* __restrict__ bias, u16* __restrict__ Y,
               float* __restrict__ raw){
  constexpr int NK = KP/32;
  __shared__ u16 WS[3*32*KP];
  __shared__ float ssum[8][32], ssq[8][32];
  __shared__ float g24s[24], g24q[24];
  __shared__ __align__(16) u16 Ysh[2*128*24];
  int bid = (blockIdx.x & 7)*64 + (blockIdx.x >> 3);   // grid 512, chunk 64
  int ftg = bid >> 8, b = (bid >> 6) & 3, t0 = (bid & 63)*2;
  int tid = threadIdx.x, wid = tid >> 6, l = tid & 63;
  int r = l & 15, q = l >> 4;
  int h = wid >> 2;            // half: t = t0 + h
  int wid4 = wid & 3;
  int t = t0 + h;

  for (int i = tid*8; i < 3*32*KP; i += 4096)
    *(int4*)(WS + i) = *(const int4*)(WR + i);

  float bv0 = bias[r];
  float bv1 = (r < 8) ? bias[16+r] : 0.f;
  float s0=0,q0=0,s1=0,q1=0;
  __syncthreads();

  #pragma unroll
  for (int fi=0; fi<2; fi++){
    int ft = ftg*2 + fi;
    int f0w = ft*128 + wid4*32;
    f32x4 acc[2][2] = {};
    #pragma unroll
    for (int dt=0; dt<3; dt++){
      const u16* Ab = X + ((long)((b*130 + t+dt)*514 + f0w + r))*CS + coff + q*8;
      bf16x8 a[2][NK];
      #pragma unroll
      for (int ks=0; ks<NK; ks++){
        a[0][ks] = *(const bf16x8*)(Ab + ks*32);
        a[1][ks] = *(const bf16x8*)(Ab + (long)16*CS + ks*32);
      }
      #pragma unroll
      for (int ks=0; ks<NK; ks++){
        const u16* Bb = WS + ((dt*NK + ks)*4 + q)*256 + r*8;
        bf16x8 b0 = *(const bf16x8*)(Bb);
        bf16x8 b1 = *(const bf16x8*)(Bb + 128);
        acc[0][0] = __builtin_amdgcn_mfma_f32_16x16x32_bf16(a[0][ks],b0,acc[0][0],0,0,0);
        acc[0][1] = __builtin_amdgcn_mfma_f32_16x16x32_bf16(a[0][ks],b1,acc[0][1],0,0,0);
        acc[1][0] = __builtin_amdgcn_mfma_f32_16x16x32_bf16(a[1][ks],b0,acc[1][0],0,0,0);
        acc[1][1] = __builtin_amdgcn_mfma_f32_16x16x32_bf16(a[1][ks],b1,acc[1][1],0,0,0);
      }
    }
    #pragma unroll
    for (int m=0;m<2;m++){
      #pragma unroll
      for (int j=0;j<4;j++){
        acc[m][0][j] += bv0; acc[m][1][j] += bv1;
        s0 += acc[m][0][j]; q0 += acc[m][0][j]*acc[m][0][j];
        s1 += acc[m][1][j]; q1 += acc[m][1][j]*acc[m][1][j];
      }
    }
    __syncthreads();   // previous f-tile's Ysh->global copy done
    #pragma unroll
    for (int m=0;m<2;m++){
      int fr = wid4*32 + m*16 + q*4;
      #pragma unroll
      for (int j=0;j<4;j++){
        Ysh[h*3072 + (fr+j)*24 + r] = f2b(acc[m][0][j]);
        if (r < 8) Ysh[h*3072 + (fr+j)*24 + 16 + r] = f2b(acc[m][1][j]);
      }
    }
    __syncthreads();
    const int4* sp = (const int4*)Ysh;
    for (int i = tid; i < 768; i += 512){
      int hh = (i >= 384) ? 1 : 0;
      int rem = i - hh*384;
      long Yb = ((long)((b*128 + t0 + hh)*512) + ft*128)*24;
      *(int4*)(Y + Yb + (long)rem*8) = sp[i];
    }
  }

  // block-wide stats reduction (once)
  #pragma unroll
  for (int off=16; off<=32; off<<=1){
    s0 += __shfl_xor(s0, off, 64); q0 += __shfl_xor(q0, off, 64);
    s1 += __shfl_xor(s1, off, 64); q1 += __shfl_xor(q1, off, 64);
  }
  if (q == 0){
    ssum[wid][r] = s0;     ssq[wid][r] = q0;
    ssum[wid][16+r] = s1;  ssq[wid][16+r] = q1;
  }
  __syncthreads();
  if (tid < 24){
    float as = 0, aq = 0;
    #pragma unroll
    for (int w2=0; w2<8; w2++){ as += ssum[w2][tid]; aq += ssq[w2][tid]; }
    g24s[tid] = as;
    g24q[tid] = aq;
  }
  __syncthreads();
  if (tid < 4){
    float as=0, aq=0;
    #pragma unroll
    for (int j=0;j<6;j++){ as += g24s[tid*6+j]; aq += g24q[tid*6+j]; }
    atomicAdd(&raw[b*4+tid], as);
    atomicAdd(&raw[16+b*4+tid], aq);
  }
}

// ---------------- normalize+relu: Y NHWC -> b72p channel slice (inline GN params) ----------------
__global__ __launch_bounds__(256)
void norm_relu_nhwc(const u16* __restrict__ Y, u16* __restrict__ dst, int coff,
                    const float* __restrict__ raw, const float* __restrict__ gw,
                    const float* __restrict__ gb, float invN){
  __shared__ float sA[24], sB[24];
  int bb = blockIdx.x / 768;
  if (threadIdx.x < 24){
    int g = bb*4 + threadIdx.x/6;
    float m = raw[g]*invN;
    float var = raw[16+g]*invN - m*m;
    float is = rsqrtf(var + EPS);
    float sc = is*gw[threadIdx.x];
    sA[threadIdx.x] = sc;
    sB[threadIdx.x] = gb[threadIdx.x] - m*sc;
  }
  __syncthreads();
  long e = ((long)blockIdx.x*256 + threadIdx.x)*8;
  int c0 = (int)(e % 24);
  long fi = e / 24;
  int f = (int)(fi & 511);
  int bt = (int)(fi >> 9); int t = bt & 127, b = bt >> 7;
  union {int4 q; u16 u[8];} pk; pk.q = *(const int4*)(Y + e);
  union {int4 q; u16 u[8];} o;
  #pragma unroll
  for (int j=0;j<8;j++){
    float v = b2f(pk.u[j])*sA[c0+j] + sB[c0+j];
    o.u[j] = f2b(v>0.f?v:0.f);
  }
  *(int4*)(dst + ((long)(b*130 + t+1)*514 + (f+1))*72 + coff + c0) = o.q;
}

// ---------------- normalize+relu + NHWC->CHW transpose (inline GN params) ----------------
__global__ __launch_bounds__(256)
void norm_relu_chw(const u16* __restrict__ Y, u16* __restrict__ xr,
                   const float* __restrict__ raw, const float* __restrict__ gw,
                   const float* __restrict__ gb, float invN){
  __shared__ u16 sh[24][520];
  __shared__ float sA[24], sB[24];
  int t = blockIdx.x & 127, b = blockIdx.x >> 7;
  if (threadIdx.x < 24){
    int g = b*4 + threadIdx.x/6;
    float m = raw[g]*invN;
    float var = raw[16+g]*invN - m*m;
    float is = rsqrtf(var + EPS);
    float sc = is*gw[threadIdx.x];
    sA[threadIdx.x] = sc;
    sB[threadIdx.x] = gb[threadIdx.x] - m*sc;
  }
  __syncthreads();
  const u16* src = Y + ((long)(b*128+t))*12288;
  for (int i = threadIdx.x; i < 1536; i += 256){
    int e = i*8; int c0 = e % 24; int f = e / 24;
    union {int4 q; u16 u[8];} pk; pk.q = *(const int4*)(src + e);
    #pragma unroll
    for (int j=0;j<8;j++){
      float v = b2f(pk.u[j])*sA[c0+j] + sB[c0+j];
      sh[c0+j][f] = f2b(v>0.f?v:0.f);
    }
  }
  __syncthreads();
  for (int i = threadIdx.x; i < 1536; i += 256){
    int c = i >> 6, fq = (i & 63)*8;
    union {int4 q; u16 u[8];} o;
    #pragma unroll
    for (int j=0;j<8;j++) o.u[j] = sh[c][fq+j];
    *(int4*)(xr + ((long)((b*24+c)*128 + t))*512 + fq) = o.q;
  }
}

// ---------------- elementwise normalize+relu on CHW rows (h1), inline GN params ----------------
__global__ __launch_bounds__(256)
void norm_chw(u16* __restrict__ h, const float* __restrict__ raw,
              const float* __restrict__ gw, const float* __restrict__ gb, float invN){
  __shared__ float s_sc, s_off;
  int bc = blockIdx.x / 12;
  if (threadIdx.x == 0){
    int b = bc/24, c = bc%24;
    int g = b*4 + c/6;
    float m = raw[g]*invN;
    float var = raw[16+g]*invN - m*m;
    float is = rsqrtf(var + EPS);
    float sc = is*gw[c];
    s_sc = sc;
    s_off = gb[c] - m*sc;
  }
  __syncthreads();
  float sc = s_sc, off = s_off;
  long e = ((long)blockIdx.x*256 + threadIdx.x)*8;
  union {int4 q; u16 u[8];} pk; pk.q = *(const int4*)(h + e);
  #pragma unroll
  for (int j=0;j<8;j++){ float v = b2f(pk.u[j])*sc + off; pk.u[j] = f2b(v>0.f?v:0.f); }
  *(int4*)(h + e) = pk.q;
}

// ---------------- gemm1: LDS-staged MFMA GEMM, depth-2 counted-vmcnt pipeline ----------------
template<int NF, bool STORE>
__global__ __launch_bounds__(256)
void gemm_lds(const u16* __restrict__ A, const u16* __restrict__ Bt, u16* __restrict__ C,
              int N, int K, int NBX, float* __restrict__ raw){
  constexpr int BN = NF*32;
  constexpr int BNP = BN + 4;
  constexpr int ABUF = 128*32;
  constexpr int BBUF = BN*32;
  __shared__ __align__(16) u16 SH[3*(ABUF+BBUF)];
  u16* Asb = SH;
  u16* Bsb = SH + 3*ABUF;
  int tid = threadIdx.x, wid = tid >> 6, l = tid & 63;
  int r = l & 15, q = l >> 4;
  int wr = wid >> 1, wc = wid & 1;
  int chunk = gridDim.x >> 3;
  int lin = (blockIdx.x & 7)*chunk + (blockIdx.x >> 3);
  int bx = lin % NBX, by = lin / NBX;
  long m0 = (long)by*128;
  int n0 = bx*BN;

  int arow[2], ach[2], aslot[2];
  #pragma unroll
  for (int j=0;j<2;j++){
    int idx = (wid*2+j)*64 + l;
    aslot[j] = idx*8;
    arow[j]  = ((idx>>6)<<4) | (idx & 15);
    ach[j]   = ((idx>>4) & 3)*8;
  }
  int brow[NF/2], bch[NF/2], bslot[NF/2];
  #pragma unroll
  for (int j=0;j<NF/2;j++){
    int idx = (wid*(NF/2)+j)*64 + l;
    bslot[j] = idx*8;
    brow[j]  = ((idx>>6)<<4) | (idx & 15);
    bch[j]   = ((idx>>4) & 3)*8;
  }

  f32x4 acc[4][NF];
  #pragma unroll
  for (int mf=0;mf<4;mf++)
    #pragma unroll
    for (int nf=0;nf<NF;nf++) acc[mf][nf] = (f32x4){0.f,0.f,0.f,0.f};

  int nt = K >> 5;
  #pragma unroll
  for (int j=0;j<2;j++)    gload16(A  + (m0+arow[j])*K + ach[j], Asb + aslot[j]);
  #pragma unroll
  for (int j=0;j<NF/2;j++) gload16(Bt + (long)(n0+brow[j])*K + bch[j], Bsb + bslot[j]);
  #pragma unroll
  for (int j=0;j<2;j++)    gload16(A  + (m0+arow[j])*K + 32 + ach[j], Asb + ABUF + aslot[j]);
  #pragma unroll
  for (int j=0;j<NF/2;j++) gload16(Bt + (long)(n0+brow[j])*K + 32 + bch[j], Bsb + BBUF + bslot[j]);

  int c0 = 0;
  for (int kt=0; kt<nt; kt++){
    if constexpr (NF==4) asm volatile("s_waitcnt vmcnt(4)" ::: "memory");
    else                 asm volatile("s_waitcnt vmcnt(3)" ::: "memory");
    __builtin_amdgcn_s_barrier();
    __builtin_amdgcn_sched_barrier(0);
    if (kt+2 < nt){
      int c2 = c0+2; if (c2>=3) c2-=3;
      int ko = (kt+2)*32;
      #pragma unroll
      for (int j=0;j<2;j++)    gload16(A  + (m0+arow[j])*K + ko + ach[j], Asb + c2*ABUF + aslot[j]);
      #pragma unroll
      for (int j=0;j<NF/2;j++) gload16(Bt + (long)(n0+brow[j])*K + ko + bch[j], Bsb + c2*BBUF + bslot[j]);
    }
    const u16* Ac = Asb + c0*ABUF;
    const u16* Bc = Bsb + c0*BBUF;
    bf16x8 af[4], bfv[NF];
    #pragma unroll
    for (int mf=0;mf<4;mf++) af[mf]  = *(const bf16x8*)(Ac + (((wr*4+mf)*4 + q)*16 + r)*8);
    #pragma unroll
    for (int nf=0;nf<NF;nf++) bfv[nf] = *(const bf16x8*)(Bc + (((wc*NF+nf)*4 + q)*16 + r)*8);
    #pragma unroll
    for (int mf=0;mf<4;mf++)
      #pragma unroll
      for (int nf=0;nf<NF;nf++)
        acc[mf][nf] = __builtin_amdgcn_mfma_f32_16x16x32_bf16(af[mf], bfv[nf], acc[mf][nf], 0,0,0);
    c0 = (c0+1==3) ? 0 : c0+1;
  }

  float s=0.f, ss=0.f;
  #pragma unroll
  for (int mf=0;mf<4;mf++)
    #pragma unroll
    for (int nf=0;nf<NF;nf++)
      #pragma unroll
      for (int j=0;j<4;j++){ float v = acc[mf][nf][j]; s += v; ss += v*v; }
  #pragma unroll
  for (int off=32; off>0; off>>=1){ s += __shfl_down(s,off,64); ss += __shfl_down(ss,off,64); }
  __shared__ float rs[4], rss[4];
  if (l==0){ rs[wid]=s; rss[wid]=ss; }
  __syncthreads();
  if (tid==0){
    int bc = (int)(m0 >> 7);
    int g = (bc/24)*4 + (bc%24)/6;
    atomicAdd(&raw[g],    rs[0]+rs[1]+rs[2]+rs[3]);
    atomicAdd(&raw[16+g], rss[0]+rss[1]+rss[2]+rss[3]);
  }

  if constexpr (STORE){
    #pragma unroll
    for (int mf=0;mf<4;mf++){
      int row = wr*64 + mf*16 + q*4;
      #pragma unroll
      for (int nf=0;nf<NF;nf++){
        int col = wc*(NF*16) + nf*16 + r;
        #pragma unroll
        for (int j=0;j<4;j++)
          SH[(row+j)*BNP + col] = f2b(acc[mf][nf][j]);
      }
    }
    __syncthreads();
    constexpr int RPT = BN/16;
    #pragma unroll
    for (int k=0;k<RPT;k++){
      int j = tid + k*256;
      int row = j / (BN/8), col8 = (j % (BN/8))*8;
      *(int4*)(C + (m0+row)*N + n0 + col8) = *(const int4*)(SH + row*BNP + col8);
    }
  }
}

// ---------------- gemm2 w8: 512 threads, 8 waves (2x4), tile 128x128, depth-2 vmcnt ring ----------------
__global__ __launch_bounds__(512)
void gemm2_w8(const u16* __restrict__ A, const u16* __restrict__ Bt, u16* __restrict__ C,
              float* __restrict__ raw){
  const int K = 192, N = 3072;
  constexpr int SB = 128*32;
  __shared__ __align__(16) u16 SH[6*SB];
  __shared__ float rs[8], rss[8];
  u16* Asb = SH;
  u16* Bsb = SH + 3*SB;
  int tid = threadIdx.x, wid = tid >> 6, l = tid & 63;
  int r = l & 15, q = l >> 4;
  int wr = wid >> 2, wc = wid & 3;
  int chunk = gridDim.x >> 3;
  int lin = (blockIdx.x & 7)*chunk + (blockIdx.x >> 3);
  int bx = lin % 24, by = lin / 24;
  long m0 = (long)by*128;
  int n0 = bx*128;

  int srow = ((tid>>6)<<4) | (tid & 15);
  int sch  = ((tid>>4) & 3)*8;
  int sslot = tid*8;

  f32x4 acc[4][2];
  #pragma unroll
  for (int mf=0;mf<4;mf++){ acc[mf][0] = (f32x4){0.f,0.f,0.f,0.f}; acc[mf][1] = (f32x4){0.f,0.f,0.f,0.f}; }

  gload16(A  + (m0+srow)*K + sch,          Asb + sslot);
  gload16(Bt + (long)(n0+srow)*K + sch,    Bsb + sslot);
  gload16(A  + (m0+srow)*K + 32 + sch,     Asb + SB + sslot);
  gload16(Bt + (long)(n0+srow)*K + 32 + sch, Bsb + SB + sslot);

  int c0 = 0;
  for (int kt=0; kt<6; kt++){
    asm volatile("s_waitcnt vmcnt(2)" ::: "memory");
    __builtin_amdgcn_s_barrier();
    __builtin_amdgcn_sched_barrier(0);
    if (kt+2 < 6){
      int c2 = c0+2; if (c2>=3) c2-=3;
      int ko = (kt+2)*32;
      gload16(A  + (m0+srow)*K + ko + sch,       Asb + c2*SB + sslot);
      gload16(Bt + (long)(n0+srow)*K + ko + sch, Bsb + c2*SB + sslot);
    }
    const u16* Ac = Asb + c0*SB;
    const u16* Bc = Bsb + c0*SB;
    bf16x8 af[4], bfv[2];
    #pragma unroll
    for (int mf=0;mf<4;mf++) af[mf]  = *(const bf16x8*)(Ac + (((wr*4+mf)*4 + q)*16 + r)*8);
    #pragma unroll
    for (int nf=0;nf<2;nf++) bfv[nf] = *(const bf16x8*)(Bc + (((wc*2+nf)*4 + q)*16 + r)*8);
    #pragma unroll
    for (int mf=0;mf<4;mf++){
      acc[mf][0] = __builtin_amdgcn_mfma_f32_16x16x32_bf16(af[mf], bfv[0], acc[mf][0], 0,0,0);
      acc[mf][1] = __builtin_amdgcn_mfma_f32_16x16x32_bf16(af[mf], bfv[1], acc[mf][1], 0,0,0);
    }
    c0 = (c0+1==3) ? 0 : c0+1;
  }

  float s=0.f, ss=0.f;
  #pragma unroll
  for (int mf=0;mf<4;mf++)
    #pragma unroll
    for (int nf=0;nf<2;nf++)
      #pragma unroll
      for (int j=0;j<4;j++){ float v = acc[mf][nf][j]; s += v; ss += v*v; }
  #pragma unroll
  for (int off=32; off>0; off>>=1){ s += __shfl_down(s,off,64); ss += __shfl_down(ss,off,64); }
  if (l==0){ rs[wid]=s; rss[wid]=ss; }
  __syncthreads();
  if (tid==0){
    float as=0, aq=0;
    #pragma unroll
    for (int j=0;j<8;j++){ as += rs[j]; aq += rss[j]; }
    int bc = (int)(m0 >> 7);
    int g = (bc/24)*4 + (bc%24)/6;
    atomicAdd(&raw[g], as);
    atomicAdd(&raw[16+g], aq);
  }

  #pragma unroll
  for (int mf=0;mf<4;mf++){
    int row = wr*64 + mf*16 + q*4;
    #pragma unroll
    for (int nf=0;nf<2;nf++){
      int col = wc*32 + nf*16 + r;
      #pragma unroll
      for (int j=0;j<4;j++)
        SH[(row+j)*132 + col] = f2b(acc[mf][nf][j]);
    }
  }
  __syncthreads();
  #pragma unroll
  for (int k=0;k<4;k++){
    int j = tid + k*512;
    int row = j >> 4, col8 = (j & 15)*8;
    *(int4*)(C + (m0+row)*N + n0 + col8) = *(const int4*)(SH + row*132 + col8);
  }
}

// ---------------- final: out(fp32) = x_ + sum_n relu(gn2(h2))[...,n]*att[b,n] (inline GN) ----------------
__global__ __launch_bounds__(256)
void final_mix(const u16* __restrict__ h2, const u16* __restrict__ xr,
               const float* __restrict__ raw, const float* __restrict__ gw,
               const float* __restrict__ gb, float invN,
               const float* __restrict__ att, float* __restrict__ out){
  __shared__ float s_sc, s_off, s_att[6];
  int bc0 = blockIdx.x / 64;
  int c  = bc0 % 24, b = bc0 / 24;
  if (threadIdx.x == 0){
    int g = b*4 + c/6;
    float m = raw[g]*invN;
    float var = raw[16+g]*invN - m*m;
    float is = rsqrtf(var + EPS);
    float sc = is*gw[c];
    s_sc = sc;
    s_off = gb[c] - m*sc;
  }
  if (threadIdx.x < 6) s_att[threadIdx.x] = att[b*6+threadIdx.x];
  __syncthreads();
  float sc = s_sc, off = s_off;
  float a[6];
  #pragma unroll
  for (int n=0;n<6;n++) a[n] = s_att[n];

  int gid = blockIdx.x*256 + threadIdx.x;
  int fq = gid & 127;
  int t  = (gid >> 7) & 127;
  int bc = gid >> 14;

  long hbase = (((long)bc*Tn + t))*3072 + (long)fq*24;
  union { int4 v[3]; u16 u[24]; } hv;
  const int4* hp = (const int4*)(h2 + hbase);
  hv.v[0]=hp[0]; hv.v[1]=hp[1]; hv.v[2]=hp[2];

  long xbase = (((long)bc*Tn + t))*Fn + (long)fq*4;
  union { unsigned long long q; u16 u[4]; } xv;
  xv.q = *(const unsigned long long*)(xr + xbase);

  float4 ov;
  float* op = &ov.x;
  #pragma unroll
  for (int j=0;j<4;j++){
    float accv = b2f(xv.u[j]);
    #pragma unroll
    for (int n=0;n<6;n++){
      float hvf = b2f(hv.u[j*6+n])*sc + off;
      hvf = hvf > 0.f ? hvf : 0.f;
      accv += hvf * a[n];
    }
    op[j] = accv;
  }
  *(float4*)(out + xbase) = ov;
}

extern "C" void kernel_launch(void* const* d_in, const int* in_sizes, int n_in,
                              void* d_out, int out_size, void* d_ws, size_t ws_size,
                              hipStream_t stream){
  const float* x   = (const float*)d_in[0];
  const float* c   = (const float*)d_in[1];
  const float* cw0 = (const float*)d_in[2];  const float* cb0 = (const float*)d_in[3];
  const float* gw0 = (const float*)d_in[4];  const float* gb0 = (const float*)d_in[5];
  const float* cw1 = (const float*)d_in[6];  const float* cb1 = (const float*)d_in[7];
  const float* gw1 = (const float*)d_in[8];  const float* gb1 = (const float*)d_in[9];
  const float* cw2 = (const float*)d_in[10]; const float* cb2 = (const float*)d_in[11];
  const float* gw2 = (const float*)d_in[12]; const float* gb2 = (const float*)d_in[13];
  const float* tw1 = (const float*)d_in[14]; const float* tg1w= (const float*)d_in[15]; const float* tg1b=(const float*)d_in[16];
  const float* tw2 = (const float*)d_in[17]; const float* tg2w= (const float*)d_in[18]; const float* tg2b=(const float*)d_in[19];
  const float* wqp = (const float*)d_in[20]; const float* bqp = (const float*)d_in[21]; const float* keys=(const float*)d_in[22];

  char* ws = (char*)d_ws;
  u16*   xr     = (u16*)(ws + 0);               // 12,582,912 B  [12288,512] bf16 CHW
  u16*   h1     = (u16*)(ws + 12582912);        //  4,718,592 B  [12288,192]
  u16*   tw1b   = (u16*)(ws + 17301504);        //    196,608 B
  u16*   tw2b   = (u16*)(ws + 17498112);        //  1,179,648 B
  float* stats5 = (float*)(ws + 18677760);      //        128 B
  float* att    = (float*)(ws + 18678656);      //        128 B
  // ---- h2 span (reused during conv phase) ----
  u16*   h2     = (u16*)(ws + 18680832);        // 75,497,472 B  [12288,3072]
  u16*   Y      = (u16*)(ws + 18680832);        // 12,582,912 B  NHWC conv out [4,128,512,24]
  u16*   b72p   = (u16*)(ws + 31263744);        // 38,488,320 B  NHWC padded [4,130,514,72]
  u16*   xc24   = (u16*)(ws + 69752064);        // 12,829,440 B (+256 slack) NHWC padded [4,130,514,24]
  float* stats14= (float*)(ws + 82581760);      //        512 B
  u16*   wr0    = (u16*)(ws + 82585344);        //     18,432 B
  u16*   wr1    = (u16*)(ws + 82603776);        //     36,864 B
  u16*   wr2    = (u16*)(ws + 82640640);        //     43,008 B

  // ---- fused prologue (1 launch) ----
  prep_all<<<1570,256,0,stream>>>(x, b72p, xc24, tw1, tw1b, tw2, tw2b,
                                  cw0, wr0, cw1, wr1, cw2, wr2,
                                  stats14, stats5, c, wqp, bqp, keys, att);

  // ---- conv block 0 ----
  conv_mfma<96,24><<<512,512,0,stream>>>(xc24, 0, wr0, cb0, Y, stats14+0);
  norm_relu_nhwc<<<3072,256,0,stream>>>(Y, b72p, 24, stats14+0, gw0, gb0, 1.f/393216.f);

  // ---- conv block 1 ----
  conv_mfma<192,72><<<512,512,0,stream>>>(b72p, 24, wr1, cb1, Y, stats14+32);
  norm_relu_nhwc<<<3072,256,0,stream>>>(Y, b72p, 0, stats14+32, gw1, gb1, 1.f/393216.f);

  // ---- conv block 2 -> xr (CHW) ----
  conv_mfma<224,72><<<512,512,0,stream>>>(b72p, 0, wr2, cb2, Y, stats14+64);
  norm_relu_chw<<<512,256,0,stream>>>(Y, xr, stats14+64, gw2, gb2, 1.f/393216.f);

  // ---- TDF: gemm1 (12288x192x512) + GN + relu ----
  gemm_lds<2,true><<<288,256,0,stream>>>(xr, tw1b, h1, 192, 512, 3, stats14+96);
  norm_chw<<<1152,256,0,stream>>>(h1, stats14+96, tg1w, tg1b, 1.f/147456.f);

  // ---- TDF: gemm2 (12288x3072x192), 8-wave 128x128 ----
  gemm2_w8<<<2304,512,0,stream>>>(h1, tw2b, h2, stats5);

  // ---- final mix (inline GN2 params) ----
  final_mix<<<6144,256,0,stream>>>(h2, xr, stats5, tg2w, tg2b, 1.f/2359296.f, att, (float*)d_out);
}

// Round 21
// 189.814 us; speedup vs baseline: 1.2947x; 1.0070x over previous
//
#include <hip/hip_runtime.h>
#include <hip/hip_bf16.h>

typedef unsigned short u16;
typedef unsigned int u32;

#define Tn 128
#define Fn 512
#define HWc (Tn*Fn)
#define EPS 1e-5f

using bf16x8 = __attribute__((ext_vector_type(8))) short;
using f32x4  = __attribute__((ext_vector_type(4))) float;

__device__ __forceinline__ float b2f(u16 x){ return __uint_as_float(((u32)x)<<16); }
__device__ __forceinline__ u16 f2b(float f){
  __hip_bfloat16 h = __float2bfloat16(f);
  return *reinterpret_cast<u16*>(&h);
}

// async global->LDS, 16B per lane
__device__ __forceinline__ void gload16(const u16* g, u16* l){
  __builtin_amdgcn_global_load_lds((const __attribute__((address_space(1))) void*)g,
                                   (__attribute__((address_space(3))) void*)l, 16, 0, 0);
}

// ---------------- prep_all: fused prologue (grid 1522) ----------------
// [0,512) copy_x2 | [512,1088) cvt tw2 | [1088,1184) cvt tw1 | [1184,1312) border b72p
// [1312,1376) border xc24 | [1376,1403) wr0 | [1403,1457) wr1 | [1457,1520) wr2
// 1520 zero stats | 1521 attention
__global__ __launch_bounds__(256)
void prep_all(const float* __restrict__ x, u16* __restrict__ b72p, u16* __restrict__ xc24,
              const float* __restrict__ tw1, u16* __restrict__ tw1b,
              const float* __restrict__ tw2, u16* __restrict__ tw2b,
              const float* __restrict__ cw0, u16* __restrict__ wr0,
              const float* __restrict__ cw1, u16* __restrict__ wr1,
              const float* __restrict__ cw2, u16* __restrict__ wr2,
              float* __restrict__ stats14, float* __restrict__ stats5,
              const float* __restrict__ cc, const float* __restrict__ wq,
              const float* __restrict__ bq, const float* __restrict__ keys,
              float* __restrict__ att){
  __shared__ __align__(16) char smem[24*520*2];
  int bid = blockIdx.x, tid = threadIdx.x;

  if (bid < 512){
    u16 (*sh)[520] = (u16(*)[520])smem;
    int t = bid & 127, b = bid >> 7;
    const float* src = x + ((long)(b*24)*128 + t)*512;
    for (int c=0; c<24; c++){
      float2 v = *(const float2*)(src + (long)c*65536 + tid*2);
      sh[c][tid*2]   = f2b(v.x);
      sh[c][tid*2+1] = f2b(v.y);
    }
    __syncthreads();
    long r72 = ((long)(b*130 + t+1))*514*72;
    long r24 = ((long)(b*130 + t+1))*514*24;
    for (int i = tid; i < 1536; i += 256){
      int f = i/3, c0 = (i%3)*8;
      union {int4 q; u16 u[8];} o;
      #pragma unroll
      for (int j=0;j<8;j++) o.u[j] = sh[c0+j][f];
      *(int4*)(b72p + r72 + (long)(f+1)*72 + 48 + c0) = o.q;
      *(int4*)(xc24 + r24 + (long)(f+1)*24 + c0) = o.q;
    }
  } else if (bid < 1088){
    int i = ((bid-512)*256 + tid)*4;
    float4 v = *(const float4*)(tw2 + i);
    ushort4 o;
    o.x=f2b(v.x); o.y=f2b(v.y); o.z=f2b(v.z); o.w=f2b(v.w);
    *(ushort4*)(tw2b + i) = o;
  } else if (bid < 1184){
    int i = ((bid-1088)*256 + tid)*4;
    float4 v = *(const float4*)(tw1 + i);
    ushort4 o;
    o.x=f2b(v.x); o.y=f2b(v.y); o.z=f2b(v.z); o.w=f2b(v.w);
    *(ushort4*)(tw1b + i) = o;
  } else if (bid < 1312){
    int sub = bid - 1184;
    int b = sub >> 5, j = sub & 31;
    u16* base = b72p + (long)b*130*514*72;
    int rowN = 514*72;
    for (int i = j*256 + tid; i < rowN; i += 32*256){
      base[i] = 0;
      base[(long)129*rowN + i] = 0;
    }
    int colN = 128*72;
    for (int i = j*256 + tid; i < colN; i += 32*256){
      int row = 1 + i/72, ch = i - (i/72)*72;
      base[((long)row*514 + 0)*72 + ch] = 0;
      base[((long)row*514 + 513)*72 + ch] = 0;
    }
  } else if (bid < 1376){
    int sub = bid - 1312;
    int b = sub >> 4, j = sub & 15;
    u16* base = xc24 + (long)b*130*514*24;
    int rowN = 514*24;
    for (int i = j*256 + tid; i < rowN; i += 16*256){
      base[i] = 0;
      base[(long)129*rowN + i] = 0;
    }
    int colN = 128*24;
    for (int i = j*256 + tid; i < colN; i += 16*256){
      int row = 1 + i/24, ch = i - (i/24)*24;
      base[((long)row*514 + 0)*24 + ch] = 0;
      base[((long)row*514 + 513)*24 + ch] = 0;
    }
  } else if (bid < 1520){
    // compact 24-row fragment order: wr[dt][NK][q:4][o:24][e:8]
    const float* w; u16* wr; int CIN, cs, cof, KP, sub;
    if (bid < 1403){ sub = bid-1376; w = cw0; wr = wr0; CIN=24; cs=24; cof=0;  KP=96;  }
    else if (bid < 1457){ sub = bid-1403; w = cw1; wr = wr1; CIN=48; cs=72; cof=24; KP=192; }
    else { sub = bid-1457; w = cw2; wr = wr2; CIN=72; cs=72; cof=0;  KP=224; }
    int i = sub*256 + tid;
    int NK = KP >> 5;
    int tot = 72*KP;
    if (i < tot){
      int e  = i & 7;
      int rest = i >> 3;
      int o  = rest % 24;  rest /= 24;
      int q  = rest & 3;   rest >>= 2;
      int ks = rest % NK;
      int dt = rest / NK;
      int k = ks*32 + q*8 + e;
      float v = 0.f;
      int g = cof + k, df = g/cs, ch = g - df*cs;
      if (df < 3 && ch >= cof && ch < cof+CIN)
        v = w[((o*CIN + (ch-cof))*3 + dt)*3 + df];
      wr[i] = f2b(v);
    }
  } else if (bid == 1520){
    if (tid < 128) stats14[tid] = 0.f;
    else if (tid < 160) stats5[tid-128] = 0.f;
  } else {
    float (*qs)[32] = (float(*)[32])smem;
    float (*ss)[6]  = (float(*)[6])(smem + 4*32*4);
    int t = tid;
    if (t < 128){
      int b = t >> 5, k = t & 31;
      float a = bq[k];
      for (int j=0;j<32;j++) a += cc[b*32+j] * wq[k*32+j];
      qs[b][k] = a;
    }
    __syncthreads();
    if (t < 24){
      int b = t/6, n = t%6;
      float a = 0.f;
      for (int k=0;k<32;k++) a += qs[b][k]*keys[k*6+n];
      ss[b][n] = a * 0.17677669529663689f;
    }
    __syncthreads();
    if (t < 4){
      float mx = -1e30f;
      for (int n=0;n<6;n++) mx = fmaxf(mx, ss[t][n]);
      float e[6], sm=0.f;
      for (int n=0;n<6;n++){ e[n]=expf(ss[t][n]-mx); sm+=e[n]; }
      for (int n=0;n<6;n++) att[t*6+n] = e[n]/sm;
    }
  }
}

// ---------------- MFMA implicit-GEMM 3x3 conv v13: v12 structure + compact 24-row WS ----------------
// 512 threads, 2 t-rows x 2 f-tiles, grid 512. LDS ~47 KB -> 3 blocks/CU = 24 waves/CU.
template<int KP, int CS>
__global__ __launch_bounds__(512)
void conv_mfma(const u16* __restrict__ X, int coff, const u16* __restrict__ WR,
               const float* __restrict__ bias, u16* __restrict__ Y,
               float* __restrict__ raw){
  constexpr int NK = KP/32;
  __shared__ u16 WS[72*KP + 128];
  __shared__ float ssum[8][32], ssq[8][32];
  __shared__ float g24s[24], g24q[24];
  __shared__ __align__(16) u16 Ysh[2*128*24];
  int bid = (blockIdx.x & 7)*64 + (blockIdx.x >> 3);   // grid 512, chunk 64
  int ftg = bid >> 8, b = (bid >> 6) & 3, t0 = (bid & 63)*2;
  int tid = threadIdx.x, wid = tid >> 6, l = tid & 63;
  int r = l & 15, q = l >> 4;
  int h = wid >> 2;            // half: t = t0 + h
  int wid4 = wid & 3;
  int t = t0 + h;

  for (int i = tid*8; i < 72*KP; i += 4096)
    *(int4*)(WS + i) = *(const int4*)(WR + i);
  if (tid < 16) *(int4*)(WS + 72*KP + tid*8) = (int4){0,0,0,0};

  float bv0 = bias[r];
  float bv1 = (r < 8) ? bias[16+r] : 0.f;
  float s0=0,q0=0,s1=0,q1=0;
  __syncthreads();

  #pragma unroll
  for (int fi=0; fi<2; fi++){
    int ft = ftg*2 + fi;
    int f0w = ft*128 + wid4*32;
    f32x4 acc[2][2] = {};
    #pragma unroll
    for (int dt=0; dt<3; dt++){
      const u16* Ab = X + ((long)((b*130 + t+dt)*514 + f0w + r))*CS + coff + q*8;
      bf16x8 a[2][NK];
      #pragma unroll
      for (int ks=0; ks<NK; ks++){
        a[0][ks] = *(const bf16x8*)(Ab + ks*32);
        a[1][ks] = *(const bf16x8*)(Ab + (long)16*CS + ks*32);
      }
      #pragma unroll
      for (int ks=0; ks<NK; ks++){
        const u16* Bb = WS + ((dt*NK + ks)*4 + q)*192 + r*8;
        bf16x8 b0 = *(const bf16x8*)(Bb);
        bf16x8 b1 = *(const bf16x8*)(Bb + 128);   // rows 16..23 (+contained garbage r>=8)
        acc[0][0] = __builtin_amdgcn_mfma_f32_16x16x32_bf16(a[0][ks],b0,acc[0][0],0,0,0);
        acc[0][1] = __builtin_amdgcn_mfma_f32_16x16x32_bf16(a[0][ks],b1,acc[0][1],0,0,0);
        acc[1][0] = __builtin_amdgcn_mfma_f32_16x16x32_bf16(a[1][ks],b0,acc[1][0],0,0,0);
        acc[1][1] = __builtin_amdgcn_mfma_f32_16x16x32_bf16(a[1][ks],b1,acc[1][1],0,0,0);
      }
    }
    #pragma unroll
    for (int m=0;m<2;m++){
      #pragma unroll
      for (int j=0;j<4;j++){
        acc[m][0][j] += bv0; acc[m][1][j] += bv1;
        s0 += acc[m][0][j]; q0 += acc[m][0][j]*acc[m][0][j];
        s1 += acc[m][1][j]; q1 += acc[m][1][j]*acc[m][1][j];
      }
    }
    __syncthreads();   // previous f-tile's Ysh->global copy done
    #pragma unroll
    for (int m=0;m<2;m++){
      int fr = wid4*32 + m*16 + q*4;
      #pragma unroll
      for (int j=0;j<4;j++){
        Ysh[h*3072 + (fr+j)*24 + r] = f2b(acc[m][0][j]);
        if (r < 8) Ysh[h*3072 + (fr+j)*24 + 16 + r] = f2b(acc[m][1][j]);
      }
    }
    __syncthreads();
    const int4* sp = (const int4*)Ysh;
    for (int i = tid; i < 768; i += 512){
      int hh = (i >= 384) ? 1 : 0;
      int rem = i - hh*384;
      long Yb = ((long)((b*128 + t0 + hh)*512) + ft*128)*24;
      *(int4*)(Y + Yb + (long)rem*8) = sp[i];
    }
  }

  // block-wide stats reduction (garbage from b1/r>=8 lands in unread slots 24..31)
  #pragma unroll
  for (int off=16; off<=32; off<<=1){
    s0 += __shfl_xor(s0, off, 64); q0 += __shfl_xor(q0, off, 64);
    s1 += __shfl_xor(s1, off, 64); q1 += __shfl_xor(q1, off, 64);
  }
  if (q == 0){
    ssum[wid][r] = s0;     ssq[wid][r] = q0;
    ssum[wid][16+r] = s1;  ssq[wid][16+r] = q1;
  }
  __syncthreads();
  if (tid < 24){
    float as = 0, aq = 0;
    #pragma unroll
    for (int w2=0; w2<8; w2++){ as += ssum[w2][tid]; aq += ssq[w2][tid]; }
    g24s[tid] = as;
    g24q[tid] = aq;
  }
  __syncthreads();
  if (tid < 4){
    float as=0, aq=0;
    #pragma unroll
    for (int j=0;j<6;j++){ as += g24s[tid*6+j]; aq += g24q[tid*6+j]; }
    atomicAdd(&raw[b*4+tid], as);
    atomicAdd(&raw[16+b*4+tid], aq);
  }
}

// ---------------- normalize+relu: Y NHWC -> b72p channel slice (inline GN params) ----------------
__global__ __launch_bounds__(256)
void norm_relu_nhwc(const u16* __restrict__ Y, u16* __restrict__ dst, int coff,
                    const float* __restrict__ raw, const float* __restrict__ gw,
                    const float* __restrict__ gb, float invN){
  __shared__ float sA[24], sB[24];
  int bb = blockIdx.x / 768;
  if (threadIdx.x < 24){
    int g = bb*4 + threadIdx.x/6;
    float m = raw[g]*invN;
    float var = raw[16+g]*invN - m*m;
    float is = rsqrtf(var + EPS);
    float sc = is*gw[threadIdx.x];
    sA[threadIdx.x] = sc;
    sB[threadIdx.x] = gb[threadIdx.x] - m*sc;
  }
  __syncthreads();
  long e = ((long)blockIdx.x*256 + threadIdx.x)*8;
  int c0 = (int)(e % 24);
  long fi = e / 24;
  int f = (int)(fi & 511);
  int bt = (int)(fi >> 9); int t = bt & 127, b = bt >> 7;
  union {int4 q; u16 u[8];} pk; pk.q = *(const int4*)(Y + e);
  union {int4 q; u16 u[8];} o;
  #pragma unroll
  for (int j=0;j<8;j++){
    float v = b2f(pk.u[j])*sA[c0+j] + sB[c0+j];
    o.u[j] = f2b(v>0.f?v:0.f);
  }
  *(int4*)(dst + ((long)(b*130 + t+1)*514 + (f+1))*72 + coff + c0) = o.q;
}

// ---------------- normalize+relu + NHWC->CHW transpose (inline GN params) ----------------
__global__ __launch_bounds__(256)
void norm_relu_chw(const u16* __restrict__ Y, u16* __restrict__ xr,
                   const float* __restrict__ raw, const float* __restrict__ gw,
                   const float* __restrict__ gb, float invN){
  __shared__ u16 sh[24][520];
  __shared__ float sA[24], sB[24];
  int t = blockIdx.x & 127, b = blockIdx.x >> 7;
  if (threadIdx.x < 24){
    int g = b*4 + threadIdx.x/6;
    float m = raw[g]*invN;
    float var = raw[16+g]*invN - m*m;
    float is = rsqrtf(var + EPS);
    float sc = is*gw[threadIdx.x];
    sA[threadIdx.x] = sc;
    sB[threadIdx.x] = gb[threadIdx.x] - m*sc;
  }
  __syncthreads();
  const u16* src = Y + ((long)(b*128+t))*12288;
  for (int i = threadIdx.x; i < 1536; i += 256){
    int e = i*8; int c0 = e % 24; int f = e / 24;
    union {int4 q; u16 u[8];} pk; pk.q = *(const int4*)(src + e);
    #pragma unroll
    for (int j=0;j<8;j++){
      float v = b2f(pk.u[j])*sA[c0+j] + sB[c0+j];
      sh[c0+j][f] = f2b(v>0.f?v:0.f);
    }
  }
  __syncthreads();
  for (int i = threadIdx.x; i < 1536; i += 256){
    int c = i >> 6, fq = (i & 63)*8;
    union {int4 q; u16 u[8];} o;
    #pragma unroll
    for (int j=0;j<8;j++) o.u[j] = sh[c][fq+j];
    *(int4*)(xr + ((long)((b*24+c)*128 + t))*512 + fq) = o.q;
  }
}

// ---------------- elementwise normalize+relu on CHW rows (h1), inline GN params ----------------
__global__ __launch_bounds__(256)
void norm_chw(u16* __restrict__ h, const float* __restrict__ raw,
              const float* __restrict__ gw, const float* __restrict__ gb, float invN){
  __shared__ float s_sc, s_off;
  int bc = blockIdx.x / 12;
  if (threadIdx.x == 0){
    int b = bc/24, c = bc%24;
    int g = b*4 + c/6;
    float m = raw[g]*invN;
    float var = raw[16+g]*invN - m*m;
    float is = rsqrtf(var + EPS);
    float sc = is*gw[c];
    s_sc = sc;
    s_off = gb[c] - m*sc;
  }
  __syncthreads();
  float sc = s_sc, off = s_off;
  long e = ((long)blockIdx.x*256 + threadIdx.x)*8;
  union {int4 q; u16 u[8];} pk; pk.q = *(const int4*)(h + e);
  #pragma unroll
  for (int j=0;j<8;j++){ float v = b2f(pk.u[j])*sc + off; pk.u[j] = f2b(v>0.f?v:0.f); }
  *(int4*)(h + e) = pk.q;
}

// ---------------- gemm1: LDS-staged MFMA GEMM, depth-2 counted-vmcnt pipeline ----------------
template<int NF, bool STORE>
__global__ __launch_bounds__(256)
void gemm_lds(const u16* __restrict__ A, const u16* __restrict__ Bt, u16* __restrict__ C,
              int N, int K, int NBX, float* __restrict__ raw){
  constexpr int BN = NF*32;
  constexpr int BNP = BN + 4;
  constexpr int ABUF = 128*32;
  constexpr int BBUF = BN*32;
  __shared__ __align__(16) u16 SH[3*(ABUF+BBUF)];
  u16* Asb = SH;
  u16* Bsb = SH + 3*ABUF;
  int tid = threadIdx.x, wid = tid >> 6, l = tid & 63;
  int r = l & 15, q = l >> 4;
  int wr = wid >> 1, wc = wid & 1;
  int chunk = gridDim.x >> 3;
  int lin = (blockIdx.x & 7)*chunk + (blockIdx.x >> 3);
  int bx = lin % NBX, by = lin / NBX;
  long m0 = (long)by*128;
  int n0 = bx*BN;

  int arow[2], ach[2], aslot[2];
  #pragma unroll
  for (int j=0;j<2;j++){
    int idx = (wid*2+j)*64 + l;
    aslot[j] = idx*8;
    arow[j]  = ((idx>>6)<<4) | (idx & 15);
    ach[j]   = ((idx>>4) & 3)*8;
  }
  int brow[NF/2], bch[NF/2], bslot[NF/2];
  #pragma unroll
  for (int j=0;j<NF/2;j++){
    int idx = (wid*(NF/2)+j)*64 + l;
    bslot[j] = idx*8;
    brow[j]  = ((idx>>6)<<4) | (idx & 15);
    bch[j]   = ((idx>>4) & 3)*8;
  }

  f32x4 acc[4][NF];
  #pragma unroll
  for (int mf=0;mf<4;mf++)
    #pragma unroll
    for (int nf=0;nf<NF;nf++) acc[mf][nf] = (f32x4){0.f,0.f,0.f,0.f};

  int nt = K >> 5;
  #pragma unroll
  for (int j=0;j<2;j++)    gload16(A  + (m0+arow[j])*K + ach[j], Asb + aslot[j]);
  #pragma unroll
  for (int j=0;j<NF/2;j++) gload16(Bt + (long)(n0+brow[j])*K + bch[j], Bsb + bslot[j]);
  #pragma unroll
  for (int j=0;j<2;j++)    gload16(A  + (m0+arow[j])*K + 32 + ach[j], Asb + ABUF + aslot[j]);
  #pragma unroll
  for (int j=0;j<NF/2;j++) gload16(Bt + (long)(n0+brow[j])*K + 32 + bch[j], Bsb + BBUF + bslot[j]);

  int c0 = 0;
  for (int kt=0; kt<nt; kt++){
    if constexpr (NF==4) asm volatile("s_waitcnt vmcnt(4)" ::: "memory");
    else                 asm volatile("s_waitcnt vmcnt(3)" ::: "memory");
    __builtin_amdgcn_s_barrier();
    __builtin_amdgcn_sched_barrier(0);
    if (kt+2 < nt){
      int c2 = c0+2; if (c2>=3) c2-=3;
      int ko = (kt+2)*32;
      #pragma unroll
      for (int j=0;j<2;j++)    gload16(A  + (m0+arow[j])*K + ko + ach[j], Asb + c2*ABUF + aslot[j]);
      #pragma unroll
      for (int j=0;j<NF/2;j++) gload16(Bt + (long)(n0+brow[j])*K + ko + bch[j], Bsb + c2*BBUF + bslot[j]);
    }
    const u16* Ac = Asb + c0*ABUF;
    const u16* Bc = Bsb + c0*BBUF;
    bf16x8 af[4], bfv[NF];
    #pragma unroll
    for (int mf=0;mf<4;mf++) af[mf]  = *(const bf16x8*)(Ac + (((wr*4+mf)*4 + q)*16 + r)*8);
    #pragma unroll
    for (int nf=0;nf<NF;nf++) bfv[nf] = *(const bf16x8*)(Bc + (((wc*NF+nf)*4 + q)*16 + r)*8);
    #pragma unroll
    for (int mf=0;mf<4;mf++)
      #pragma unroll
      for (int nf=0;nf<NF;nf++)
        acc[mf][nf] = __builtin_amdgcn_mfma_f32_16x16x32_bf16(af[mf], bfv[nf], acc[mf][nf], 0,0,0);
    c0 = (c0+1==3) ? 0 : c0+1;
  }

  float s=0.f, ss=0.f;
  #pragma unroll
  for (int mf=0;mf<4;mf++)
    #pragma unroll
    for (int nf=0;nf<NF;nf++)
      #pragma unroll
      for (int j=0;j<4;j++){ float v = acc[mf][nf][j]; s += v; ss += v*v; }
  #pragma unroll
  for (int off=32; off>0; off>>=1){ s += __shfl_down(s,off,64); ss += __shfl_down(ss,off,64); }
  __shared__ float rs[4], rss[4];
  if (l==0){ rs[wid]=s; rss[wid]=ss; }
  __syncthreads();
  if (tid==0){
    int bc = (int)(m0 >> 7);
    int g = (bc/24)*4 + (bc%24)/6;
    atomicAdd(&raw[g],    rs[0]+rs[1]+rs[2]+rs[3]);
    atomicAdd(&raw[16+g], rss[0]+rss[1]+rss[2]+rss[3]);
  }

  if constexpr (STORE){
    #pragma unroll
    for (int mf=0;mf<4;mf++){
      int row = wr*64 + mf*16 + q*4;
      #pragma unroll
      for (int nf=0;nf<NF;nf++){
        int col = wc*(NF*16) + nf*16 + r;
        #pragma unroll
        for (int j=0;j<4;j++)
          SH[(row+j)*BNP + col] = f2b(acc[mf][nf][j]);
      }
    }
    __syncthreads();
    constexpr int RPT = BN/16;
    #pragma unroll
    for (int k=0;k<RPT;k++){
      int j = tid + k*256;
      int row = j / (BN/8), col8 = (j % (BN/8))*8;
      *(int4*)(C + (m0+row)*N + n0 + col8) = *(const int4*)(SH + row*BNP + col8);
    }
  }
}

// ---------------- gemm2 w8: 512 threads, 8 waves (2x4), tile 128x128, depth-2 vmcnt ring ----------------
__global__ __launch_bounds__(512)
void gemm2_w8(const u16* __restrict__ A, const u16* __restrict__ Bt, u16* __restrict__ C,
              float* __restrict__ raw){
  const int K = 192, N = 3072;
  constexpr int SB = 128*32;
  __shared__ __align__(16) u16 SH[6*SB];
  __shared__ float rs[8], rss[8];
  u16* Asb = SH;
  u16* Bsb = SH + 3*SB;
  int tid = threadIdx.x, wid = tid >> 6, l = tid & 63;
  int r = l & 15, q = l >> 4;
  int wr = wid >> 2, wc = wid & 3;
  int chunk = gridDim.x >> 3;
  int lin = (blockIdx.x & 7)*chunk + (blockIdx.x >> 3);
  int bx = lin % 24, by = lin / 24;
  long m0 = (long)by*128;
  int n0 = bx*128;

  int srow = ((tid>>6)<<4) | (tid & 15);
  int sch  = ((tid>>4) & 3)*8;
  int sslot = tid*8;

  f32x4 acc[4][2];
  #pragma unroll
  for (int mf=0;mf<4;mf++){ acc[mf][0] = (f32x4){0.f,0.f,0.f,0.f}; acc[mf][1] = (f32x4){0.f,0.f,0.f,0.f}; }

  gload16(A  + (m0+srow)*K + sch,          Asb + sslot);
  gload16(Bt + (long)(n0+srow)*K + sch,    Bsb + sslot);
  gload16(A  + (m0+srow)*K + 32 + sch,     Asb + SB + sslot);
  gload16(Bt + (long)(n0+srow)*K + 32 + sch, Bsb + SB + sslot);

  int c0 = 0;
  for (int kt=0; kt<6; kt++){
    asm volatile("s_waitcnt vmcnt(2)" ::: "memory");
    __builtin_amdgcn_s_barrier();
    __builtin_amdgcn_sched_barrier(0);
    if (kt+2 < 6){
      int c2 = c0+2; if (c2>=3) c2-=3;
      int ko = (kt+2)*32;
      gload16(A  + (m0+srow)*K + ko + sch,       Asb + c2*SB + sslot);
      gload16(Bt + (long)(n0+srow)*K + ko + sch, Bsb + c2*SB + sslot);
    }
    const u16* Ac = Asb + c0*SB;
    const u16* Bc = Bsb + c0*SB;
    bf16x8 af[4], bfv[2];
    #pragma unroll
    for (int mf=0;mf<4;mf++) af[mf]  = *(const bf16x8*)(Ac + (((wr*4+mf)*4 + q)*16 + r)*8);
    #pragma unroll
    for (int nf=0;nf<2;nf++) bfv[nf] = *(const bf16x8*)(Bc + (((wc*2+nf)*4 + q)*16 + r)*8);
    #pragma unroll
    for (int mf=0;mf<4;mf++){
      acc[mf][0] = __builtin_amdgcn_mfma_f32_16x16x32_bf16(af[mf], bfv[0], acc[mf][0], 0,0,0);
      acc[mf][1] = __builtin_amdgcn_mfma_f32_16x16x32_bf16(af[mf], bfv[1], acc[mf][1], 0,0,0);
    }
    c0 = (c0+1==3) ? 0 : c0+1;
  }

  float s=0.f, ss=0.f;
  #pragma unroll
  for (int mf=0;mf<4;mf++)
    #pragma unroll
    for (int nf=0;nf<2;nf++)
      #pragma unroll
      for (int j=0;j<4;j++){ float v = acc[mf][nf][j]; s += v; ss += v*v; }
  #pragma unroll
  for (int off=32; off>0; off>>=1){ s += __shfl_down(s,off,64); ss += __shfl_down(ss,off,64); }
  if (l==0){ rs[wid]=s; rss[wid]=ss; }
  __syncthreads();
  if (tid==0){
    float as=0, aq=0;
    #pragma unroll
    for (int j=0;j<8;j++){ as += rs[j]; aq += rss[j]; }
    int bc = (int)(m0 >> 7);
    int g = (bc/24)*4 + (bc%24)/6;
    atomicAdd(&raw[g], as);
    atomicAdd(&raw[16+g], aq);
  }

  #pragma unroll
  for (int mf=0;mf<4;mf++){
    int row = wr*64 + mf*16 + q*4;
    #pragma unroll
    for (int nf=0;nf<2;nf++){
      int col = wc*32 + nf*16 + r;
      #pragma unroll
      for (int j=0;j<4;j++)
        SH[(row+j)*132 + col] = f2b(acc[mf][nf][j]);
    }
  }
  __syncthreads();
  #pragma unroll
  for (int k=0;k<4;k++){
    int j = tid + k*512;
    int row = j >> 4, col8 = (j & 15)*8;
    *(int4*)(C + (m0+row)*N + n0 + col8) = *(const int4*)(SH + row*132 + col8);
  }
}

// ---------------- final: out(fp32) = x_ + sum_n relu(gn2(h2))[...,n]*att[b,n] (inline GN) ----------------
__global__ __launch_bounds__(256)
void final_mix(const u16* __restrict__ h2, const u16* __restrict__ xr,
               const float* __restrict__ raw, const float* __restrict__ gw,
               const float* __restrict__ gb, float invN,
               const float* __restrict__ att, float* __restrict__ out){
  __shared__ float s_sc, s_off, s_att[6];
  int bc0 = blockIdx.x / 64;
  int c  = bc0 % 24, b = bc0 / 24;
  if (threadIdx.x == 0){
    int g = b*4 + c/6;
    float m = raw[g]*invN;
    float var = raw[16+g]*invN - m*m;
    float is = rsqrtf(var + EPS);
    float sc = is*gw[c];
    s_sc = sc;
    s_off = gb[c] - m*sc;
  }
  if (threadIdx.x < 6) s_att[threadIdx.x] = att[b*6+threadIdx.x];
  __syncthreads();
  float sc = s_sc, off = s_off;
  float a[6];
  #pragma unroll
  for (int n=0;n<6;n++) a[n] = s_att[n];

  int gid = blockIdx.x*256 + threadIdx.x;
  int fq = gid & 127;
  int t  = (gid >> 7) & 127;
  int bc = gid >> 14;

  long hbase = (((long)bc*Tn + t))*3072 + (long)fq*24;
  union { int4 v[3]; u16 u[24]; } hv;
  const int4* hp = (const int4*)(h2 + hbase);
  hv.v[0]=hp[0]; hv.v[1]=hp[1]; hv.v[2]=hp[2];

  long xbase = (((long)bc*Tn + t))*Fn + (long)fq*4;
  union { unsigned long long q; u16 u[4]; } xv;
  xv.q = *(const unsigned long long*)(xr + xbase);

  float4 ov;
  float* op = &ov.x;
  #pragma unroll
  for (int j=0;j<4;j++){
    float accv = b2f(xv.u[j]);
    #pragma unroll
    for (int n=0;n<6;n++){
      float hvf = b2f(hv.u[j*6+n])*sc + off;
      hvf = hvf > 0.f ? hvf : 0.f;
      accv += hvf * a[n];
    }
    op[j] = accv;
  }
  *(float4*)(out + xbase) = ov;
}

extern "C" void kernel_launch(void* const* d_in, const int* in_sizes, int n_in,
                              void* d_out, int out_size, void* d_ws, size_t ws_size,
                              hipStream_t stream){
  const float* x   = (const float*)d_in[0];
  const float* c   = (const float*)d_in[1];
  const float* cw0 = (const float*)d_in[2];  const float* cb0 = (const float*)d_in[3];
  const float* gw0 = (const float*)d_in[4];  const float* gb0 = (const float*)d_in[5];
  const float* cw1 = (const float*)d_in[6];  const float* cb1 = (const float*)d_in[7];
  const float* gw1 = (const float*)d_in[8];  const float* gb1 = (const float*)d_in[9];
  const float* cw2 = (const float*)d_in[10]; const float* cb2 = (const float*)d_in[11];
  const float* gw2 = (const float*)d_in[12]; const float* gb2 = (const float*)d_in[13];
  const float* tw1 = (const float*)d_in[14]; const float* tg1w= (const float*)d_in[15]; const float* tg1b=(const float*)d_in[16];
  const float* tw2 = (const float*)d_in[17]; const float* tg2w= (const float*)d_in[18]; const float* tg2b=(const float*)d_in[19];
  const float* wqp = (const float*)d_in[20]; const float* bqp = (const float*)d_in[21]; const float* keys=(const float*)d_in[22];

  char* ws = (char*)d_ws;
  u16*   xr     = (u16*)(ws + 0);               // 12,582,912 B  [12288,512] bf16 CHW
  u16*   h1     = (u16*)(ws + 12582912);        //  4,718,592 B  [12288,192]
  u16*   tw1b   = (u16*)(ws + 17301504);        //    196,608 B
  u16*   tw2b   = (u16*)(ws + 17498112);        //  1,179,648 B
  float* stats5 = (float*)(ws + 18677760);      //        128 B
  float* att    = (float*)(ws + 18678656);      //        128 B
  // ---- h2 span (reused during conv phase) ----
  u16*   h2     = (u16*)(ws + 18680832);        // 75,497,472 B  [12288,3072]
  u16*   Y      = (u16*)(ws + 18680832);        // 12,582,912 B  NHWC conv out [4,128,512,24]
  u16*   b72p   = (u16*)(ws + 31263744);        // 38,488,320 B  NHWC padded [4,130,514,72]
  u16*   xc24   = (u16*)(ws + 69752064);        // 12,829,440 B (+256 slack) NHWC padded [4,130,514,24]
  float* stats14= (float*)(ws + 82581760);      //        512 B
  u16*   wr0    = (u16*)(ws + 82585344);        //     18,432 B  (72*96*2 = 13,824 used)
  u16*   wr1    = (u16*)(ws + 82603776);        //     36,864 B  (72*192*2 = 27,648 used)
  u16*   wr2    = (u16*)(ws + 82640640);        //     43,008 B  (72*224*2 = 32,256 used)

  // ---- fused prologue (1 launch) ----
  prep_all<<<1522,256,0,stream>>>(x, b72p, xc24, tw1, tw1b, tw2, tw2b,
                                  cw0, wr0, cw1, wr1, cw2, wr2,
                                  stats14, stats5, c, wqp, bqp, keys, att);

  // ---- conv block 0 ----
  conv_mfma<96,24><<<512,512,0,stream>>>(xc24, 0, wr0, cb0, Y, stats14+0);
  norm_relu_nhwc<<<3072,256,0,stream>>>(Y, b72p, 24, stats14+0, gw0, gb0, 1.f/393216.f);

  // ---- conv block 1 ----
  conv_mfma<192,72><<<512,512,0,stream>>>(b72p, 24, wr1, cb1, Y, stats14+32);
  norm_relu_nhwc<<<3072,256,0,stream>>>(Y, b72p, 0, stats14+32, gw1, gb1, 1.f/393216.f);

  // ---- conv block 2 -> xr (CHW) ----
  conv_mfma<224,72><<<512,512,0,stream>>>(b72p, 0, wr2, cb2, Y, stats14+64);
  norm_relu_chw<<<512,256,0,stream>>>(Y, xr, stats14+64, gw2, gb2, 1.f/393216.f);

  // ---- TDF: gemm1 (12288x192x512) + GN + relu ----
  gemm_lds<2,true><<<288,256,0,stream>>>(xr, tw1b, h1, 192, 512, 3, stats14+96);
  norm_chw<<<1152,256,0,stream>>>(h1, stats14+96, tg1w, tg1b, 1.f/147456.f);

  // ---- TDF: gemm2 (12288x3072x192), 8-wave 128x128 ----
  gemm2_w8<<<2304,512,0,stream>>>(h1, tw2b, h2, stats5);

  // ---- final mix (inline GN2 params) ----
  final_mix<<<6144,256,0,stream>>>(h2, xr, stats5, tg2w, tg2b, 1.f/2359296.f, att, (float*)d_out);
}

// Round 22
// 189.443 us; speedup vs baseline: 1.2972x; 1.0020x over previous
//
#include <hip/hip_runtime.h>
#include <hip/hip_bf16.h>

typedef unsigned short u16;
typedef unsigned int u32;

#define Tn 128
#define Fn 512
#define HWc (Tn*Fn)
#define EPS 1e-5f

using bf16x8 = __attribute__((ext_vector_type(8))) short;
using f32x4  = __attribute__((ext_vector_type(4))) float;

__device__ __forceinline__ float b2f(u16 x){ return __uint_as_float(((u32)x)<<16); }
__device__ __forceinline__ u16 f2b(float f){
  __hip_bfloat16 h = __float2bfloat16(f);
  return *reinterpret_cast<u16*>(&h);
}

// async global->LDS, 16B per lane
__device__ __forceinline__ void gload16(const u16* g, u16* l){
  __builtin_amdgcn_global_load_lds((const __attribute__((address_space(1))) void*)g,
                                   (__attribute__((address_space(3))) void*)l, 16, 0, 0);
}

// ---------------- prep_all: fused prologue (grid 1522) ----------------
__global__ __launch_bounds__(256)
void prep_all(const float* __restrict__ x, u16* __restrict__ b72p, u16* __restrict__ xc24,
              const float* __restrict__ tw1, u16* __restrict__ tw1b,
              const float* __restrict__ tw2, u16* __restrict__ tw2b,
              const float* __restrict__ cw0, u16* __restrict__ wr0,
              const float* __restrict__ cw1, u16* __restrict__ wr1,
              const float* __restrict__ cw2, u16* __restrict__ wr2,
              float* __restrict__ stats14, float* __restrict__ stats5,
              const float* __restrict__ cc, const float* __restrict__ wq,
              const float* __restrict__ bq, const float* __restrict__ keys,
              float* __restrict__ att){
  __shared__ __align__(16) char smem[24*520*2];
  int bid = blockIdx.x, tid = threadIdx.x;

  if (bid < 512){
    u16 (*sh)[520] = (u16(*)[520])smem;
    int t = bid & 127, b = bid >> 7;
    const float* src = x + ((long)(b*24)*128 + t)*512;
    for (int c=0; c<24; c++){
      float2 v = *(const float2*)(src + (long)c*65536 + tid*2);
      sh[c][tid*2]   = f2b(v.x);
      sh[c][tid*2+1] = f2b(v.y);
    }
    __syncthreads();
    long r72 = ((long)(b*130 + t+1))*514*72;
    long r24 = ((long)(b*130 + t+1))*514*24;
    for (int i = tid; i < 1536; i += 256){
      int f = i/3, c0 = (i%3)*8;
      union {int4 q; u16 u[8];} o;
      #pragma unroll
      for (int j=0;j<8;j++) o.u[j] = sh[c0+j][f];
      *(int4*)(b72p + r72 + (long)(f+1)*72 + 48 + c0) = o.q;
      *(int4*)(xc24 + r24 + (long)(f+1)*24 + c0) = o.q;
    }
  } else if (bid < 1088){
    int i = ((bid-512)*256 + tid)*4;
    float4 v = *(const float4*)(tw2 + i);
    ushort4 o;
    o.x=f2b(v.x); o.y=f2b(v.y); o.z=f2b(v.z); o.w=f2b(v.w);
    *(ushort4*)(tw2b + i) = o;
  } else if (bid < 1184){
    int i = ((bid-1088)*256 + tid)*4;
    float4 v = *(const float4*)(tw1 + i);
    ushort4 o;
    o.x=f2b(v.x); o.y=f2b(v.y); o.z=f2b(v.z); o.w=f2b(v.w);
    *(ushort4*)(tw1b + i) = o;
  } else if (bid < 1312){
    int sub = bid - 1184;
    int b = sub >> 5, j = sub & 31;
    u16* base = b72p + (long)b*130*514*72;
    int rowN = 514*72;
    for (int i = j*256 + tid; i < rowN; i += 32*256){
      base[i] = 0;
      base[(long)129*rowN + i] = 0;
    }
    int colN = 128*72;
    for (int i = j*256 + tid; i < colN; i += 32*256){
      int row = 1 + i/72, ch = i - (i/72)*72;
      base[((long)row*514 + 0)*72 + ch] = 0;
      base[((long)row*514 + 513)*72 + ch] = 0;
    }
  } else if (bid < 1376){
    int sub = bid - 1312;
    int b = sub >> 4, j = sub & 15;
    u16* base = xc24 + (long)b*130*514*24;
    int rowN = 514*24;
    for (int i = j*256 + tid; i < rowN; i += 16*256){
      base[i] = 0;
      base[(long)129*rowN + i] = 0;
    }
    int colN = 128*24;
    for (int i = j*256 + tid; i < colN; i += 16*256){
      int row = 1 + i/24, ch = i - (i/24)*24;
      base[((long)row*514 + 0)*24 + ch] = 0;
      base[((long)row*514 + 513)*24 + ch] = 0;
    }
  } else if (bid < 1520){
    // compact 24-row fragment order: wr[dt][NK][q:4][o:24][e:8]
    const float* w; u16* wr; int CIN, cs, cof, KP, sub;
    if (bid < 1403){ sub = bid-1376; w = cw0; wr = wr0; CIN=24; cs=24; cof=0;  KP=96;  }
    else if (bid < 1457){ sub = bid-1403; w = cw1; wr = wr1; CIN=48; cs=72; cof=24; KP=192; }
    else { sub = bid-1457; w = cw2; wr = wr2; CIN=72; cs=72; cof=0;  KP=224; }
    int i = sub*256 + tid;
    int NK = KP >> 5;
    int tot = 72*KP;
    if (i < tot){
      int e  = i & 7;
      int rest = i >> 3;
      int o  = rest % 24;  rest /= 24;
      int q  = rest & 3;   rest >>= 2;
      int ks = rest % NK;
      int dt = rest / NK;
      int k = ks*32 + q*8 + e;
      float v = 0.f;
      int g = cof + k, df = g/cs, ch = g - df*cs;
      if (df < 3 && ch >= cof && ch < cof+CIN)
        v = w[((o*CIN + (ch-cof))*3 + dt)*3 + df];
      wr[i] = f2b(v);
    }
  } else if (bid == 1520){
    if (tid < 128) stats14[tid] = 0.f;
    else if (tid < 160) stats5[tid-128] = 0.f;
  } else {
    float (*qs)[32] = (float(*)[32])smem;
    float (*ss)[6]  = (float(*)[6])(smem + 4*32*4);
    int t = tid;
    if (t < 128){
      int b = t >> 5, k = t & 31;
      float a = bq[k];
      for (int j=0;j<32;j++) a += cc[b*32+j] * wq[k*32+j];
      qs[b][k] = a;
    }
    __syncthreads();
    if (t < 24){
      int b = t/6, n = t%6;
      float a = 0.f;
      for (int k=0;k<32;k++) a += qs[b][k]*keys[k*6+n];
      ss[b][n] = a * 0.17677669529663689f;
    }
    __syncthreads();
    if (t < 4){
      float mx = -1e30f;
      for (int n=0;n<6;n++) mx = fmaxf(mx, ss[t][n]);
      float e[6], sm=0.f;
      for (int n=0;n<6;n++){ e[n]=expf(ss[t][n]-mx); sm+=e[n]; }
      for (int n=0;n<6;n++) att[t*6+n] = e[n]/sm;
    }
  }
}

// ---------------- MFMA implicit-GEMM 3x3 conv v13 (r21 best) ----------------
template<int KP, int CS>
__global__ __launch_bounds__(512)
void conv_mfma(const u16* __restrict__ X, int coff, const u16* __restrict__ WR,
               const float* __restrict__ bias, u16* __restrict__ Y,
               float* __restrict__ raw){
  constexpr int NK = KP/32;
  __shared__ u16 WS[72*KP + 128];
  __shared__ float ssum[8][32], ssq[8][32];
  __shared__ float g24s[24], g24q[24];
  __shared__ __align__(16) u16 Ysh[2*128*24];
  int bid = (blockIdx.x & 7)*64 + (blockIdx.x >> 3);   // grid 512, chunk 64
  int ftg = bid >> 8, b = (bid >> 6) & 3, t0 = (bid & 63)*2;
  int tid = threadIdx.x, wid = tid >> 6, l = tid & 63;
  int r = l & 15, q = l >> 4;
  int h = wid >> 2;            // half: t = t0 + h
  int wid4 = wid & 3;
  int t = t0 + h;

  for (int i = tid*8; i < 72*KP; i += 4096)
    *(int4*)(WS + i) = *(const int4*)(WR + i);
  if (tid < 16) *(int4*)(WS + 72*KP + tid*8) = (int4){0,0,0,0};

  float bv0 = bias[r];
  float bv1 = (r < 8) ? bias[16+r] : 0.f;
  float s0=0,q0=0,s1=0,q1=0;
  __syncthreads();

  #pragma unroll
  for (int fi=0; fi<2; fi++){
    int ft = ftg*2 + fi;
    int f0w = ft*128 + wid4*32;
    f32x4 acc[2][2] = {};
    #pragma unroll
    for (int dt=0; dt<3; dt++){
      const u16* Ab = X + ((long)((b*130 + t+dt)*514 + f0w + r))*CS + coff + q*8;
      bf16x8 a[2][NK];
      #pragma unroll
      for (int ks=0; ks<NK; ks++){
        a[0][ks] = *(const bf16x8*)(Ab + ks*32);
        a[1][ks] = *(const bf16x8*)(Ab + (long)16*CS + ks*32);
      }
      #pragma unroll
      for (int ks=0; ks<NK; ks++){
        const u16* Bb = WS + ((dt*NK + ks)*4 + q)*192 + r*8;
        bf16x8 b0 = *(const bf16x8*)(Bb);
        bf16x8 b1 = *(const bf16x8*)(Bb + 128);
        acc[0][0] = __builtin_amdgcn_mfma_f32_16x16x32_bf16(a[0][ks],b0,acc[0][0],0,0,0);
        acc[0][1] = __builtin_amdgcn_mfma_f32_16x16x32_bf16(a[0][ks],b1,acc[0][1],0,0,0);
        acc[1][0] = __builtin_amdgcn_mfma_f32_16x16x32_bf16(a[1][ks],b0,acc[1][0],0,0,0);
        acc[1][1] = __builtin_amdgcn_mfma_f32_16x16x32_bf16(a[1][ks],b1,acc[1][1],0,0,0);
      }
    }
    #pragma unroll
    for (int m=0;m<2;m++){
      #pragma unroll
      for (int j=0;j<4;j++){
        acc[m][0][j] += bv0; acc[m][1][j] += bv1;
        s0 += acc[m][0][j]; q0 += acc[m][0][j]*acc[m][0][j];
        s1 += acc[m][1][j]; q1 += acc[m][1][j]*acc[m][1][j];
      }
    }
    __syncthreads();
    #pragma unroll
    for (int m=0;m<2;m++){
      int fr = wid4*32 + m*16 + q*4;
      #pragma unroll
      for (int j=0;j<4;j++){
        Ysh[h*3072 + (fr+j)*24 + r] = f2b(acc[m][0][j]);
        if (r < 8) Ysh[h*3072 + (fr+j)*24 + 16 + r] = f2b(acc[m][1][j]);
      }
    }
    __syncthreads();
    const int4* sp = (const int4*)Ysh;
    for (int i = tid; i < 768; i += 512){
      int hh = (i >= 384) ? 1 : 0;
      int rem = i - hh*384;
      long Yb = ((long)((b*128 + t0 + hh)*512) + ft*128)*24;
      *(int4*)(Y + Yb + (long)rem*8) = sp[i];
    }
  }

  #pragma unroll
  for (int off=16; off<=32; off<<=1){
    s0 += __shfl_xor(s0, off, 64); q0 += __shfl_xor(q0, off, 64);
    s1 += __shfl_xor(s1, off, 64); q1 += __shfl_xor(q1, off, 64);
  }
  if (q == 0){
    ssum[wid][r] = s0;     ssq[wid][r] = q0;
    ssum[wid][16+r] = s1;  ssq[wid][16+r] = q1;
  }
  __syncthreads();
  if (tid < 24){
    float as = 0, aq = 0;
    #pragma unroll
    for (int w2=0; w2<8; w2++){ as += ssum[w2][tid]; aq += ssq[w2][tid]; }
    g24s[tid] = as;
    g24q[tid] = aq;
  }
  __syncthreads();
  if (tid < 4){
    float as=0, aq=0;
    #pragma unroll
    for (int j=0;j<6;j++){ as += g24s[tid*6+j]; aq += g24q[tid*6+j]; }
    atomicAdd(&raw[b*4+tid], as);
    atomicAdd(&raw[16+b*4+tid], aq);
  }
}

// ---------------- normalize+relu: Y NHWC -> b72p channel slice (inline GN params) ----------------
__global__ __launch_bounds__(256)
void norm_relu_nhwc(const u16* __restrict__ Y, u16* __restrict__ dst, int coff,
                    const float* __restrict__ raw, const float* __restrict__ gw,
                    const float* __restrict__ gb, float invN){
  __shared__ float sA[24], sB[24];
  int bb = blockIdx.x / 768;
  if (threadIdx.x < 24){
    int g = bb*4 + threadIdx.x/6;
    float m = raw[g]*invN;
    float var = raw[16+g]*invN - m*m;
    float is = rsqrtf(var + EPS);
    float sc = is*gw[threadIdx.x];
    sA[threadIdx.x] = sc;
    sB[threadIdx.x] = gb[threadIdx.x] - m*sc;
  }
  __syncthreads();
  long e = ((long)blockIdx.x*256 + threadIdx.x)*8;
  int c0 = (int)(e % 24);
  long fi = e / 24;
  int f = (int)(fi & 511);
  int bt = (int)(fi >> 9); int t = bt & 127, b = bt >> 7;
  union {int4 q; u16 u[8];} pk; pk.q = *(const int4*)(Y + e);
  union {int4 q; u16 u[8];} o;
  #pragma unroll
  for (int j=0;j<8;j++){
    float v = b2f(pk.u[j])*sA[c0+j] + sB[c0+j];
    o.u[j] = f2b(v>0.f?v:0.f);
  }
  *(int4*)(dst + ((long)(b*130 + t+1)*514 + (f+1))*72 + coff + c0) = o.q;
}

// ---------------- normalize+relu + NHWC->CHW transpose (inline GN params) ----------------
__global__ __launch_bounds__(256)
void norm_relu_chw(const u16* __restrict__ Y, u16* __restrict__ xr,
                   const float* __restrict__ raw, const float* __restrict__ gw,
                   const float* __restrict__ gb, float invN){
  __shared__ u16 sh[24][520];
  __shared__ float sA[24], sB[24];
  int t = blockIdx.x & 127, b = blockIdx.x >> 7;
  if (threadIdx.x < 24){
    int g = b*4 + threadIdx.x/6;
    float m = raw[g]*invN;
    float var = raw[16+g]*invN - m*m;
    float is = rsqrtf(var + EPS);
    float sc = is*gw[threadIdx.x];
    sA[threadIdx.x] = sc;
    sB[threadIdx.x] = gb[threadIdx.x] - m*sc;
  }
  __syncthreads();
  const u16* src = Y + ((long)(b*128+t))*12288;
  for (int i = threadIdx.x; i < 1536; i += 256){
    int e = i*8; int c0 = e % 24; int f = e / 24;
    union {int4 q; u16 u[8];} pk; pk.q = *(const int4*)(src + e);
    #pragma unroll
    for (int j=0;j<8;j++){
      float v = b2f(pk.u[j])*sA[c0+j] + sB[c0+j];
      sh[c0+j][f] = f2b(v>0.f?v:0.f);
    }
  }
  __syncthreads();
  for (int i = threadIdx.x; i < 1536; i += 256){
    int c = i >> 6, fq = (i & 63)*8;
    union {int4 q; u16 u[8];} o;
    #pragma unroll
    for (int j=0;j<8;j++) o.u[j] = sh[c][fq+j];
    *(int4*)(xr + ((long)((b*24+c)*128 + t))*512 + fq) = o.q;
  }
}

// ---------------- elementwise normalize+relu on CHW rows (h1), inline GN params ----------------
__global__ __launch_bounds__(256)
void norm_chw(u16* __restrict__ h, const float* __restrict__ raw,
              const float* __restrict__ gw, const float* __restrict__ gb, float invN){
  __shared__ float s_sc, s_off;
  int bc = blockIdx.x / 12;
  if (threadIdx.x == 0){
    int b = bc/24, c = bc%24;
    int g = b*4 + c/6;
    float m = raw[g]*invN;
    float var = raw[16+g]*invN - m*m;
    float is = rsqrtf(var + EPS);
    float sc = is*gw[c];
    s_sc = sc;
    s_off = gb[c] - m*sc;
  }
  __syncthreads();
  float sc = s_sc, off = s_off;
  long e = ((long)blockIdx.x*256 + threadIdx.x)*8;
  union {int4 q; u16 u[8];} pk; pk.q = *(const int4*)(h + e);
  #pragma unroll
  for (int j=0;j<8;j++){ float v = b2f(pk.u[j])*sc + off; pk.u[j] = f2b(v>0.f?v:0.f); }
  *(int4*)(h + e) = pk.q;
}

// ---------------- gemm1 w8: 512 threads, 8 waves (4Mx2N), tile 128x64, K=512, 16-step pipeline ----------------
// LDS 36 KB (3-ring A 8KB + B 4KB). Waves 0-3 stage A+B (vmcnt 2), waves 4-7 stage A only (vmcnt 1).
__global__ __launch_bounds__(512)
void gemm1_w8(const u16* __restrict__ A, const u16* __restrict__ Bt, u16* __restrict__ C,
              float* __restrict__ raw){
  const int K = 512, N = 192;
  constexpr int AB = 128*32;   // 4096 u16
  constexpr int BB = 64*32;    // 2048 u16
  __shared__ __align__(16) u16 SH[3*(AB+BB)];
  __shared__ float rs[8], rss[8];
  u16* Asb = SH;
  u16* Bsb = SH + 3*AB;
  int tid = threadIdx.x, wid = tid >> 6, l = tid & 63;
  int r = l & 15, q = l >> 4;
  int wr = wid >> 1, wc = wid & 1;
  int lin = (blockIdx.x & 7)*36 + (blockIdx.x >> 3);   // grid 288, chunk 36
  int bx = lin % 3, by = lin / 3;
  long m0 = (long)by*128;
  int n0 = bx*64;

  int srow = ((tid>>6)<<4) | (tid & 15);
  int sch  = ((tid>>4) & 3)*8;
  bool doB = (tid < 256);      // wave-uniform (waves 0-3)

  f32x4 acc[2][2];
  #pragma unroll
  for (int mf=0;mf<2;mf++){ acc[mf][0] = (f32x4){0.f,0.f,0.f,0.f}; acc[mf][1] = (f32x4){0.f,0.f,0.f,0.f}; }

  // prologue: stage kt=0,1
  gload16(A + (m0+srow)*K + sch, Asb + tid*8);
  if (doB) gload16(Bt + (long)(n0+srow)*K + sch, Bsb + tid*8);
  gload16(A + (m0+srow)*K + 32 + sch, Asb + AB + tid*8);
  if (doB) gload16(Bt + (long)(n0+srow)*K + 32 + sch, Bsb + BB + tid*8);

  int c0 = 0;
  for (int kt=0; kt<16; kt++){
    if (kt == 15)  asm volatile("s_waitcnt vmcnt(0)" ::: "memory");
    else if (doB)  asm volatile("s_waitcnt vmcnt(2)" ::: "memory");
    else           asm volatile("s_waitcnt vmcnt(1)" ::: "memory");
    __builtin_amdgcn_s_barrier();
    __builtin_amdgcn_sched_barrier(0);
    if (kt+2 < 16){
      int c2 = c0+2; if (c2>=3) c2-=3;
      int ko = (kt+2)*32;
      gload16(A + (m0+srow)*K + ko + sch, Asb + c2*AB + tid*8);
      if (doB) gload16(Bt + (long)(n0+srow)*K + ko + sch, Bsb + c2*BB + tid*8);
    }
    const u16* Ac = Asb + c0*AB;
    const u16* Bc = Bsb + c0*BB;
    bf16x8 af[2], bfv[2];
    #pragma unroll
    for (int mf=0;mf<2;mf++) af[mf]  = *(const bf16x8*)(Ac + (((wr*2+mf)*4 + q)*16 + r)*8);
    #pragma unroll
    for (int nf=0;nf<2;nf++) bfv[nf] = *(const bf16x8*)(Bc + (((wc*2+nf)*4 + q)*16 + r)*8);
    #pragma unroll
    for (int mf=0;mf<2;mf++){
      acc[mf][0] = __builtin_amdgcn_mfma_f32_16x16x32_bf16(af[mf], bfv[0], acc[mf][0], 0,0,0);
      acc[mf][1] = __builtin_amdgcn_mfma_f32_16x16x32_bf16(af[mf], bfv[1], acc[mf][1], 0,0,0);
    }
    c0 = (c0+1==3) ? 0 : c0+1;
  }

  // fused GN stats (block spans 128 rows = one (b,c) plane)
  float s=0.f, ss=0.f;
  #pragma unroll
  for (int mf=0;mf<2;mf++)
    #pragma unroll
    for (int nf=0;nf<2;nf++)
      #pragma unroll
      for (int j=0;j<4;j++){ float v = acc[mf][nf][j]; s += v; ss += v*v; }
  #pragma unroll
  for (int off=32; off>0; off>>=1){ s += __shfl_down(s,off,64); ss += __shfl_down(ss,off,64); }
  if (l==0){ rs[wid]=s; rss[wid]=ss; }
  __syncthreads();                 // all reads of SH done -> reusable for repack
  if (tid==0){
    float as=0, aq=0;
    #pragma unroll
    for (int j=0;j<8;j++){ as += rs[j]; aq += rss[j]; }
    int bc = (int)(m0 >> 7);
    int g = (bc/24)*4 + (bc%24)/6;
    atomicAdd(&raw[g], as);
    atomicAdd(&raw[16+g], aq);
  }

  // padded repack (stride 68) + coalesced int4 stores, 2 per thread
  #pragma unroll
  for (int mf=0;mf<2;mf++){
    int row = wr*32 + mf*16 + q*4;
    #pragma unroll
    for (int nf=0;nf<2;nf++){
      int col = wc*32 + nf*16 + r;
      #pragma unroll
      for (int j=0;j<4;j++)
        SH[(row+j)*68 + col] = f2b(acc[mf][nf][j]);
    }
  }
  __syncthreads();
  #pragma unroll
  for (int k=0;k<2;k++){
    int j = tid + k*512;
    int row = j >> 3, col8 = (j & 7)*8;
    *(int4*)(C + (m0+row)*N + n0 + col8) = *(const int4*)(SH + row*68 + col8);
  }
}

// ---------------- gemm2 w8: 512 threads, 8 waves (2x4), tile 128x128, depth-2 vmcnt ring ----------------
__global__ __launch_bounds__(512)
void gemm2_w8(const u16* __restrict__ A, const u16* __restrict__ Bt, u16* __restrict__ C,
              float* __restrict__ raw){
  const int K = 192, N = 3072;
  constexpr int SB = 128*32;
  __shared__ __align__(16) u16 SH[6*SB];
  __shared__ float rs[8], rss[8];
  u16* Asb = SH;
  u16* Bsb = SH + 3*SB;
  int tid = threadIdx.x, wid = tid >> 6, l = tid & 63;
  int r = l & 15, q = l >> 4;
  int wr = wid >> 2, wc = wid & 3;
  int chunk = gridDim.x >> 3;
  int lin = (blockIdx.x & 7)*chunk + (blockIdx.x >> 3);
  int bx = lin % 24, by = lin / 24;
  long m0 = (long)by*128;
  int n0 = bx*128;

  int srow = ((tid>>6)<<4) | (tid & 15);
  int sch  = ((tid>>4) & 3)*8;
  int sslot = tid*8;

  f32x4 acc[4][2];
  #pragma unroll
  for (int mf=0;mf<4;mf++){ acc[mf][0] = (f32x4){0.f,0.f,0.f,0.f}; acc[mf][1] = (f32x4){0.f,0.f,0.f,0.f}; }

  gload16(A  + (m0+srow)*K + sch,          Asb + sslot);
  gload16(Bt + (long)(n0+srow)*K + sch,    Bsb + sslot);
  gload16(A  + (m0+srow)*K + 32 + sch,     Asb + SB + sslot);
  gload16(Bt + (long)(n0+srow)*K + 32 + sch, Bsb + SB + sslot);

  int c0 = 0;
  for (int kt=0; kt<6; kt++){
    if (kt == 5) asm volatile("s_waitcnt vmcnt(0)" ::: "memory");
    else         asm volatile("s_waitcnt vmcnt(2)" ::: "memory");
    __builtin_amdgcn_s_barrier();
    __builtin_amdgcn_sched_barrier(0);
    if (kt+2 < 6){
      int c2 = c0+2; if (c2>=3) c2-=3;
      int ko = (kt+2)*32;
      gload16(A  + (m0+srow)*K + ko + sch,       Asb + c2*SB + sslot);
      gload16(Bt + (long)(n0+srow)*K + ko + sch, Bsb + c2*SB + sslot);
    }
    const u16* Ac = Asb + c0*SB;
    const u16* Bc = Bsb + c0*SB;
    bf16x8 af[4], bfv[2];
    #pragma unroll
    for (int mf=0;mf<4;mf++) af[mf]  = *(const bf16x8*)(Ac + (((wr*4+mf)*4 + q)*16 + r)*8);
    #pragma unroll
    for (int nf=0;nf<2;nf++) bfv[nf] = *(const bf16x8*)(Bc + (((wc*2+nf)*4 + q)*16 + r)*8);
    #pragma unroll
    for (int mf=0;mf<4;mf++){
      acc[mf][0] = __builtin_amdgcn_mfma_f32_16x16x32_bf16(af[mf], bfv[0], acc[mf][0], 0,0,0);
      acc[mf][1] = __builtin_amdgcn_mfma_f32_16x16x32_bf16(af[mf], bfv[1], acc[mf][1], 0,0,0);
    }
    c0 = (c0+1==3) ? 0 : c0+1;
  }

  float s=0.f, ss=0.f;
  #pragma unroll
  for (int mf=0;mf<4;mf++)
    #pragma unroll
    for (int nf=0;nf<2;nf++)
      #pragma unroll
      for (int j=0;j<4;j++){ float v = acc[mf][nf][j]; s += v; ss += v*v; }
  #pragma unroll
  for (int off=32; off>0; off>>=1){ s += __shfl_down(s,off,64); ss += __shfl_down(ss,off,64); }
  if (l==0){ rs[wid]=s; rss[wid]=ss; }
  __syncthreads();
  if (tid==0){
    float as=0, aq=0;
    #pragma unroll
    for (int j=0;j<8;j++){ as += rs[j]; aq += rss[j]; }
    int bc = (int)(m0 >> 7);
    int g = (bc/24)*4 + (bc%24)/6;
    atomicAdd(&raw[g], as);
    atomicAdd(&raw[16+g], aq);
  }

  #pragma unroll
  for (int mf=0;mf<4;mf++){
    int row = wr*64 + mf*16 + q*4;
    #pragma unroll
    for (int nf=0;nf<2;nf++){
      int col = wc*32 + nf*16 + r;
      #pragma unroll
      for (int j=0;j<4;j++)
        SH[(row+j)*132 + col] = f2b(acc[mf][nf][j]);
    }
  }
  __syncthreads();
  #pragma unroll
  for (int k=0;k<4;k++){
    int j = tid + k*512;
    int row = j >> 4, col8 = (j & 15)*8;
    *(int4*)(C + (m0+row)*N + n0 + col8) = *(const int4*)(SH + row*132 + col8);
  }
}

// ---------------- final: out(fp32) = x_ + sum_n relu(gn2(h2))[...,n]*att[b,n] (inline GN) ----------------
__global__ __launch_bounds__(256)
void final_mix(const u16* __restrict__ h2, const u16* __restrict__ xr,
               const float* __restrict__ raw, const float* __restrict__ gw,
               const float* __restrict__ gb, float invN,
               const float* __restrict__ att, float* __restrict__ out){
  __shared__ float s_sc, s_off, s_att[6];
  int bc0 = blockIdx.x / 64;
  int c  = bc0 % 24, b = bc0 / 24;
  if (threadIdx.x == 0){
    int g = b*4 + c/6;
    float m = raw[g]*invN;
    float var = raw[16+g]*invN - m*m;
    float is = rsqrtf(var + EPS);
    float sc = is*gw[c];
    s_sc = sc;
    s_off = gb[c] - m*sc;
  }
  if (threadIdx.x < 6) s_att[threadIdx.x] = att[b*6+threadIdx.x];
  __syncthreads();
  float sc = s_sc, off = s_off;
  float a[6];
  #pragma unroll
  for (int n=0;n<6;n++) a[n] = s_att[n];

  int gid = blockIdx.x*256 + threadIdx.x;
  int fq = gid & 127;
  int t  = (gid >> 7) & 127;
  int bc = gid >> 14;

  long hbase = (((long)bc*Tn + t))*3072 + (long)fq*24;
  union { int4 v[3]; u16 u[24]; } hv;
  const int4* hp = (const int4*)(h2 + hbase);
  hv.v[0]=hp[0]; hv.v[1]=hp[1]; hv.v[2]=hp[2];

  long xbase = (((long)bc*Tn + t))*Fn + (long)fq*4;
  union { unsigned long long q; u16 u[4]; } xv;
  xv.q = *(const unsigned long long*)(xr + xbase);

  float4 ov;
  float* op = &ov.x;
  #pragma unroll
  for (int j=0;j<4;j++){
    float accv = b2f(xv.u[j]);
    #pragma unroll
    for (int n=0;n<6;n++){
      float hvf = b2f(hv.u[j*6+n])*sc + off;
      hvf = hvf > 0.f ? hvf : 0.f;
      accv += hvf * a[n];
    }
    op[j] = accv;
  }
  *(float4*)(out + xbase) = ov;
}

extern "C" void kernel_launch(void* const* d_in, const int* in_sizes, int n_in,
                              void* d_out, int out_size, void* d_ws, size_t ws_size,
                              hipStream_t stream){
  const float* x   = (const float*)d_in[0];
  const float* c   = (const float*)d_in[1];
  const float* cw0 = (const float*)d_in[2];  const float* cb0 = (const float*)d_in[3];
  const float* gw0 = (const float*)d_in[4];  const float* gb0 = (const float*)d_in[5];
  const float* cw1 = (const float*)d_in[6];  const float* cb1 = (const float*)d_in[7];
  const float* gw1 = (const float*)d_in[8];  const float* gb1 = (const float*)d_in[9];
  const float* cw2 = (const float*)d_in[10]; const float* cb2 = (const float*)d_in[11];
  const float* gw2 = (const float*)d_in[12]; const float* gb2 = (const float*)d_in[13];
  const float* tw1 = (const float*)d_in[14]; const float* tg1w= (const float*)d_in[15]; const float* tg1b=(const float*)d_in[16];
  const float* tw2 = (const float*)d_in[17]; const float* tg2w= (const float*)d_in[18]; const float* tg2b=(const float*)d_in[19];
  const float* wqp = (const float*)d_in[20]; const float* bqp = (const float*)d_in[21]; const float* keys=(const float*)d_in[22];

  char* ws = (char*)d_ws;
  u16*   xr     = (u16*)(ws + 0);               // 12,582,912 B  [12288,512] bf16 CHW
  u16*   h1     = (u16*)(ws + 12582912);        //  4,718,592 B  [12288,192]
  u16*   tw1b   = (u16*)(ws + 17301504);        //    196,608 B
  u16*   tw2b   = (u16*)(ws + 17498112);        //  1,179,648 B
  float* stats5 = (float*)(ws + 18677760);      //        128 B
  float* att    = (float*)(ws + 18678656);      //        128 B
  // ---- h2 span (reused during conv phase) ----
  u16*   h2     = (u16*)(ws + 18680832);        // 75,497,472 B  [12288,3072]
  u16*   Y      = (u16*)(ws + 18680832);        // 12,582,912 B  NHWC conv out [4,128,512,24]
  u16*   b72p   = (u16*)(ws + 31263744);        // 38,488,320 B  NHWC padded [4,130,514,72]
  u16*   xc24   = (u16*)(ws + 69752064);        // 12,829,440 B (+256 slack) NHWC padded [4,130,514,24]
  float* stats14= (float*)(ws + 82581760);      //        512 B
  u16*   wr0    = (u16*)(ws + 82585344);        //     18,432 B
  u16*   wr1    = (u16*)(ws + 82603776);        //     36,864 B
  u16*   wr2    = (u16*)(ws + 82640640);        //     43,008 B

  // ---- fused prologue (1 launch) ----
  prep_all<<<1522,256,0,stream>>>(x, b72p, xc24, tw1, tw1b, tw2, tw2b,
                                  cw0, wr0, cw1, wr1, cw2, wr2,
                                  stats14, stats5, c, wqp, bqp, keys, att);

  // ---- conv block 0 ----
  conv_mfma<96,24><<<512,512,0,stream>>>(xc24, 0, wr0, cb0, Y, stats14+0);
  norm_relu_nhwc<<<3072,256,0,stream>>>(Y, b72p, 24, stats14+0, gw0, gb0, 1.f/393216.f);

  // ---- conv block 1 ----
  conv_mfma<192,72><<<512,512,0,stream>>>(b72p, 24, wr1, cb1, Y, stats14+32);
  norm_relu_nhwc<<<3072,256,0,stream>>>(Y, b72p, 0, stats14+32, gw1, gb1, 1.f/393216.f);

  // ---- conv block 2 -> xr (CHW) ----
  conv_mfma<224,72><<<512,512,0,stream>>>(b72p, 0, wr2, cb2, Y, stats14+64);
  norm_relu_chw<<<512,256,0,stream>>>(Y, xr, stats14+64, gw2, gb2, 1.f/393216.f);

  // ---- TDF: gemm1 (12288x192x512), 8-wave 128x64, + GN + relu ----
  gemm1_w8<<<288,512,0,stream>>>(xr, tw1b, h1, stats14+96);
  norm_chw<<<1152,256,0,stream>>>(h1, stats14+96, tg1w, tg1b, 1.f/147456.f);

  // ---- TDF: gemm2 (12288x3072x192), 8-wave 128x128 ----
  gemm2_w8<<<2304,512,0,stream>>>(h1, tw2b, h2, stats5);

  // ---- final mix (inline GN2 params) ----
  final_mix<<<6144,256,0,stream>>>(h2, xr, stats5, tg2w, tg2b, 1.f/2359296.f, att, (float*)d_out);
}